// Round 1
// baseline (34038.821 us; speedup 1.0000x reference)
//
#include <hip/hip_runtime.h>
#include <math.h>

#define TT 512
#define LOG2PI 1.8378770664093453

// d_ws layout (float offsets). Total ~2.3 MB.
enum : int {
  WS_BA    = 0,                   // [TT][32][32] bA_t (t=1..511 used)
  WS_BAV   = WS_BA  + TT*32*32,   // [TT][32] ba_t
  WS_YT    = WS_BAV + TT*32,      // [TT][32] HtRi@(y_t-eb)
  WS_MTP   = WS_YT  + TT*32,      // inv(m_trans_cov)
  WS_MEP   = WS_MTP + 1024,       // inv(m_emis_cov)
  WS_MPP   = WS_MEP + 1024,       // inv(m_prior_cov)
  WS_QI    = WS_MPP + 1024,       // inv(v_trans_cov)
  WS_RI    = WS_QI  + 1024,       // inv(v_emis_cov)
  WS_P0I   = WS_RI  + 1024,       // inv(v_prior_cov)
  WS_QIW   = WS_P0I + 1024,       // Qi @ vtw
  WS_CW    = WS_QIW + 1024,       // vtw^T Qi vtw
  WS_HTRI  = WS_CW  + 1024,       // vew^T Ri
  WS_HTRIH = WS_HTRI+ 1024,       // vew^T Ri vew
  WS_TQ    = WS_HTRIH+1024,       // mtw^T Mtp mtw
  WS_EM    = WS_TQ  + 1024,       // -0.5 mew^T Mep mew
  WS_EML   = WS_EM  + 1024,       // -0.5 Mep mew
  WS_LAM0  = WS_EML + 1024,
  WS_S1    = WS_LAM0+ 1024,
  WS_FPT   = WS_S1  + 1024,       // final fP (also K2 temp)
  WS_ETA0  = WS_FPT + 1024,
  WS_CTB   = WS_ETA0+ 32,         // (QiW)^T vtb
  WS_FMT   = WS_CTB + 32,         // final fm
  WS_LDS3  = WS_FMT + 32,         // logdets: mtc, mec, mpc (+pad)
  WS_DACC  = WS_LDS3 + 4,         // 2 doubles: c_const, c_forward
  WS_END   = WS_DACC + 4
};

#define SM(A,i,j) A[(i)*33+(j)]

// Gauss-Jordan on [32|32] augmented matrix in LDS (stride 65, ping-pong
// buffers at +0 / +2080). One __syncthreads per pivot. Input in buf0,
// inverse lands in buf0 right half. Returns product of pivots (= det).
__device__ __forceinline__ double gj_pivots(float* aug, int tid) {
  const int j = tid & 31, r0 = tid >> 5;
  double pp = 1.0;
  for (int p = 0; p < 32; ++p) {
    float* Abuf = aug + (p & 1) * 2080;
    float* Bbuf = aug + ((p & 1) ^ 1) * 2080;
    const float piv = Abuf[p*65 + p];
    pp *= (double)piv;
    const float ip = 1.0f / piv;
    const float apj0 = Abuf[p*65 + j] * ip;
    const float apj1 = Abuf[p*65 + 32 + j] * ip;
#pragma unroll
    for (int m = 0; m < 4; ++m) {
      const int ri = r0 + 8*m;
      const float aip = Abuf[ri*65 + p];
      if (ri == p) {
        Bbuf[ri*65 + j]      = apj0;
        Bbuf[ri*65 + 32 + j] = apj1;
      } else {
        Bbuf[ri*65 + j]      = Abuf[ri*65 + j]      - aip * apj0;
        Bbuf[ri*65 + 32 + j] = Abuf[ri*65 + 32 + j] - aip * apj1;
      }
    }
    __syncthreads();
  }
  return pp;
}

__device__ __forceinline__ float block_reduce(float v, float* red, int tid) {
#pragma unroll
  for (int m = 32; m >= 1; m >>= 1) v += __shfl_xor(v, m, 64);
  if ((tid & 63) == 0) red[tid >> 6] = v;
  __syncthreads();
  return red[0] + red[1] + red[2] + red[3];
}

// K1: invert the 6 constant SPD matrices, logdets for the 3 model covs.
__global__ __launch_bounds__(256) void k1_invert(
    const float* __restrict__ mtc, const float* __restrict__ mec,
    const float* __restrict__ mpc, const float* __restrict__ vtc,
    const float* __restrict__ vcc, const float* __restrict__ vpc,
    float* __restrict__ ws) {
  __shared__ float aug[2*2080];
  const int tid = threadIdx.x, j = tid & 31, r0 = tid >> 5;
  const float* src; float* dst; int lds = -1;
  switch (blockIdx.x) {
    case 0: src = mtc; dst = ws + WS_MTP; lds = 0; break;
    case 1: src = mec; dst = ws + WS_MEP; lds = 1; break;
    case 2: src = mpc; dst = ws + WS_MPP; lds = 2; break;
    case 3: src = vtc; dst = ws + WS_QI;  break;
    case 4: src = vcc; dst = ws + WS_RI;  break;
    default: src = vpc; dst = ws + WS_P0I; break;
  }
#pragma unroll
  for (int m = 0; m < 4; ++m) {
    const int ri = r0 + 8*m;
    aug[ri*65 + j] = src[ri*32 + j];
    aug[ri*65 + 32 + j] = (ri == j) ? 1.f : 0.f;
  }
  __syncthreads();
  double pp = gj_pivots(aug, tid);
#pragma unroll
  for (int m = 0; m < 4; ++m) {
    const int ri = r0 + 8*m;
    dst[ri*32 + j] = aug[ri*65 + 32 + j];
  }
  if (tid == 0 && lds >= 0) ws[WS_LDS3 + lds] = (float)log(pp);
}

// K2: derived constant matrices/vectors + analytic constant sum (double).
__global__ __launch_bounds__(256) void k2_derived(
    const float* __restrict__ obs, const float* __restrict__ vpm,
    const float* __restrict__ vtw, const float* __restrict__ vtb,
    const float* __restrict__ vew, const float* __restrict__ veb,
    const float* __restrict__ mtw, const float* __restrict__ mew,
    float* __restrict__ ws) {
  const int tid = threadIdx.x, j = tid & 31, r0 = tid >> 5;
  // stage 1: QiW, HtRi, tmp=Mtp@mtw (in WS_FPT), EmL=-0.5 Mep@mew
#pragma unroll
  for (int m = 0; m < 4; ++m) {
    const int ri = r0 + 8*m;
    float s1 = 0.f, s2 = 0.f, s3 = 0.f, s4 = 0.f;
    for (int k = 0; k < 32; ++k) {
      s1 += ws[WS_QI  + ri*32 + k] * vtw[k*32 + j];
      s2 += vew[k*32 + ri] * ws[WS_RI + k*32 + j];
      s3 += ws[WS_MTP + ri*32 + k] * mtw[k*32 + j];
      s4 += ws[WS_MEP + ri*32 + k] * mew[k*32 + j];
    }
    ws[WS_QIW + ri*32 + j] = s1;
    ws[WS_HTRI + ri*32 + j] = s2;
    ws[WS_FPT + ri*32 + j] = s3;
    ws[WS_EML + ri*32 + j] = -0.5f * s4;
  }
  __syncthreads();
  // stage 2: CW, HtRiH(+Lam0), TQ, Em(+S1), ctb, eta0
#pragma unroll
  for (int m = 0; m < 4; ++m) {
    const int ri = r0 + 8*m;
    float s1 = 0.f, s2 = 0.f, s3 = 0.f, s4 = 0.f;
    for (int k = 0; k < 32; ++k) {
      s1 += vtw[k*32 + ri] * ws[WS_QIW + k*32 + j];
      s2 += ws[WS_HTRI + ri*32 + k] * vew[k*32 + j];
      s3 += mtw[k*32 + ri] * ws[WS_FPT + k*32 + j];
      s4 += mew[k*32 + ri] * ws[WS_EML + k*32 + j];
    }
    ws[WS_CW + ri*32 + j] = s1;
    ws[WS_HTRIH + ri*32 + j] = s2;
    ws[WS_LAM0 + ri*32 + j] = ws[WS_P0I + ri*32 + j] + s2;
    ws[WS_TQ + ri*32 + j] = s3;
    ws[WS_EM + ri*32 + j] = s4;
    ws[WS_S1 + ri*32 + j] = s4 - 0.5f * ws[WS_MPP + ri*32 + j];
  }
  if (tid < 32) {
    float s1 = 0.f, s2 = 0.f;
    for (int k = 0; k < 32; ++k) {
      s1 += ws[WS_QIW + k*32 + tid] * vtb[k];
      s2 += ws[WS_P0I + tid*32 + k] * vpm[k]
          + ws[WS_HTRI + tid*32 + k] * (obs[k] - veb[k]);
    }
    ws[WS_CTB + tid] = s1;
    ws[WS_ETA0 + tid] = s2;
  }
  __syncthreads();
  if (tid == 0) {
    const double ldmt = (double)ws[WS_LDS3 + 0];
    const double ldme = (double)ws[WS_LDS3 + 1];
    const double ldmp = (double)ws[WS_LDS3 + 2];
    const double ct_me = -0.5 * (32.0 * LOG2PI + ldme);
    const double ct_mt = -0.5 * (32.0 * LOG2PI + ldmt);
    const double ct_mp = -0.5 * (32.0 * LOG2PI + ldmp);
    double c = ct_mp + ct_me;                                        // c0
    c += (double)(TT - 1) * (ct_me + ct_mt + 0.5 * 32.0 * LOG2PI + 16.0);
    c += 0.5 * 32.0 * LOG2PI + 16.0;   // final logdet-fP const + final 0.5*dz
    ((double*)(ws + WS_DACC))[0] = c;
  }
}

// K3: Yt[t] = HtRi @ (y_t - veb), all t in parallel.
__global__ __launch_bounds__(256) void k3_yt(const float* __restrict__ obs,
                                             const float* __restrict__ veb,
                                             float* __restrict__ ws) {
  const int tid = threadIdx.x, i = tid & 31, lt = tid >> 5;
  const int t = blockIdx.x * 8 + lt;
  float s = 0.f;
  for (int k = 0; k < 32; ++k)
    s += ws[WS_HTRI + i*32 + k] * (obs[t*32 + k] - veb[k]);
  ws[WS_YT + t*32 + i] = s;
}

// K4: sequential forward sweep (info-form KF + S-recursion), 1 block.
__global__ __launch_bounds__(256) void k4_forward(const float* __restrict__ mtw,
                                                  const float* __restrict__ vtb,
                                                  float* __restrict__ ws) {
  __shared__ float aug[2*2080];
  __shared__ float Lam[32*33], Smat[32*33], X[32*33], T1[32*33];
  __shared__ float Jm[32*33], P2[32*33], Lp[32*33];
  __shared__ float eta[32], eta2[32], e2[32];
  __shared__ float red[4];
  __shared__ double acc_s;
  const int tid = threadIdx.x, j = tid & 31, r0 = tid >> 5;
#pragma unroll
  for (int m = 0; m < 4; ++m) {
    const int ri = r0 + 8*m;
    SM(Lam,ri,j)  = ws[WS_LAM0 + ri*32 + j];
    SM(Smat,ri,j) = ws[WS_S1 + ri*32 + j];
  }
  if (tid < 32) eta[tid] = ws[WS_ETA0 + tid];
  if (tid == 0) acc_s = 0.0;
  __syncthreads();

  for (int t = 1; t < TT; ++t) {
    // A: aug = [Lam + CW | I]
#pragma unroll
    for (int m = 0; m < 4; ++m) {
      const int ri = r0 + 8*m;
      aug[ri*65 + j] = SM(Lam,ri,j) + ws[WS_CW + ri*32 + j];
      aug[ri*65 + 32 + j] = (ri == j) ? 1.f : 0.f;
    }
    __syncthreads();
    const double pp = gj_pivots(aug, tid);   // bcov in aug[.][32+.]
    const float ld_bcov = -(float)log(pp);
    // C: traces + X = QiW @ bcov ; bA = X^T to global ; e2 = eta - ctb
    float part = 0.f;
#pragma unroll
    for (int m = 0; m < 4; ++m) {
      const int ri = r0 + 8*m;
      part += (SM(Smat,ri,j) - 0.5f*ws[WS_TQ + ri*32 + j]) * aug[j*65 + 32 + ri];
      float s = 0.f;
      for (int k = 0; k < 32; ++k)
        s += ws[WS_QIW + ri*32 + k] * aug[k*65 + 32 + j];
      SM(X,ri,j) = s;
      ws[WS_BA + t*1024 + j*32 + ri] = s;    // bA_t = X^T
    }
    if (tid < 32) e2[tid] = eta[tid] - ws[WS_CTB + tid];
    const float r2 = block_reduce(part, red, tid);   // sync: X,e2 visible
    if (tid == 0) acc_s += (double)r2 + 0.5 * (double)ld_bcov;
    // D: T1 = X@S ; Lp = Qi - X@QiW^T ; Jm = Mw@X^T - I ; ba_t
#pragma unroll
    for (int m = 0; m < 4; ++m) {
      const int ri = r0 + 8*m;
      float sT = 0.f, sL = 0.f, sJ = 0.f;
      for (int k = 0; k < 32; ++k) {
        const float xik = SM(X,ri,k);
        sT += xik * SM(Smat,k,j);
        sL += xik * ws[WS_QIW + j*32 + k];
        sJ += mtw[ri*32 + k] * SM(X,j,k);
      }
      SM(T1,ri,j) = sT;
      SM(Lp,ri,j) = ws[WS_QI + ri*32 + j] - sL;
      SM(Jm,ri,j) = sJ - ((ri == j) ? 1.f : 0.f);
    }
    if (tid < 32) {
      float s = 0.f;
      for (int k = 0; k < 32; ++k) s += aug[tid*65 + 32 + k] * e2[k];
      ws[WS_BAV + t*32 + tid] = s;           // ba_t
    }
    __syncthreads();
    // E: P2 = Mtp@Jm ; eta2 = X@eta + Lp@vtb + Yt
#pragma unroll
    for (int m = 0; m < 4; ++m) {
      const int ri = r0 + 8*m;
      float s = 0.f;
      for (int k = 0; k < 32; ++k)
        s += ws[WS_MTP + ri*32 + k] * SM(Jm,k,j);
      SM(P2,ri,j) = s;
    }
    if (tid < 32) {
      float s = ws[WS_YT + t*32 + tid];
      for (int k = 0; k < 32; ++k)
        s += SM(X,tid,k) * eta[k] + SM(Lp,tid,k) * vtb[k];
      eta2[tid] = s;
    }
    __syncthreads();
    // F: S' = T1@X^T + Em - 0.5 J^T P2 ; Lam' = Lp + HtRiH ; eta'
#pragma unroll
    for (int m = 0; m < 4; ++m) {
      const int ri = r0 + 8*m;
      float s1 = 0.f, s2 = 0.f;
      for (int k = 0; k < 32; ++k) {
        s1 += SM(T1,ri,k) * SM(X,j,k);
        s2 += SM(Jm,k,ri) * SM(P2,k,j);
      }
      SM(Smat,ri,j) = s1 + ws[WS_EM + ri*32 + j] - 0.5f * s2;
      SM(Lam,ri,j)  = SM(Lp,ri,j) + ws[WS_HTRIH + ri*32 + j];
    }
    if (tid < 32) eta[tid] = eta2[tid];
    __syncthreads();
  }

  // final: fP = inv(Lam), fm = fP@eta, + 0.5*logdet(fP)
#pragma unroll
  for (int m = 0; m < 4; ++m) {
    const int ri = r0 + 8*m;
    aug[ri*65 + j] = SM(Lam,ri,j);
    aug[ri*65 + 32 + j] = (ri == j) ? 1.f : 0.f;
  }
  __syncthreads();
  const double pp = gj_pivots(aug, tid);
#pragma unroll
  for (int m = 0; m < 4; ++m) {
    const int ri = r0 + 8*m;
    ws[WS_FPT + ri*32 + j] = aug[ri*65 + 32 + j];
  }
  if (tid < 32) {
    float s = 0.f;
    for (int k = 0; k < 32; ++k) s += aug[tid*65 + 32 + k] * eta[k];
    ws[WS_FMT + tid] = s;
  }
  if (tid == 0) ((double*)(ws + WS_DACC))[1] = acc_s + 0.5 * (-log(pp));
}

// K5: backward sweep (G,h recursion) + final tr/qf terms, 1 block.
__global__ __launch_bounds__(256) void k5_backward(
    const float* __restrict__ obs, const float* __restrict__ mpm,
    const float* __restrict__ mtw, const float* __restrict__ mtb,
    const float* __restrict__ mew, const float* __restrict__ meb,
    float* __restrict__ ws, float* __restrict__ out) {
  __shared__ float G[32*33], Gn[32*33], fPl[32*33], BA[32*33];
  __shared__ float Mb[32*33], Ub[32*33], Vb[32*33], Jb[32*33];
  __shared__ float M2[32*33], U2[32*33], V2[32*33];
  __shared__ float fm[32], h[32], hn[32], g[32], cme[32], cmo[32], bav[32];
  __shared__ float red[4];
  __shared__ double acc_s;
  const int tid = threadIdx.x, j = tid & 31, r0 = tid >> 5;
#pragma unroll
  for (int m = 0; m < 4; ++m) {
    const int ri = r0 + 8*m;
    SM(G,ri,j) = (ri == j) ? 1.f : 0.f;
    SM(fPl,ri,j) = ws[WS_FPT + ri*32 + j];
  }
  if (tid < 32) { h[tid] = 0.f; fm[tid] = ws[WS_FMT + tid]; }
  if (tid == 0) acc_s = 0.0;
  __syncthreads();

  for (int s = TT - 1; s >= 1; --s) {
    // A: stage bA_s, ba_s ; g = G@fm + h
#pragma unroll
    for (int m = 0; m < 4; ++m) {
      const int ri = r0 + 8*m;
      SM(BA,ri,j) = ws[WS_BA + s*1024 + ri*32 + j];
    }
    if (tid < 32) bav[tid] = ws[WS_BAV + s*32 + tid];
    else if (tid < 64) {
      const int i2 = tid - 32;
      float sg = h[i2];
      for (int k = 0; k < 32; ++k) sg += SM(G,i2,k) * fm[k];
      g[i2] = sg;
    }
    __syncthreads();
    // B: Mb = Ew@G ; Ub = EmL@G ; Jb = Mw@BA - I ; cme ; hn
#pragma unroll
    for (int m = 0; m < 4; ++m) {
      const int ri = r0 + 8*m;
      float s1 = 0.f, s2 = 0.f, s3 = 0.f;
      for (int k = 0; k < 32; ++k) {
        const float gk = SM(G,k,j);
        s1 += mew[ri*32 + k] * gk;
        s2 += ws[WS_EML + ri*32 + k] * gk;
        s3 += mtw[ri*32 + k] * SM(BA,k,j);
      }
      SM(Mb,ri,j) = s1; SM(Ub,ri,j) = s2;
      SM(Jb,ri,j) = s3 - ((ri == j) ? 1.f : 0.f);
    }
    if (tid < 32) {
      float s1 = meb[tid] - obs[s*32 + tid];
      for (int k = 0; k < 32; ++k) s1 += mew[tid*32 + k] * g[k];
      cme[tid] = s1;
    } else if (tid < 64) {
      const int i2 = tid - 32;
      float s1 = bav[i2];
      for (int k = 0; k < 32; ++k) s1 += SM(BA,i2,k) * h[k];
      hn[i2] = s1;
    }
    __syncthreads();
    // C: Vb = fP@Mb ; M2 = Jb@G ; cmo = Jb@g + Mw@ba + mtb
#pragma unroll
    for (int m = 0; m < 4; ++m) {
      const int ri = r0 + 8*m;
      float s1 = 0.f, s2 = 0.f;
      for (int k = 0; k < 32; ++k) {
        s1 += SM(fPl,ri,k) * SM(Mb,k,j);
        s2 += SM(Jb,ri,k) * SM(G,k,j);
      }
      SM(Vb,ri,j) = s1; SM(M2,ri,j) = s2;
    }
    if (tid < 32) {
      float s1 = mtb[tid];
      for (int k = 0; k < 32; ++k)
        s1 += SM(Jb,tid,k) * g[k] + mtw[tid*32 + k] * bav[k];
      cmo[tid] = s1;
    }
    __syncthreads();
    // D: U2 = -0.5 Mtp@M2 ; V2 = fP@M2 ; Gn = BA@G
#pragma unroll
    for (int m = 0; m < 4; ++m) {
      const int ri = r0 + 8*m;
      float s1 = 0.f, s2 = 0.f, s3 = 0.f;
      for (int k = 0; k < 32; ++k) {
        const float mk = SM(M2,k,j);
        s1 += ws[WS_MTP + ri*32 + k] * mk;
        s2 += SM(fPl,ri,k) * mk;
        s3 += SM(BA,ri,k) * SM(G,k,j);
      }
      SM(U2,ri,j) = -0.5f * s1; SM(V2,ri,j) = s2; SM(Gn,ri,j) = s3;
    }
    __syncthreads();
    // E: accumulate tr + qf for both slots ; G <- Gn, h <- hn
    float part = 0.f;
#pragma unroll
    for (int m = 0; m < 4; ++m) {
      const int ri = r0 + 8*m;
      part += SM(Ub,ri,j) * SM(Vb,j,ri) + SM(U2,ri,j) * SM(V2,j,ri)
            - 0.5f * cme[ri] * ws[WS_MEP + ri*32 + j] * cme[j]
            - 0.5f * cmo[ri] * ws[WS_MTP + ri*32 + j] * cmo[j];
      SM(G,ri,j) = SM(Gn,ri,j);
    }
    if (tid < 32) h[tid] = hn[tid];
    const float r2 = block_reduce(part, red, tid);
    if (tid == 0) acc_s += (double)r2;
    __syncthreads();
  }

  // s = 0 slots: even (emis, y_0) and prior (A=I, Om=-0.5 Mpp)
  if (tid < 32) {
    float sg = h[tid];
    for (int k = 0; k < 32; ++k) sg += SM(G,tid,k) * fm[k];
    g[tid] = sg;
  }
  __syncthreads();
#pragma unroll
  for (int m = 0; m < 4; ++m) {
    const int ri = r0 + 8*m;
    float s1 = 0.f, s2 = 0.f, s3 = 0.f;
    for (int k = 0; k < 32; ++k) {
      const float gk = SM(G,k,j);
      s1 += mew[ri*32 + k] * gk;
      s2 += ws[WS_EML + ri*32 + k] * gk;
      s3 += ws[WS_MPP + ri*32 + k] * gk;
    }
    SM(Mb,ri,j) = s1; SM(Ub,ri,j) = s2; SM(U2,ri,j) = -0.5f * s3;
  }
  if (tid < 32) {
    float s1 = meb[tid] - obs[tid];
    for (int k = 0; k < 32; ++k) s1 += mew[tid*32 + k] * g[k];
    cme[tid] = s1;
    cmo[tid] = g[tid] - mpm[tid];
  }
  __syncthreads();
#pragma unroll
  for (int m = 0; m < 4; ++m) {
    const int ri = r0 + 8*m;
    float s1 = 0.f, s2 = 0.f;
    for (int k = 0; k < 32; ++k) {
      s1 += SM(fPl,ri,k) * SM(Mb,k,j);
      s2 += SM(fPl,ri,k) * SM(G,k,j);
    }
    SM(Vb,ri,j) = s1; SM(V2,ri,j) = s2;
  }
  __syncthreads();
  float part = 0.f;
#pragma unroll
  for (int m = 0; m < 4; ++m) {
    const int ri = r0 + 8*m;
    part += SM(Ub,ri,j) * SM(Vb,j,ri) + SM(U2,ri,j) * SM(V2,j,ri)
          - 0.5f * cme[ri] * ws[WS_MEP + ri*32 + j] * cme[j]
          - 0.5f * cmo[ri] * ws[WS_MPP + ri*32 + j] * cmo[j];
  }
  const float r2 = block_reduce(part, red, tid);
  if (tid == 0) {
    const double ctot = ((double*)(ws + WS_DACC))[0]
                      + ((double*)(ws + WS_DACC))[1]
                      + acc_s + (double)r2;
    out[0] = (float)ctot;
  }
}

extern "C" void kernel_launch(void* const* d_in, const int* in_sizes, int n_in,
                              void* d_out, int out_size, void* d_ws, size_t ws_size,
                              hipStream_t stream) {
  (void)in_sizes; (void)n_in; (void)out_size; (void)ws_size;
  const float* obs = (const float*)d_in[0];
  const float* mpm = (const float*)d_in[1];
  const float* mpc = (const float*)d_in[2];
  const float* mtw = (const float*)d_in[3];
  const float* mtb = (const float*)d_in[4];
  const float* mtc = (const float*)d_in[5];
  const float* mew = (const float*)d_in[6];
  const float* meb = (const float*)d_in[7];
  const float* mec = (const float*)d_in[8];
  const float* vpm = (const float*)d_in[9];
  const float* vpc = (const float*)d_in[10];
  const float* vtw = (const float*)d_in[11];
  const float* vtb = (const float*)d_in[12];
  const float* vtc = (const float*)d_in[13];
  const float* vew = (const float*)d_in[14];
  const float* veb = (const float*)d_in[15];
  const float* vcc = (const float*)d_in[16];
  float* ws  = (float*)d_ws;
  float* out = (float*)d_out;

  k1_invert<<<6, 256, 0, stream>>>(mtc, mec, mpc, vtc, vcc, vpc, ws);
  k2_derived<<<1, 256, 0, stream>>>(obs, vpm, vtw, vtb, vew, veb, mtw, mew, ws);
  k3_yt<<<TT/8, 256, 0, stream>>>(obs, veb, ws);
  k4_forward<<<1, 256, 0, stream>>>(mtw, vtb, ws);
  k5_backward<<<1, 256, 0, stream>>>(obs, mpm, mtw, mtb, mew, meb, ws, out);
}

// Round 2
// 6146.166 us; speedup vs baseline: 5.5382x; 5.5382x over previous
//
#include <hip/hip_runtime.h>
#include <math.h>

#define TT 512
#define LOG2PI 1.8378770664093453

// ---------------- workspace layout (float offsets) ----------------
enum : int {
  WS_X     = 0,                    // [TT][32][32] X_t = QiW@bcov_t (bA_t = X^T), t=1..511
  WS_BCOV  = WS_X    + TT*1024,    // [TT][32][32] bcov_t
  WS_BA    = WS_BCOV + TT*1024,    // [TT][32] ba_t
  WS_YT    = WS_BA   + TT*32,      // [TT][32] HtRi@(y_t - veb)
  WS_MTP   = WS_YT   + TT*32,      // inv(m_trans_cov)
  WS_MEP   = WS_MTP + 1024,
  WS_MPP   = WS_MEP + 1024,
  WS_QI    = WS_MPP + 1024,
  WS_RI    = WS_QI  + 1024,
  WS_P0I   = WS_RI  + 1024,
  WS_QIW   = WS_P0I + 1024,        // Qi@vtw
  WS_CW    = WS_QIW + 1024,        // vtw^T Qi vtw
  WS_HTRI  = WS_CW  + 1024,
  WS_HTRIH = WS_HTRI+ 1024,
  WS_TQ    = WS_HTRIH+1024,        // mtw^T Mtp mtw
  WS_EM    = WS_TQ  + 1024,        // -0.5 mew^T Mep mew
  WS_EML   = WS_EM  + 1024,        // -0.5 Mep mew
  WS_LAM0CW= WS_EML + 1024,        // P0i + HtRiH + CW
  WS_QHC   = WS_LAM0CW + 1024,     // Qi + HtRiH + CW
  WS_S1    = WS_QHC + 1024,        // S_0 = Em - 0.5 Mpp
  WS_FPT   = WS_S1  + 1024,        // final fP
  WS_ETA0  = WS_FPT + 1024,
  WS_CTB   = WS_ETA0+ 32,          // QiW^T vtb
  WS_QIVTB = WS_CTB + 32,          // Qi vtb
  WS_FMT   = WS_QIVTB + 32,        // final fm
  WS_LDS3  = WS_FMT + 32,          // 3 logdets + pad
  WS_DACC  = WS_LDS3 + 4,          // 4 doubles: const, k4(ld), S-traces, finals
  WS_CEA   = WS_DACC + 8,          // 32 x (BT 1024 + K 1024): S-scan ping
  WS_CEB   = WS_CEA + 32*2048,     // S-scan pong
  WS_GEA   = WS_CEB + 32*2048,     // 32 x (AT 1024 + b 32): G-scan ping
  WS_GEB   = WS_GEA + 32*1056,
  WS_END   = WS_GEB + 32*1056
};
static_assert(WS_DACC % 2 == 0, "double alignment");

#define SM(A,i,j) A[(i)*33+(j)]

// ---------------- helpers ----------------
__device__ __forceinline__ float rlane(float v, int l) {
  return __uint_as_float(__builtin_amdgcn_readlane(__float_as_uint(v), l));
}

// single-wave register Gauss-Jordan: lane c holds augmented column c in a[0..31].
// lanes>=32 end with inverse column (lane-32). returns det (pivot product).
__device__ __forceinline__ double gj_inv32(float a[32]) {
  double pp = 1.0;
#pragma unroll
  for (int p = 0; p < 32; ++p) {
    const float piv = rlane(a[p], p);
    pp *= (double)piv;
    const float sc = a[p] * (1.0f / piv);
#pragma unroll
    for (int r = 0; r < 32; ++r) {
      if (r != p) a[r] -= rlane(a[r], p) * sc;
    }
    a[p] = sc;
  }
  return pp;
}

__device__ __forceinline__ float block_reduce(float v, float* red, int tid) {
#pragma unroll
  for (int m = 32; m >= 1; m >>= 1) v += __shfl_xor(v, m, 64);
  if ((tid & 63) == 0) red[tid >> 6] = v;
  __syncthreads();
  return red[0] + red[1] + red[2] + red[3];
}

// global row-major 32x32 -> LDS stride-33
__device__ __forceinline__ void stage_mat(const float* __restrict__ g, float* L, int tid) {
  const int r = tid >> 3, c = (tid & 7) * 4;
  const float4 v = *(const float4*)(g + r*32 + c);
  L[r*33+c] = v.x; L[r*33+c+1] = v.y; L[r*33+c+2] = v.z; L[r*33+c+3] = v.w;
}
// transposed stage: L[c][r] = g[r][c]
__device__ __forceinline__ void stage_matT(const float* __restrict__ g, float* L, int tid) {
  const int r = tid >> 3, c = (tid & 7) * 4;
  const float4 v = *(const float4*)(g + r*32 + c);
  L[(c  )*33+r] = v.x; L[(c+1)*33+r] = v.y; L[(c+2)*33+r] = v.z; L[(c+3)*33+r] = v.w;
}

// C = A @ B^T (row-row), all LDS stride 33
__device__ __forceinline__ void mm_rr(const float* A, const float* B, float* C, int tid) {
  const int j = tid & 31, r0 = tid >> 5;
#pragma unroll
  for (int m = 0; m < 4; ++m) {
    const int ri = r0 + 8*m;
    float s = 0.f;
    for (int k = 0; k < 32; ++k) s += A[ri*33+k] * B[j*33+k];
    C[ri*33+j] = s;
  }
}
// C = A @ B^T - I
__device__ __forceinline__ void mm_rr_mI(const float* A, const float* B, float* C, int tid) {
  const int j = tid & 31, r0 = tid >> 5;
#pragma unroll
  for (int m = 0; m < 4; ++m) {
    const int ri = r0 + 8*m;
    float s = 0.f;
    for (int k = 0; k < 32; ++k) s += A[ri*33+k] * B[j*33+k];
    C[ri*33+j] = s - ((ri == j) ? 1.f : 0.f);
  }
}
// C = A @ B (plain)
__device__ __forceinline__ void mm_p(const float* A, const float* B, float* C, int tid) {
  const int j = tid & 31, r0 = tid >> 5;
#pragma unroll
  for (int m = 0; m < 4; ++m) {
    const int ri = r0 + 8*m;
    float s = 0.f;
    for (int k = 0; k < 32; ++k) s += A[ri*33+k] * B[k*33+j];
    C[ri*33+j] = s;
  }
}

// legacy LDS GJ for K1 (verified in R1)
__device__ __forceinline__ double gj_pivots(float* aug, int tid) {
  const int j = tid & 31, r0 = tid >> 5;
  double pp = 1.0;
  for (int p = 0; p < 32; ++p) {
    float* Abuf = aug + (p & 1) * 2080;
    float* Bbuf = aug + ((p & 1) ^ 1) * 2080;
    const float piv = Abuf[p*65 + p];
    pp *= (double)piv;
    const float ip = 1.0f / piv;
    const float apj0 = Abuf[p*65 + j] * ip;
    const float apj1 = Abuf[p*65 + 32 + j] * ip;
#pragma unroll
    for (int m = 0; m < 4; ++m) {
      const int ri = r0 + 8*m;
      const float aip = Abuf[ri*65 + p];
      if (ri == p) {
        Bbuf[ri*65 + j]      = apj0;
        Bbuf[ri*65 + 32 + j] = apj1;
      } else {
        Bbuf[ri*65 + j]      = Abuf[ri*65 + j]      - aip * apj0;
        Bbuf[ri*65 + 32 + j] = Abuf[ri*65 + 32 + j] - aip * apj1;
      }
    }
    __syncthreads();
  }
  return pp;
}

// ---------------- K0: init accumulators + scan identities ----------------
__global__ __launch_bounds__(256) void k0_init(float* __restrict__ ws) {
  const int tid = threadIdx.x;
  if (tid == 0) {
    ((double*)(ws + WS_DACC))[2] = 0.0;
    ((double*)(ws + WS_DACC))[3] = 0.0;
  }
  const int idx = tid * 4;
#pragma unroll
  for (int x = 0; x < 4; ++x) {
    const int e = idx + x, r = e >> 5, c = e & 31;
    const float id = (r == c) ? 1.f : 0.f;
    ws[WS_CEA + e]        = id;   // CE_A[0].BT = I
    ws[WS_CEA + 1024 + e] = 0.f;  // CE_A[0].K  = 0
    ws[WS_GEA + 31*1056 + e] = id; // GE_A[31].AT = I
  }
  if (tid < 32) ws[WS_GEA + 31*1056 + 1024 + tid] = 0.f;
}

// ---------------- K1: invert the 6 constant SPD matrices ----------------
__global__ __launch_bounds__(256) void k1_invert(
    const float* __restrict__ mtc, const float* __restrict__ mec,
    const float* __restrict__ mpc, const float* __restrict__ vtc,
    const float* __restrict__ vcc, const float* __restrict__ vpc,
    float* __restrict__ ws) {
  __shared__ float aug[2*2080];
  const int tid = threadIdx.x, j = tid & 31, r0 = tid >> 5;
  const float* src; float* dst; int lds = -1;
  switch (blockIdx.x) {
    case 0: src = mtc; dst = ws + WS_MTP; lds = 0; break;
    case 1: src = mec; dst = ws + WS_MEP; lds = 1; break;
    case 2: src = mpc; dst = ws + WS_MPP; lds = 2; break;
    case 3: src = vtc; dst = ws + WS_QI;  break;
    case 4: src = vcc; dst = ws + WS_RI;  break;
    default: src = vpc; dst = ws + WS_P0I; break;
  }
#pragma unroll
  for (int m = 0; m < 4; ++m) {
    const int ri = r0 + 8*m;
    aug[ri*65 + j] = src[ri*32 + j];
    aug[ri*65 + 32 + j] = (ri == j) ? 1.f : 0.f;
  }
  __syncthreads();
  double pp = gj_pivots(aug, tid);
#pragma unroll
  for (int m = 0; m < 4; ++m) {
    const int ri = r0 + 8*m;
    dst[ri*32 + j] = aug[ri*65 + 32 + j];
  }
  if (tid == 0 && lds >= 0) ws[WS_LDS3 + lds] = (float)log(pp);
}

// ---------------- K2: derived constants + analytic constant (double) ----------------
__global__ __launch_bounds__(256) void k2_derived(
    const float* __restrict__ obs, const float* __restrict__ vpm,
    const float* __restrict__ vtw, const float* __restrict__ vtb,
    const float* __restrict__ vew, const float* __restrict__ veb,
    const float* __restrict__ mtw, const float* __restrict__ mew,
    float* __restrict__ ws) {
  const int tid = threadIdx.x, j = tid & 31, r0 = tid >> 5;
#pragma unroll
  for (int m = 0; m < 4; ++m) {
    const int ri = r0 + 8*m;
    float s1 = 0.f, s2 = 0.f, s3 = 0.f, s4 = 0.f;
    for (int k = 0; k < 32; ++k) {
      s1 += ws[WS_QI  + ri*32 + k] * vtw[k*32 + j];
      s2 += vew[k*32 + ri] * ws[WS_RI + k*32 + j];
      s3 += ws[WS_MTP + ri*32 + k] * mtw[k*32 + j];
      s4 += ws[WS_MEP + ri*32 + k] * mew[k*32 + j];
    }
    ws[WS_QIW + ri*32 + j] = s1;
    ws[WS_HTRI + ri*32 + j] = s2;
    ws[WS_FPT + ri*32 + j] = s3;      // temp Mtp@mtw
    ws[WS_EML + ri*32 + j] = -0.5f * s4;
  }
  __syncthreads();
#pragma unroll
  for (int m = 0; m < 4; ++m) {
    const int ri = r0 + 8*m;
    float s1 = 0.f, s2 = 0.f, s3 = 0.f, s4 = 0.f;
    for (int k = 0; k < 32; ++k) {
      s1 += vtw[k*32 + ri] * ws[WS_QIW + k*32 + j];
      s2 += ws[WS_HTRI + ri*32 + k] * vew[k*32 + j];
      s3 += mtw[k*32 + ri] * ws[WS_FPT + k*32 + j];
      s4 += mew[k*32 + ri] * ws[WS_EML + k*32 + j];
    }
    ws[WS_CW + ri*32 + j] = s1;
    ws[WS_HTRIH + ri*32 + j] = s2;
    ws[WS_LAM0CW + ri*32 + j] = ws[WS_P0I + ri*32 + j] + s1 + s2;
    ws[WS_QHC    + ri*32 + j] = ws[WS_QI  + ri*32 + j] + s1 + s2;
    ws[WS_TQ + ri*32 + j] = s3;
    ws[WS_EM + ri*32 + j] = s4;
    ws[WS_S1 + ri*32 + j] = s4 - 0.5f * ws[WS_MPP + ri*32 + j];
  }
  if (tid < 32) {
    float s1 = 0.f, s2 = 0.f, s3 = 0.f;
    for (int k = 0; k < 32; ++k) {
      s1 += ws[WS_QIW + k*32 + tid] * vtb[k];
      s2 += ws[WS_P0I + tid*32 + k] * vpm[k]
          + ws[WS_HTRI + tid*32 + k] * (obs[k] - veb[k]);
      s3 += ws[WS_QI + tid*32 + k] * vtb[k];
    }
    ws[WS_CTB + tid] = s1;
    ws[WS_ETA0 + tid] = s2;
    ws[WS_QIVTB + tid] = s3;
  }
  __syncthreads();
  if (tid == 0) {
    const double ldmt = (double)ws[WS_LDS3 + 0];
    const double ldme = (double)ws[WS_LDS3 + 1];
    const double ldmp = (double)ws[WS_LDS3 + 2];
    const double ct_me = -0.5 * (32.0 * LOG2PI + ldme);
    const double ct_mt = -0.5 * (32.0 * LOG2PI + ldmt);
    const double ct_mp = -0.5 * (32.0 * LOG2PI + ldmp);
    double c = ct_mp + ct_me;
    c += (double)(TT - 1) * (ct_me + ct_mt + 0.5 * 32.0 * LOG2PI + 16.0);
    c += 0.5 * 32.0 * LOG2PI + 16.0;
    ((double*)(ws + WS_DACC))[0] = c;
  }
}

// ---------------- K3: Yt[t] = HtRi @ (y_t - veb) ----------------
__global__ __launch_bounds__(256) void k3_yt(const float* __restrict__ obs,
                                             const float* __restrict__ veb,
                                             float* __restrict__ ws) {
  const int tid = threadIdx.x, i = tid & 31, lt = tid >> 5;
  const int t = blockIdx.x * 8 + lt;
  float s = 0.f;
  for (int k = 0; k < 32; ++k)
    s += ws[WS_HTRI + i*32 + k] * (obs[t*32 + k] - veb[k]);
  ws[WS_YT + t*32 + i] = s;
}

// 4x4-tile per-wave matmul C = A@B^T (64 lanes cover 32x32)
__device__ __forceinline__ void w44_rr(const float* A, const float* B,
                                       float out[4][4], int lane) {
  const int r4 = lane >> 3, c4 = lane & 7;
#pragma unroll
  for (int i = 0; i < 4; ++i)
#pragma unroll
    for (int x = 0; x < 4; ++x) out[i][x] = 0.f;
  for (int k = 0; k < 32; ++k) {
    float av[4], bv[4];
#pragma unroll
    for (int i = 0; i < 4; ++i) av[i] = A[(4*r4+i)*33 + k];
#pragma unroll
    for (int x = 0; x < 4; ++x) bv[x] = B[(4*c4+x)*33 + k];
#pragma unroll
    for (int i = 0; i < 4; ++i)
#pragma unroll
      for (int x = 0; x < 4; ++x) out[i][x] += av[i] * bv[x];
  }
}

// ---------------- K4min: sequential information-form filter ----------------
__global__ __launch_bounds__(256) void k4min(float* __restrict__ ws) {
  __shared__ float LamCW[1056], Bcv[1056], Xs[1056], QiWl[1056], QHCl[1056];
  __shared__ float eta[32], ctbl[32], qivtbl[32];
  const int tid = threadIdx.x, lane = tid & 63, wv = tid >> 6;
  stage_mat(ws + WS_QIW, QiWl, tid);
  stage_mat(ws + WS_QHC, QHCl, tid);
  stage_mat(ws + WS_LAM0CW, LamCW, tid);
  if (tid < 32) {
    eta[tid] = ws[WS_ETA0 + tid];
    ctbl[tid] = ws[WS_CTB + tid];
    qivtbl[tid] = ws[WS_QIVTB + tid];
  }
  __syncthreads();
  double acc = 0.0;
  for (int t = 1; t < TT; ++t) {
    if (wv == 0) {
      float a[32];
      const int cc = lane & 31;
#pragma unroll
      for (int r = 0; r < 32; ++r) {
        const float v = LamCW[r*33 + cc];
        a[r] = (lane < 32) ? v : ((r == lane - 32) ? 1.f : 0.f);
      }
      const double pp = gj_inv32(a);
      if (lane >= 32) {
        const int c2 = lane - 32;
#pragma unroll
        for (int r = 0; r < 32; ++r) {
          Bcv[r*33 + c2] = a[r];
          ws[WS_BCOV + t*1024 + r*32 + c2] = a[r];
        }
      }
      if (tid == 0) acc += -log(pp);
    }
    __syncthreads();
    if (wv == 0) {
      // X = QiW @ bcov (bcov symmetric -> row-row)
      float c4t[4][4];
      w44_rr(QiWl, Bcv, c4t, lane);
      const int r4 = lane >> 3, c4 = lane & 7;
#pragma unroll
      for (int i = 0; i < 4; ++i) {
#pragma unroll
        for (int x = 0; x < 4; ++x) Xs[(4*r4+i)*33 + 4*c4 + x] = c4t[i][x];
        float4 v = make_float4(c4t[i][0], c4t[i][1], c4t[i][2], c4t[i][3]);
        *(float4*)(ws + WS_X + t*1024 + (4*r4+i)*32 + 4*c4) = v;
      }
    } else if (wv == 1 && lane < 32) {
      // ba_t = bcov @ (eta - ctb)
      float s = 0.f;
      for (int k = 0; k < 32; ++k) s += Bcv[lane*33 + k] * (eta[k] - ctbl[k]);
      ws[WS_BA + t*32 + lane] = s;
    }
    __syncthreads();
    if (wv == 0) {
      // LamCW' = QHC - X @ QiW^T
      float c4t[4][4];
      w44_rr(Xs, QiWl, c4t, lane);
      const int r4 = lane >> 3, c4 = lane & 7;
#pragma unroll
      for (int i = 0; i < 4; ++i)
#pragma unroll
        for (int x = 0; x < 4; ++x)
          LamCW[(4*r4+i)*33 + 4*c4 + x] =
              QHCl[(4*r4+i)*33 + 4*c4 + x] - c4t[i][x];
    } else if (wv == 1 && lane < 32) {
      // eta' = X@(eta - ctb) + Qi@vtb + Yt   (== X@eta + Lp@vtb + Yt)
      float s = qivtbl[lane] + ws[WS_YT + t*32 + lane];
      for (int k = 0; k < 32; ++k) s += Xs[lane*33 + k] * (eta[k] - ctbl[k]);
      eta[lane] = s;   // single-wave lockstep: all reads precede this write
    }
    __syncthreads();
  }
  // final: fP = inv(LamCW - CW), fm = fP@eta
  if (wv == 0) {
    float a[32];
    const int cc = lane & 31;
#pragma unroll
    for (int r = 0; r < 32; ++r) {
      const float v = LamCW[r*33 + cc] - ws[WS_CW + r*32 + cc];
      a[r] = (lane < 32) ? v : ((r == lane - 32) ? 1.f : 0.f);
    }
    const double pp = gj_inv32(a);
    if (lane >= 32) {
      const int c2 = lane - 32;
      float fmv = 0.f;
#pragma unroll
      for (int r = 0; r < 32; ++r) {
        ws[WS_FPT + r*32 + c2] = a[r];
        fmv += a[r] * eta[r];    // fP symmetric: column c2 == row c2
      }
      ws[WS_FMT + c2] = fmv;
    }
    if (tid == 0) {
      acc += -log(pp);
      ((double*)(ws + WS_DACC))[1] = 0.5 * acc;
    }
  }
}

// ---------------- K_S-A: compose S-maps within each chunk ----------------
// element t: S -> X_t S X_t^T + K_t,  K_t = Em - 0.5 J^T Mtp J, J^T = X@mtw^T - I
__global__ __launch_bounds__(256) void ksa(const float* __restrict__ mtw,
                                           float* __restrict__ ws) {
  __shared__ float BTa[1056], BTb[1056], Ka[1056], Kb[1056];
  __shared__ float JT[1056], W1T[1056], Tk[1056], Xl[1056];
  __shared__ float mtwl[1056], Mtpl[1056], Eml[1056];
  const int tid = threadIdx.x, c = blockIdx.x;      // c = 0..30
  const int t1 = 16*c + 1, t2 = 16*c + 16;
  const int j = tid & 31, r0 = tid >> 5;
  stage_mat(mtw, mtwl, tid);
  stage_mat(ws + WS_MTP, Mtpl, tid);
  stage_mat(ws + WS_EM, Eml, tid);
  stage_mat(ws + WS_X + t1*1024, Xl, tid);
  stage_matT(ws + WS_X + t1*1024, BTa, tid);        // BT = X_{t1}^T
  __syncthreads();
  mm_rr_mI(Xl, mtwl, JT, tid);  __syncthreads();
  mm_rr(JT, Mtpl, W1T, tid);    __syncthreads();
#pragma unroll
  for (int m = 0; m < 4; ++m) {
    const int ri = r0 + 8*m;
    float s = 0.f;
    for (int k = 0; k < 32; ++k) s += W1T[ri*33+k] * JT[j*33+k];
    Ka[ri*33+j] = Eml[ri*33+j] - 0.5f * s;
  }
  __syncthreads();
  float *BTc = BTa, *BTn = BTb, *Kc = Ka, *Kn = Kb;
  for (int t = t1 + 1; t <= t2; ++t) {
    stage_mat(ws + WS_X + t*1024, Xl, tid);
    __syncthreads();
    mm_rr_mI(Xl, mtwl, JT, tid);       // J^T for K_t
    mm_rr(BTc, Xl, BTn, tid);          // BT' = BT @ X_t^T
    mm_rr(Xl, Kc, Tk, tid);            // Tk = X@K (K sym)
    __syncthreads();
    mm_rr(JT, Mtpl, W1T, tid);
    mm_rr(Tk, Xl, Kn, tid);            // X K X^T
    __syncthreads();
#pragma unroll
    for (int m = 0; m < 4; ++m) {
      const int ri = r0 + 8*m;
      float s = 0.f;
      for (int k = 0; k < 32; ++k) s += W1T[ri*33+k] * JT[j*33+k];
      Kn[ri*33+j] += Eml[ri*33+j] - 0.5f * s;
    }
    __syncthreads();
    float* tp = BTc; BTc = BTn; BTn = tp;
    tp = Kc; Kc = Kn; Kn = tp;
  }
  // write to CE_A[c+1] (shift for exclusive prefix)
  {
    const int r = tid >> 3, cc = (tid & 7) * 4;
    float* dst = ws + WS_CEA + (c+1)*2048;
    float4 v = make_float4(BTc[r*33+cc], BTc[r*33+cc+1], BTc[r*33+cc+2], BTc[r*33+cc+3]);
    *(float4*)(dst + r*32 + cc) = v;
    float4 w = make_float4(Kc[r*33+cc], Kc[r*33+cc+1], Kc[r*33+cc+2], Kc[r*33+cc+3]);
    *(float4*)(dst + 1024 + r*32 + cc) = w;
  }
}

// ---------------- S-scan doubling level ----------------
__global__ __launch_bounds__(256) void ks_level(float* __restrict__ ws,
                                                int inoff, int outoff, int step) {
  const int c = blockIdx.x, tid = threadIdx.x;
  const float* in = ws + inoff;
  float* out = ws + outoff;
  if (c < step) {
    const int base = c*2048 + tid*8;
#pragma unroll
    for (int x = 0; x < 8; ++x) out[base + x] = in[base + x];
    return;
  }
  __shared__ float BTo[1056], Ko[1056], BTn[1056], tmp[1056], BTr[1056];
  stage_mat(in + (c-step)*2048, BTo, tid);
  stage_mat(in + (c-step)*2048 + 1024, Ko, tid);
  stage_mat(in + c*2048, BTn, tid);
  __syncthreads();
  mm_p(BTo, BTn, BTr, tid);   // BT' = BT_old @ BT_new
  mm_p(Ko, BTn, tmp, tid);    // tmp = K_old @ B_new^T
  __syncthreads();
  const int j = tid & 31, r0 = tid >> 5;
#pragma unroll
  for (int m = 0; m < 4; ++m) {
    const int ri = r0 + 8*m;
    float s = 0.f;
    for (int k = 0; k < 32; ++k) s += BTn[k*33+ri] * tmp[k*33+j];  // B_new @ tmp
    out[c*2048 + ri*32 + j] = BTr[ri*33+j];
    out[c*2048 + 1024 + ri*32 + j] = s + in[c*2048 + 1024 + ri*32 + j];
  }
}

// ---------------- K_S-C: expand chunks + trace terms ----------------
__global__ __launch_bounds__(256) void ksc(const float* __restrict__ mtw,
                                           float* __restrict__ ws) {
  __shared__ float S[1056], S2[1056], JT[1056], W1T[1056], T1[1056];
  __shared__ float Xl[1056], Bcl[1056], BTP[1056];
  __shared__ float Mtpl[1056], Eml[1056], TQl[1056], mtwl[1056];
  __shared__ float red[4];
  const int tid = threadIdx.x, c = blockIdx.x;
  const int j = tid & 31, r0 = tid >> 5;
  stage_mat(mtw, mtwl, tid);
  stage_mat(ws + WS_MTP, Mtpl, tid);
  stage_mat(ws + WS_EM, Eml, tid);
  stage_mat(ws + WS_TQ, TQl, tid);
  stage_mat(ws + WS_CEB + c*2048, BTP, tid);
  stage_mat(ws + WS_S1, S2, tid);      // S0
  __syncthreads();
  mm_p(S2, BTP, T1, tid);              // T1 = S0 @ B_P^T
  __syncthreads();
#pragma unroll
  for (int m = 0; m < 4; ++m) {        // S_start = B_P @ T1 + K_P
    const int ri = r0 + 8*m;
    float s = 0.f;
    for (int k = 0; k < 32; ++k) s += BTP[k*33+ri] * T1[k*33+j];
    S[ri*33+j] = s + ws[WS_CEB + c*2048 + 1024 + ri*32 + j];
  }
  __syncthreads();
  double accd = 0.0;
  for (int i = 0; i < 16; ++i) {
    const int t = 16*c + 1 + i;
    if (t >= TT) break;
    stage_mat(ws + WS_X + t*1024, Xl, tid);
    stage_mat(ws + WS_BCOV + t*1024, Bcl, tid);
    __syncthreads();
    mm_rr_mI(Xl, mtwl, JT, tid);
    mm_rr(Xl, S, T1, tid);             // T1 = X @ S
    float part = 0.f;
#pragma unroll
    for (int m = 0; m < 4; ++m) {      // trace((S - .5 TQ) @ bcov), bcov sym
      const int ri = r0 + 8*m;
      part += (S[ri*33+j] - 0.5f*TQl[ri*33+j]) * Bcl[ri*33+j];
    }
    const float r2 = block_reduce(part, red, tid);
    if (tid == 0) accd += (double)r2;
    mm_rr(JT, Mtpl, W1T, tid);
    mm_rr(T1, Xl, S2, tid);            // X S X^T
    __syncthreads();
#pragma unroll
    for (int m = 0; m < 4; ++m) {
      const int ri = r0 + 8*m;
      float s = 0.f;
      for (int k = 0; k < 32; ++k) s += W1T[ri*33+k] * JT[j*33+k];
      S[ri*33+j] = S2[ri*33+j] + Eml[ri*33+j] - 0.5f * s;
    }
    __syncthreads();
  }
  if (tid == 0) atomicAdd(((double*)(ws + WS_DACC)) + 2, accd);
}

// ---------------- K_G-A: compose affine suffix maps within each chunk ----------------
__global__ __launch_bounds__(256) void kga(float* __restrict__ ws) {
  __shared__ float ATa[1056], ATb[1056], XTl[1056];
  __shared__ float bb[2][32];
  const int tid = threadIdx.x, c = blockIdx.x + 1;  // c = 1..31
  const int t1 = 16*c + 1;
  const int t2 = (16*c + 16 < TT) ? 16*c + 16 : TT - 1;
  stage_mat(ws + WS_X + t2*1024, ATa, tid);         // AT = bA_{t2}^T = X_{t2}
  if (tid < 32) bb[0][tid] = ws[WS_BA + t2*32 + tid];
  __syncthreads();
  float *ATc = ATa, *ATn = ATb;
  int pb = 0;
  for (int t = t2 - 1; t >= t1; --t) {
    stage_matT(ws + WS_X + t*1024, XTl, tid);
    __syncthreads();
    mm_rr(ATc, XTl, ATn, tid);                      // AT' = AT @ X_t
    if (tid < 32) {
      float s = ws[WS_BA + t*32 + tid];
      for (int k = 0; k < 32; ++k) s += XTl[tid*33+k] * bb[pb][k];
      bb[pb^1][tid] = s;
    }
    __syncthreads();
    float* tp = ATc; ATc = ATn; ATn = tp; pb ^= 1;
  }
  {
    const int r = tid >> 3, cc = (tid & 7) * 4;
    float* dst = ws + WS_GEA + (c-1)*1056;
    float4 v = make_float4(ATc[r*33+cc], ATc[r*33+cc+1], ATc[r*33+cc+2], ATc[r*33+cc+3]);
    *(float4*)(dst + r*32 + cc) = v;
    if (tid < 32) dst[1024 + tid] = bb[pb][tid];
  }
}

// ---------------- G-scan doubling level (suffix) ----------------
__global__ __launch_bounds__(256) void kg_level(float* __restrict__ ws,
                                                int inoff, int outoff, int step) {
  const int c = blockIdx.x, tid = threadIdx.x;
  const float* in = ws + inoff;
  float* out = ws + outoff;
  if (c + step > 31) {
    const int base = c*1056;
    const int e = tid*4;
#pragma unroll
    for (int x = 0; x < 4; ++x) out[base + e + x] = in[base + e + x];
    if (tid < 32) out[base + 1024 + tid] = in[base + 1024 + tid];
    return;
  }
  __shared__ float AT1[1056], AT2[1056], ATr[1056];
  __shared__ float b2l[32];
  stage_mat(in + c*1056, AT1, tid);
  stage_mat(in + (c+step)*1056, AT2, tid);
  if (tid < 32) b2l[tid] = in[(c+step)*1056 + 1024 + tid];
  __syncthreads();
  mm_p(AT2, AT1, ATr, tid);           // AT' = AT_later @ AT_earlier
  if (tid < 32) {
    float s = in[c*1056 + 1024 + tid];
    for (int k = 0; k < 32; ++k) s += AT1[k*33+tid] * b2l[k];   // A1 @ b2 + b1
    out[c*1056 + 1024 + tid] = s;
  }
  __syncthreads();
  {
    const int j = tid & 31, r0 = tid >> 5;
#pragma unroll
    for (int m = 0; m < 4; ++m) {
      const int ri = r0 + 8*m;
      out[c*1056 + ri*32 + j] = ATr[ri*33+j];
    }
  }
}

// ---------------- K_G-B: expand suffix + evaluate final per-s terms ----------------
__global__ __launch_bounds__(256) void kgb(
    const float* __restrict__ obs, const float* __restrict__ mpm,
    const float* __restrict__ mtw, const float* __restrict__ mtb,
    const float* __restrict__ mew, const float* __restrict__ meb,
    float* __restrict__ ws) {
  __shared__ float ATa[1056], ATb[1056], XTl[1056];
  __shared__ float Y1[1056], Y2[1056], Jb[1056], M2T[1056], E1[1056];
  __shared__ float mewl[1056], EmLl[1056], fPl[1056], Mtpl[1056], Mepl[1056], mtwl[1056];
  __shared__ float fml[32], mebl[32], mtbl[32], mpml[32], yl[32], bal[32];
  __shared__ float gv[32], cme[32], cmo[32], bv[2][32];
  __shared__ float red[4];
  const int tid = threadIdx.x, c = blockIdx.x;
  const int j = tid & 31, r0 = tid >> 5;
  stage_mat(mew, mewl, tid);
  stage_mat(ws + WS_EML, EmLl, tid);
  stage_mat(ws + WS_FPT, fPl, tid);
  stage_mat(ws + WS_MTP, Mtpl, tid);
  stage_mat(ws + WS_MEP, Mepl, tid);
  stage_mat(mtw, mtwl, tid);
  stage_mat(ws + WS_GEB + c*1056, ATa, tid);
  if (tid < 32) {
    fml[tid] = ws[WS_FMT + tid];
    mebl[tid] = meb[tid]; mtbl[tid] = mtb[tid]; mpml[tid] = mpm[tid];
    bv[0][tid] = ws[WS_GEB + c*1056 + 1024 + tid];
  }
  __syncthreads();
  float *ATc = ATa, *ATo = ATb;
  int bc = 0;
  double accd = 0.0;
  for (int s = 16*c + 15; s >= 16*c; --s) {
    // P0: stage
    if (s < TT-1) stage_matT(ws + WS_X + (s+1)*1024, XTl, tid);
    if (s == 0)   stage_mat(ws + WS_MPP, Jb, tid);   // Jb buffer repurposed = Mpp
    if (tid < 32) {
      yl[tid] = obs[s*32 + tid];
      if (s >= 1) bal[tid] = ws[WS_BA + s*32 + tid];
    }
    __syncthreads();
    // P1: D <- F_{s+1} o D
    if (s < TT-1) {
      mm_rr(ATc, XTl, ATo, tid);                 // AT' = AT @ X_{s+1}
      if (tid < 32) {
        float v = ws[WS_BA + (s+1)*32 + tid];
        for (int k = 0; k < 32; ++k) v += XTl[tid*33+k] * bv[bc][k];
        bv[bc^1][tid] = v;
      }
    }
    __syncthreads();
    const float* AT = (s < TT-1) ? ATo : ATc;    // = G(s)^T
    const float* bl = (s < TT-1) ? bv[bc^1] : bv[bc];
    // P2
    mm_rr(mewl, AT, Y1, tid);                    // Mb = mew@G
    mm_rr(EmLl, AT, Y2, tid);                    // Ub = EmL@G
    if (s >= 1) {                                // Jb = mtw@X_s^T - I, X_s from global
      const float* Xg = ws + WS_X + s*1024;
      float s0 = 0.f, s1 = 0.f, s2 = 0.f, s3 = 0.f;
      for (int k = 0; k < 32; ++k) {
        const float b = Xg[j*32 + k];
        s0 += mtwl[(r0     )*33+k] * b;
        s1 += mtwl[(r0 +  8)*33+k] * b;
        s2 += mtwl[(r0 + 16)*33+k] * b;
        s3 += mtwl[(r0 + 24)*33+k] * b;
      }
      Jb[(r0     )*33+j] = s0 - ((r0      == j) ? 1.f : 0.f);
      Jb[(r0 +  8)*33+j] = s1 - ((r0 +  8 == j) ? 1.f : 0.f);
      Jb[(r0 + 16)*33+j] = s2 - ((r0 + 16 == j) ? 1.f : 0.f);
      Jb[(r0 + 24)*33+j] = s3 - ((r0 + 24 == j) ? 1.f : 0.f);
    }
    if (tid < 32) {
      float g = bl[tid];
      for (int k = 0; k < 32; ++k) g += AT[k*33+tid] * fml[k];
      gv[tid] = g;                               // g = G@fm + h
    }
    __syncthreads();
    // P3
    if (s >= 1) mm_rr(AT, Jb, M2T, tid);         // M2^T = GT @ Jb^T-rowrow
    if (tid < 32) {
      float s1 = mebl[tid] - yl[tid];
      for (int k = 0; k < 32; ++k) s1 += mewl[tid*33+k] * gv[k];
      cme[tid] = s1;
      float s2;
      if (s >= 1) {
        s2 = mtbl[tid];
        for (int k = 0; k < 32; ++k)
          s2 += Jb[tid*33+k] * gv[k] + mtwl[tid*33+k] * bal[k];
      } else {
        s2 = gv[tid] - mpml[tid];
      }
      cmo[tid] = s2;
    }
    __syncthreads();
    const float* M2Tp = (s >= 1) ? M2T : AT;     // s=0: M2 = G
    const float* Mqp  = (s >= 1) ? Mtpl : Jb;    // s=0: Jb holds Mpp
    // P4: E1 = Mq @ M2  (rowrow with M2T)
    mm_rr(Mqp, M2Tp, E1, tid);
    __syncthreads();
    // P5: fused reductions
    float part = 0.f;
#pragma unroll
    for (int m = 0; m < 4; ++m) {
      const int ri = r0 + 8*m;
      // term1: Y3[ri][j]*Y1[j][ri], Y3 = Y2@fP (rowrow inline)
      float y3 = 0.f, e2 = 0.f;
      for (int k = 0; k < 32; ++k) {
        y3 += Y2[ri*33+k] * fPl[j*33+k];
        e2 += fPl[j*33+k] * M2Tp[ri*33+k];       // E2[j][ri] = (fP@M2)[j][ri]
      }
      part += y3 * Y1[j*33+ri]
            - 0.5f * E1[ri*33+j] * e2
            - 0.5f * cme[ri] * Mepl[ri*33+j] * cme[j]
            - 0.5f * cmo[ri] * Mqp[ri*33+j] * cmo[j];
    }
    const float r2 = block_reduce(part, red, tid);
    if (tid == 0) accd += (double)r2;
    if (s < TT-1) { float* tp = ATc; ATc = ATo; ATo = tp; bc ^= 1; }
    __syncthreads();
  }
  if (tid == 0) atomicAdd(((double*)(ws + WS_DACC)) + 3, accd);
}

// ---------------- Kout ----------------
__global__ __launch_bounds__(64) void kout(const float* __restrict__ ws,
                                           float* __restrict__ out) {
  if (threadIdx.x == 0) {
    const double* d = (const double*)(ws + WS_DACC);
    out[0] = (float)(d[0] + d[1] + d[2] + d[3]);
  }
}

extern "C" void kernel_launch(void* const* d_in, const int* in_sizes, int n_in,
                              void* d_out, int out_size, void* d_ws, size_t ws_size,
                              hipStream_t stream) {
  (void)in_sizes; (void)n_in; (void)out_size; (void)ws_size;
  const float* obs = (const float*)d_in[0];
  const float* mpm = (const float*)d_in[1];
  const float* mpc = (const float*)d_in[2];
  const float* mtw = (const float*)d_in[3];
  const float* mtb = (const float*)d_in[4];
  const float* mtc = (const float*)d_in[5];
  const float* mew = (const float*)d_in[6];
  const float* meb = (const float*)d_in[7];
  const float* mec = (const float*)d_in[8];
  const float* vpm = (const float*)d_in[9];
  const float* vpc = (const float*)d_in[10];
  const float* vtw = (const float*)d_in[11];
  const float* vtb = (const float*)d_in[12];
  const float* vtc = (const float*)d_in[13];
  const float* vew = (const float*)d_in[14];
  const float* veb = (const float*)d_in[15];
  const float* vcc = (const float*)d_in[16];
  float* ws  = (float*)d_ws;
  float* out = (float*)d_out;

  k0_init<<<1, 256, 0, stream>>>(ws);
  k1_invert<<<6, 256, 0, stream>>>(mtc, mec, mpc, vtc, vcc, vpc, ws);
  k2_derived<<<1, 256, 0, stream>>>(obs, vpm, vtw, vtb, vew, veb, mtw, mew, ws);
  k3_yt<<<TT/8, 256, 0, stream>>>(obs, veb, ws);
  k4min<<<1, 256, 0, stream>>>(ws);

  // S-machinery: chunk compose -> exclusive prefix scan -> expand+trace
  ksa<<<31, 256, 0, stream>>>(mtw, ws);
  ks_level<<<32, 256, 0, stream>>>(ws, WS_CEA, WS_CEB, 1);
  ks_level<<<32, 256, 0, stream>>>(ws, WS_CEB, WS_CEA, 2);
  ks_level<<<32, 256, 0, stream>>>(ws, WS_CEA, WS_CEB, 4);
  ks_level<<<32, 256, 0, stream>>>(ws, WS_CEB, WS_CEA, 8);
  ks_level<<<32, 256, 0, stream>>>(ws, WS_CEA, WS_CEB, 16);
  ksc<<<32, 256, 0, stream>>>(mtw, ws);

  // G-machinery: chunk compose -> suffix scan -> expand + final terms
  kga<<<31, 256, 0, stream>>>(ws);
  kg_level<<<32, 256, 0, stream>>>(ws, WS_GEA, WS_GEB, 1);
  kg_level<<<32, 256, 0, stream>>>(ws, WS_GEB, WS_GEA, 2);
  kg_level<<<32, 256, 0, stream>>>(ws, WS_GEA, WS_GEB, 4);
  kg_level<<<32, 256, 0, stream>>>(ws, WS_GEB, WS_GEA, 8);
  kg_level<<<32, 256, 0, stream>>>(ws, WS_GEA, WS_GEB, 16);
  kgb<<<32, 256, 0, stream>>>(obs, mpm, mtw, mtb, mew, meb, ws);

  kout<<<1, 64, 0, stream>>>(ws, out);
}

// Round 3
// 1258.063 us; speedup vs baseline: 27.0565x; 4.8854x over previous
//
#include <hip/hip_runtime.h>
#include <math.h>

#define TT 512
#define LOG2PI 1.8378770664093453

// ---------------- workspace layout (float offsets) ----------------
enum : int {
  WS_X     = 0,                    // [TT][32][32] X_t = QiW@bcov_t (bA_t = X^T), t=1..511
  WS_BCOV  = WS_X    + TT*1024,    // [TT][32][32] bcov_t
  WS_BA    = WS_BCOV + TT*1024,    // [TT][32] ba_t
  WS_YT    = WS_BA   + TT*32,      // [TT][32] Wt = HtRi@(y_t-veb) + qivtb - ctb
  WS_MTP   = WS_YT   + TT*32,      // inv(m_trans_cov)
  WS_MEP   = WS_MTP + 1024,
  WS_MPP   = WS_MEP + 1024,
  WS_QI    = WS_MPP + 1024,
  WS_RI    = WS_QI  + 1024,
  WS_P0I   = WS_RI  + 1024,
  WS_QIW   = WS_P0I + 1024,        // Qi@vtw
  WS_CW    = WS_QIW + 1024,        // vtw^T Qi vtw
  WS_HTRI  = WS_CW  + 1024,
  WS_HTRIH = WS_HTRI+ 1024,
  WS_TQ    = WS_HTRIH+1024,        // mtw^T Mtp mtw
  WS_EM    = WS_TQ  + 1024,        // -0.5 mew^T Mep mew
  WS_EML   = WS_EM  + 1024,        // -0.5 Mep mew
  WS_LAM0CW= WS_EML + 1024,        // P0i + HtRiH + CW  (= Z_1)
  WS_QHC   = WS_LAM0CW + 1024,     // Qi + HtRiH + CW
  WS_S1    = WS_QHC + 1024,        // S_0 = Em - 0.5 Mpp
  WS_FPT   = WS_S1  + 1024,        // final fP (also K2 temp)
  WS_ETA0  = WS_FPT + 1024,
  WS_CTB   = WS_ETA0+ 32,          // QiW^T vtb
  WS_QIVTB = WS_CTB + 32,          // Qi vtb
  WS_FMT   = WS_QIVTB + 32,        // final fm
  WS_LDS3  = WS_FMT + 32,          // 3 logdets + pad
  WS_DACC  = WS_LDS3 + 4,          // 4 doubles: const, logdets, S-traces, finals
  WS_ETAF  = WS_DACC + 8,          // eta_{511}
  WS_CEA   = WS_ETAF + 32,         // 32*2048: S-scan ping; also eta-scan ping (1056-stride)
  WS_CEB   = WS_CEA + 32*2048,     // S-scan pong; eta-scan pong; aliases ZB/Z512 (see below)
  WS_GEA   = WS_CEB + 32*2048,     // 32 x (AT 1024 + b 32): G-scan ping
  WS_GEB   = WS_GEA + 32*1056,
  WS_END   = WS_GEB + 32*1056
};
// Aliases inside CEB (consumed by kr_exp/kfin BEFORE eta-scan / S-scan write CEB):
enum : int {
  WS_ZB   = WS_CEB,            // 32 x 1024 chunk-boundary Z_{16c+1}
  WS_Z512 = WS_CEB + 34816     // Z_512 (beyond eta-slot region 32*1056=33792)
};
static_assert(WS_DACC % 2 == 0, "double alignment");

// ---------------- helpers ----------------
__device__ __forceinline__ float rlane(float v, int l) {
  return __uint_as_float(__builtin_amdgcn_readlane(__float_as_uint(v), l));
}

// single-wave register Gauss-Jordan: lane c holds augmented column c in a[0..31].
// lanes>=32 end with inverse column (lane-32). returns det (pivot product).
__device__ __forceinline__ double gj_inv32(float a[32]) {
  double pp = 1.0;
#pragma unroll
  for (int p = 0; p < 32; ++p) {
    const float piv = rlane(a[p], p);
    pp *= (double)piv;
    const float sc = a[p] * (1.0f / piv);
#pragma unroll
    for (int r = 0; r < 32; ++r) {
      if (r != p) a[r] -= rlane(a[r], p) * sc;
    }
    a[p] = sc;
  }
  return pp;
}

__device__ __forceinline__ float block_reduce(float v, float* red, int tid) {
#pragma unroll
  for (int m = 32; m >= 1; m >>= 1) v += __shfl_xor(v, m, 64);
  if ((tid & 63) == 0) red[tid >> 6] = v;
  __syncthreads();
  return red[0] + red[1] + red[2] + red[3];
}

// global row-major 32x32 -> LDS stride-33
__device__ __forceinline__ void stage_mat(const float* __restrict__ g, float* L, int tid) {
  const int r = tid >> 3, c = (tid & 7) * 4;
  const float4 v = *(const float4*)(g + r*32 + c);
  L[r*33+c] = v.x; L[r*33+c+1] = v.y; L[r*33+c+2] = v.z; L[r*33+c+3] = v.w;
}
// transposed stage: L[c][r] = g[r][c]
__device__ __forceinline__ void stage_matT(const float* __restrict__ g, float* L, int tid) {
  const int r = tid >> 3, c = (tid & 7) * 4;
  const float4 v = *(const float4*)(g + r*32 + c);
  L[(c  )*33+r] = v.x; L[(c+1)*33+r] = v.y; L[(c+2)*33+r] = v.z; L[(c+3)*33+r] = v.w;
}
// LDS stride-33 -> global row-major
__device__ __forceinline__ void destage_mat(const float* L, float* __restrict__ g, int tid) {
  const int r = tid >> 3, c = (tid & 7) * 4;
  float4 v = make_float4(L[r*33+c], L[r*33+c+1], L[r*33+c+2], L[r*33+c+3]);
  *(float4*)(g + r*32 + c) = v;
}

// C = A @ B^T (row-row), all LDS stride 33
__device__ __forceinline__ void mm_rr(const float* A, const float* B, float* C, int tid) {
  const int j = tid & 31, r0 = tid >> 5;
#pragma unroll
  for (int m = 0; m < 4; ++m) {
    const int ri = r0 + 8*m;
    float s = 0.f;
    for (int k = 0; k < 32; ++k) s += A[ri*33+k] * B[j*33+k];
    C[ri*33+j] = s;
  }
}
// C = A @ B^T - I
__device__ __forceinline__ void mm_rr_mI(const float* A, const float* B, float* C, int tid) {
  const int j = tid & 31, r0 = tid >> 5;
#pragma unroll
  for (int m = 0; m < 4; ++m) {
    const int ri = r0 + 8*m;
    float s = 0.f;
    for (int k = 0; k < 32; ++k) s += A[ri*33+k] * B[j*33+k];
    C[ri*33+j] = s - ((ri == j) ? 1.f : 0.f);
  }
}
// C = A @ B (plain)
__device__ __forceinline__ void mm_p(const float* A, const float* B, float* C, int tid) {
  const int j = tid & 31, r0 = tid >> 5;
#pragma unroll
  for (int m = 0; m < 4; ++m) {
    const int ri = r0 + 8*m;
    float s = 0.f;
    for (int k = 0; k < 32; ++k) s += A[ri*33+k] * B[k*33+j];
    C[ri*33+j] = s;
  }
}
// C = A^T @ B
__device__ __forceinline__ void mm_tp(const float* A, const float* B, float* C, int tid) {
  const int j = tid & 31, r0 = tid >> 5;
#pragma unroll
  for (int m = 0; m < 4; ++m) {
    const int ri = r0 + 8*m;
    float s = 0.f;
    for (int k = 0; k < 32; ++k) s += A[k*33+ri] * B[k*33+j];
    C[ri*33+j] = s;
  }
}

// legacy LDS GJ for K1 (verified in R1)
__device__ __forceinline__ double gj_pivots(float* aug, int tid) {
  const int j = tid & 31, r0 = tid >> 5;
  double pp = 1.0;
  for (int p = 0; p < 32; ++p) {
    float* Abuf = aug + (p & 1) * 2080;
    float* Bbuf = aug + ((p & 1) ^ 1) * 2080;
    const float piv = Abuf[p*65 + p];
    pp *= (double)piv;
    const float ip = 1.0f / piv;
    const float apj0 = Abuf[p*65 + j] * ip;
    const float apj1 = Abuf[p*65 + 32 + j] * ip;
#pragma unroll
    for (int m = 0; m < 4; ++m) {
      const int ri = r0 + 8*m;
      const float aip = Abuf[ri*65 + p];
      if (ri == p) {
        Bbuf[ri*65 + j]      = apj0;
        Bbuf[ri*65 + 32 + j] = apj1;
      } else {
        Bbuf[ri*65 + j]      = Abuf[ri*65 + j]      - aip * apj0;
        Bbuf[ri*65 + 32 + j] = Abuf[ri*65 + 32 + j] - aip * apj1;
      }
    }
    __syncthreads();
  }
  return pp;
}

// ---------------- K0: init accumulators + scan identities ----------------
__global__ __launch_bounds__(256) void k0_init(float* __restrict__ ws) {
  const int tid = threadIdx.x;
  if (tid == 0) {
    double* d = (double*)(ws + WS_DACC);
    d[1] = 0.0; d[2] = 0.0; d[3] = 0.0;
  }
  // eta-scan slot0 identity in CEA (1056-stride: A=I, b=0)
  for (int e = tid; e < 1056; e += 256)
    ws[WS_CEA + e] = (e < 1024 && ((e >> 5) == (e & 31))) ? 1.f : 0.f;
  // G-scan slot31 identity in GEA
  const int idx = tid * 4;
#pragma unroll
  for (int x = 0; x < 4; ++x) {
    const int e = idx + x, r = e >> 5, c = e & 31;
    ws[WS_GEA + 31*1056 + e] = (r == c) ? 1.f : 0.f;
  }
  if (tid < 32) ws[WS_GEA + 31*1056 + 1024 + tid] = 0.f;
}

// ---------------- K1: invert the 6 constant SPD matrices ----------------
__global__ __launch_bounds__(256) void k1_invert(
    const float* __restrict__ mtc, const float* __restrict__ mec,
    const float* __restrict__ mpc, const float* __restrict__ vtc,
    const float* __restrict__ vcc, const float* __restrict__ vpc,
    float* __restrict__ ws) {
  __shared__ float aug[2*2080];
  const int tid = threadIdx.x, j = tid & 31, r0 = tid >> 5;
  const float* src; float* dst; int lds = -1;
  switch (blockIdx.x) {
    case 0: src = mtc; dst = ws + WS_MTP; lds = 0; break;
    case 1: src = mec; dst = ws + WS_MEP; lds = 1; break;
    case 2: src = mpc; dst = ws + WS_MPP; lds = 2; break;
    case 3: src = vtc; dst = ws + WS_QI;  break;
    case 4: src = vcc; dst = ws + WS_RI;  break;
    default: src = vpc; dst = ws + WS_P0I; break;
  }
#pragma unroll
  for (int m = 0; m < 4; ++m) {
    const int ri = r0 + 8*m;
    aug[ri*65 + j] = src[ri*32 + j];
    aug[ri*65 + 32 + j] = (ri == j) ? 1.f : 0.f;
  }
  __syncthreads();
  double pp = gj_pivots(aug, tid);
#pragma unroll
  for (int m = 0; m < 4; ++m) {
    const int ri = r0 + 8*m;
    dst[ri*32 + j] = aug[ri*65 + 32 + j];
  }
  if (tid == 0 && lds >= 0) ws[WS_LDS3 + lds] = (float)log(pp);
}

// ---------------- K2: derived constants + analytic constant (double) ----------------
__global__ __launch_bounds__(256) void k2_derived(
    const float* __restrict__ obs, const float* __restrict__ vpm,
    const float* __restrict__ vtw, const float* __restrict__ vtb,
    const float* __restrict__ vew, const float* __restrict__ veb,
    const float* __restrict__ mtw, const float* __restrict__ mew,
    float* __restrict__ ws) {
  const int tid = threadIdx.x, j = tid & 31, r0 = tid >> 5;
#pragma unroll
  for (int m = 0; m < 4; ++m) {
    const int ri = r0 + 8*m;
    float s1 = 0.f, s2 = 0.f, s3 = 0.f, s4 = 0.f;
    for (int k = 0; k < 32; ++k) {
      s1 += ws[WS_QI  + ri*32 + k] * vtw[k*32 + j];
      s2 += vew[k*32 + ri] * ws[WS_RI + k*32 + j];
      s3 += ws[WS_MTP + ri*32 + k] * mtw[k*32 + j];
      s4 += ws[WS_MEP + ri*32 + k] * mew[k*32 + j];
    }
    ws[WS_QIW + ri*32 + j] = s1;
    ws[WS_HTRI + ri*32 + j] = s2;
    ws[WS_FPT + ri*32 + j] = s3;      // temp Mtp@mtw
    ws[WS_EML + ri*32 + j] = -0.5f * s4;
  }
  __syncthreads();
#pragma unroll
  for (int m = 0; m < 4; ++m) {
    const int ri = r0 + 8*m;
    float s1 = 0.f, s2 = 0.f, s3 = 0.f, s4 = 0.f;
    for (int k = 0; k < 32; ++k) {
      s1 += vtw[k*32 + ri] * ws[WS_QIW + k*32 + j];
      s2 += ws[WS_HTRI + ri*32 + k] * vew[k*32 + j];
      s3 += mtw[k*32 + ri] * ws[WS_FPT + k*32 + j];
      s4 += mew[k*32 + ri] * ws[WS_EML + k*32 + j];
    }
    ws[WS_CW + ri*32 + j] = s1;
    ws[WS_HTRIH + ri*32 + j] = s2;
    ws[WS_LAM0CW + ri*32 + j] = ws[WS_P0I + ri*32 + j] + s1 + s2;
    ws[WS_QHC    + ri*32 + j] = ws[WS_QI  + ri*32 + j] + s1 + s2;
    ws[WS_TQ + ri*32 + j] = s3;
    ws[WS_EM + ri*32 + j] = s4;
    ws[WS_S1 + ri*32 + j] = s4 - 0.5f * ws[WS_MPP + ri*32 + j];
  }
  if (tid < 32) {
    float s1 = 0.f, s2 = 0.f, s3 = 0.f;
    for (int k = 0; k < 32; ++k) {
      s1 += ws[WS_QIW + k*32 + tid] * vtb[k];
      s2 += ws[WS_P0I + tid*32 + k] * vpm[k]
          + ws[WS_HTRI + tid*32 + k] * (obs[k] - veb[k]);
      s3 += ws[WS_QI + tid*32 + k] * vtb[k];
    }
    ws[WS_CTB + tid] = s1;
    ws[WS_ETA0 + tid] = s2;
    ws[WS_QIVTB + tid] = s3;
  }
  __syncthreads();
  if (tid == 0) {
    const double ldmt = (double)ws[WS_LDS3 + 0];
    const double ldme = (double)ws[WS_LDS3 + 1];
    const double ldmp = (double)ws[WS_LDS3 + 2];
    const double ct_me = -0.5 * (32.0 * LOG2PI + ldme);
    const double ct_mt = -0.5 * (32.0 * LOG2PI + ldmt);
    const double ct_mp = -0.5 * (32.0 * LOG2PI + ldmp);
    double c = ct_mp + ct_me;
    c += (double)(TT - 1) * (ct_me + ct_mt + 0.5 * 32.0 * LOG2PI + 16.0);
    c += 0.5 * 32.0 * LOG2PI + 16.0;
    ((double*)(ws + WS_DACC))[0] = c;
  }
}

// ---------------- K3: Wt[t] = HtRi@(y_t - veb) + qivtb - ctb ----------------
__global__ __launch_bounds__(256) void k3_yt(const float* __restrict__ obs,
                                             const float* __restrict__ veb,
                                             float* __restrict__ ws) {
  const int tid = threadIdx.x, i = tid & 31, lt = tid >> 5;
  const int t = blockIdx.x * 8 + lt;
  float s = ws[WS_QIVTB + i] - ws[WS_CTB + i];
  for (int k = 0; k < 32; ++k)
    s += ws[WS_HTRI + i*32 + k] * (obs[t*32 + k] - veb[k]);
  ws[WS_YT + t*32 + i] = s;
}

// ---------------- KR_seq: doubling of Phi + 31 boundary applications ----------------
// Phi(Z) = K - A (Z+G)^-1 A^T ; E1 = (QHC, QiW, 0); compose:
//   M = K1+G2 ; K' = K2 - A2 M^-1 A2^T ; A' = A2 M^-1 A1 ; G' = G1 - A1^T M^-1 A1
__global__ __launch_bounds__(256) void kr_seq(float* __restrict__ ws) {
  __shared__ float Ka[1056], Kb[1056], Aa[1056], Ab[1056], Ga[1056], Gb[1056];
  __shared__ float Mi[1056], V1[1056], Wm[1056], Zl[1056];
  const int tid = threadIdx.x, lane = tid & 63, wv = tid >> 6;
  const int j = tid & 31, r0 = tid >> 5;
  stage_mat(ws + WS_QHC, Ka, tid);
  stage_mat(ws + WS_QIW, Aa, tid);
  for (int e = tid; e < 1056; e += 256) Ga[e] = 0.f;
  __syncthreads();
  float *Kc=Ka, *Kn=Kb, *Ac=Aa, *An=Ab, *Gc=Ga, *Gn=Gb;
  for (int d = 0; d < 4; ++d) {        // E2, E4, E8, E16
    for (int e = tid; e < 1056; e += 256) Mi[e] = Kc[e] + Gc[e];
    __syncthreads();
    if (wv == 0) {
      float a[32]; const int cc = lane & 31;
#pragma unroll
      for (int r = 0; r < 32; ++r)
        a[r] = (lane < 32) ? Mi[r*33 + cc] : ((r == lane - 32) ? 1.f : 0.f);
      gj_inv32(a);
      if (lane >= 32) {
        const int c2 = lane - 32;
#pragma unroll
        for (int r = 0; r < 32; ++r) Mi[r*33 + c2] = a[r];
      }
    }
    __syncthreads();
    mm_rr(Ac, Mi, V1, tid);   // A M^-1   (M^-1 symmetric)
    mm_tp(Ac, Mi, Wm, tid);   // A^T M^-1
    __syncthreads();
#pragma unroll
    for (int m = 0; m < 4; ++m) {
      const int ri = r0 + 8*m;
      float s1 = 0.f, s2 = 0.f, s3 = 0.f;
      for (int k = 0; k < 32; ++k) {
        const float v = V1[ri*33+k];
        s1 += v * Ac[j*33+k];           // V1 A^T
        s2 += v * Ac[k*33+j];           // V1 A
        s3 += Wm[ri*33+k] * Ac[k*33+j]; // W A
      }
      Kn[ri*33+j] = Kc[ri*33+j] - s1;
      An[ri*33+j] = s2;
      Gn[ri*33+j] = Gc[ri*33+j] - s3;
    }
    __syncthreads();
    float* tp;
    tp = Kc; Kc = Kn; Kn = tp;
    tp = Ac; Ac = An; An = tp;
    tp = Gc; Gc = Gn; Gn = tp;
  }
  // phase 2: chunk boundaries ZB[c] = Z_{16c+1}
  stage_mat(ws + WS_LAM0CW, Zl, tid);
  {  // ZB[0] = Z_1
    const int e = tid * 4;
    float4 v = *(const float4*)(ws + WS_LAM0CW + e);
    *(float4*)(ws + WS_ZB + e) = v;
  }
  __syncthreads();
  for (int c = 1; c < 32; ++c) {
    for (int e = tid; e < 1056; e += 256) Mi[e] = Zl[e] + Gc[e];
    __syncthreads();
    if (wv == 0) {
      float a[32]; const int cc = lane & 31;
#pragma unroll
      for (int r = 0; r < 32; ++r)
        a[r] = (lane < 32) ? Mi[r*33 + cc] : ((r == lane - 32) ? 1.f : 0.f);
      gj_inv32(a);
      if (lane >= 32) {
        const int c2 = lane - 32;
#pragma unroll
        for (int r = 0; r < 32; ++r) Mi[r*33 + c2] = a[r];
      }
    }
    __syncthreads();
    mm_rr(Ac, Mi, V1, tid);
    __syncthreads();
#pragma unroll
    for (int m = 0; m < 4; ++m) {
      const int ri = r0 + 8*m;
      float s = 0.f;
      for (int k = 0; k < 32; ++k) s += V1[ri*33+k] * Ac[j*33+k];
      const float zv = Kc[ri*33+j] - s;
      Zl[ri*33+j] = zv;
      ws[WS_ZB + c*1024 + ri*32 + j] = zv;
    }
    __syncthreads();
  }
}

// ---------------- KR_exp: expand chunks with exact per-step map ----------------
__global__ __launch_bounds__(256) void kr_exp(float* __restrict__ ws) {
  __shared__ float Zl[1056], Bcv[1056], Xs[1056], QiWl[1056], QHCl[1056];
  const int tid = threadIdx.x, lane = tid & 63, wv = tid >> 6;
  const int c = blockIdx.x;
  const int nst = (c == 31) ? 15 : 16;
  const int j = tid & 31, r0 = tid >> 5;
  stage_mat(ws + WS_QIW, QiWl, tid);
  stage_mat(ws + WS_QHC, QHCl, tid);
  stage_mat(ws + WS_ZB + c*1024, Zl, tid);
  __syncthreads();
  double acc = 0.0;
  for (int i = 0; i < nst; ++i) {
    const int t = 16*c + 1 + i;
    if (wv == 0) {
      float a[32]; const int cc = lane & 31;
#pragma unroll
      for (int r = 0; r < 32; ++r)
        a[r] = (lane < 32) ? Zl[r*33 + cc] : ((r == lane - 32) ? 1.f : 0.f);
      const double pp = gj_inv32(a);
      if (lane >= 32) {
        const int c2 = lane - 32;
#pragma unroll
        for (int r = 0; r < 32; ++r) {
          Bcv[r*33 + c2] = a[r];
          ws[WS_BCOV + t*1024 + r*32 + c2] = a[r];
        }
      }
      if (tid == 0) acc += -log(pp);
    }
    __syncthreads();
    mm_rr(QiWl, Bcv, Xs, tid);          // X = QiW @ bcov (bcov sym)
    __syncthreads();
    destage_mat(Xs, ws + WS_X + t*1024, tid);
#pragma unroll
    for (int m = 0; m < 4; ++m) {       // Z' = QHC - X @ QiW^T
      const int ri = r0 + 8*m;
      float s = 0.f;
      for (int k = 0; k < 32; ++k) s += Xs[ri*33+k] * QiWl[j*33+k];
      Zl[ri*33+j] = QHCl[ri*33+j] - s;
    }
    __syncthreads();
  }
  if (c == 31) destage_mat(Zl, ws + WS_Z512, tid);   // Z_512 = Lam_511 + CW
  if (tid == 0) atomicAdd(((double*)(ws + WS_DACC)) + 1, acc);
}

// ---------------- eta-scan: zeta_t = X_t zeta_{t-1} + Wt_t ----------------
// chunk compose (c = 0..30 -> slot c+1 in CEA, 1056-stride)
__global__ __launch_bounds__(256) void keta_a(float* __restrict__ ws) {
  __shared__ float Aa[1056], Ab[1056], Xl[1056];
  __shared__ float bb[2][32];
  const int tid = threadIdx.x, c = blockIdx.x;
  const int t1 = 16*c + 1;
  stage_mat(ws + WS_X + t1*1024, Aa, tid);
  if (tid < 32) bb[0][tid] = ws[WS_YT + t1*32 + tid];
  __syncthreads();
  float *Acur = Aa, *Anew = Ab; int pb = 0;
  for (int t = t1 + 1; t <= t1 + 15; ++t) {
    stage_mat(ws + WS_X + t*1024, Xl, tid);
    __syncthreads();
    mm_p(Xl, Acur, Anew, tid);
    if (tid < 32) {
      float s = ws[WS_YT + t*32 + tid];
      for (int k = 0; k < 32; ++k) s += Xl[tid*33+k] * bb[pb][k];
      bb[pb^1][tid] = s;
    }
    __syncthreads();
    float* tp = Acur; Acur = Anew; Anew = tp; pb ^= 1;
  }
  float* dst = ws + WS_CEA + (c+1)*1056;
  destage_mat(Acur, dst, tid);
  if (tid < 32) dst[1024 + tid] = bb[pb][tid];
}

// prefix-scan doubling level over 32 affine elements (1056-stride)
__global__ __launch_bounds__(256) void keta_lvl(float* __restrict__ ws,
                                                int inoff, int outoff, int step) {
  const int c = blockIdx.x, tid = threadIdx.x;
  const float* in = ws + inoff;
  float* out = ws + outoff;
  if (c < step) {
    for (int e = tid; e < 1056; e += 256) out[c*1056 + e] = in[c*1056 + e];
    return;
  }
  __shared__ float A1[1056], A0[1056], Ar[1056];
  __shared__ float b0l[32];
  stage_mat(in + c*1056, A1, tid);            // later
  stage_mat(in + (c-step)*1056, A0, tid);     // earlier
  if (tid < 32) b0l[tid] = in[(c-step)*1056 + 1024 + tid];
  __syncthreads();
  mm_p(A1, A0, Ar, tid);                      // A = A_later @ A_earlier
  if (tid < 32) {
    float s = in[c*1056 + 1024 + tid];
    for (int k = 0; k < 32; ++k) s += A1[tid*33+k] * b0l[k];
    out[c*1056 + 1024 + tid] = s;             // b = A_later b_earlier + b_later
  }
  __syncthreads();
  destage_mat(Ar, out + c*1056, tid);
}

// expand: per-t ba_t = bcov_t zeta_{t-1}; advance zeta; block31 stores eta_511
__global__ __launch_bounds__(256) void keta_b(float* __restrict__ ws) {
  __shared__ float Ap[1056], Bl[1056], Xl[1056];
  __shared__ float zeta[32], zn[32];
  const int tid = threadIdx.x, c = blockIdx.x;
  const int nst = (c == 31) ? 15 : 16;
  stage_mat(ws + WS_CEB + c*1056, Ap, tid);
  __syncthreads();
  if (tid < 32) {
    float s = ws[WS_CEB + c*1056 + 1024 + tid];
    for (int k = 0; k < 32; ++k)
      s += Ap[tid*33+k] * (ws[WS_ETA0 + k] - ws[WS_CTB + k]);
    zeta[tid] = s;                     // zeta_{16c}
  }
  __syncthreads();
  for (int i = 0; i < nst; ++i) {
    const int t = 16*c + 1 + i;
    stage_mat(ws + WS_BCOV + t*1024, Bl, tid);
    stage_mat(ws + WS_X + t*1024, Xl, tid);
    __syncthreads();
    if (tid < 32) {
      float s = 0.f;
      for (int k = 0; k < 32; ++k) s += Bl[tid*33+k] * zeta[k];
      ws[WS_BA + t*32 + tid] = s;      // ba_t = bcov_t zeta_{t-1}
    } else if (tid < 64) {
      const int i2 = tid - 32;
      float s = ws[WS_YT + t*32 + i2];
      for (int k = 0; k < 32; ++k) s += Xl[i2*33+k] * zeta[k];
      zn[i2] = s;
    }
    __syncthreads();
    if (tid < 32) zeta[tid] = zn[tid];
    __syncthreads();
  }
  if (c == 31 && tid < 32)
    ws[WS_ETAF + tid] = zeta[tid] + ws[WS_CTB + tid];   // eta_511
}

// ---------------- kfin: fP = inv(Z512 - CW), fm, logdet finalize ----------------
__global__ __launch_bounds__(64) void kfin(float* __restrict__ ws) {
  const int lane = threadIdx.x;
  float a[32]; const int cc = lane & 31;
#pragma unroll
  for (int r = 0; r < 32; ++r) {
    const float v = ws[WS_Z512 + r*32 + cc] - ws[WS_CW + r*32 + cc];
    a[r] = (lane < 32) ? v : ((r == lane - 32) ? 1.f : 0.f);
  }
  const double pp = gj_inv32(a);
  if (lane >= 32) {
    const int c2 = lane - 32;
    float fmv = 0.f;
#pragma unroll
    for (int r = 0; r < 32; ++r) {
      ws[WS_FPT + r*32 + c2] = a[r];
      fmv += a[r] * ws[WS_ETAF + r];   // fP symmetric
    }
    ws[WS_FMT + c2] = fmv;
  }
  if (lane == 0) {
    double* d = (double*)(ws + WS_DACC);
    d[1] = 0.5 * (d[1] + (-log(pp)));
  }
}

// ---------------- K_S-A: compose S-maps within each chunk ----------------
__global__ __launch_bounds__(256) void ksa(const float* __restrict__ mtw,
                                           float* __restrict__ ws) {
  __shared__ float BTa[1056], BTb[1056], Ka[1056], Kb[1056];
  __shared__ float JT[1056], W1T[1056], Tk[1056], Xl[1056];
  __shared__ float mtwl[1056], Mtpl[1056], Eml[1056];
  const int tid = threadIdx.x, c = blockIdx.x;      // c = 0..30
  const int t1 = 16*c + 1, t2 = 16*c + 16;
  const int j = tid & 31, r0 = tid >> 5;
  stage_mat(mtw, mtwl, tid);
  stage_mat(ws + WS_MTP, Mtpl, tid);
  stage_mat(ws + WS_EM, Eml, tid);
  stage_mat(ws + WS_X + t1*1024, Xl, tid);
  stage_matT(ws + WS_X + t1*1024, BTa, tid);        // BT = X_{t1}^T
  __syncthreads();
  mm_rr_mI(Xl, mtwl, JT, tid);  __syncthreads();
  mm_rr(JT, Mtpl, W1T, tid);    __syncthreads();
#pragma unroll
  for (int m = 0; m < 4; ++m) {
    const int ri = r0 + 8*m;
    float s = 0.f;
    for (int k = 0; k < 32; ++k) s += W1T[ri*33+k] * JT[j*33+k];
    Ka[ri*33+j] = Eml[ri*33+j] - 0.5f * s;
  }
  __syncthreads();
  float *BTc = BTa, *BTn = BTb, *Kc = Ka, *Kn = Kb;
  for (int t = t1 + 1; t <= t2; ++t) {
    stage_mat(ws + WS_X + t*1024, Xl, tid);
    __syncthreads();
    mm_rr_mI(Xl, mtwl, JT, tid);       // J^T for K_t
    mm_rr(BTc, Xl, BTn, tid);          // BT' = BT @ X_t^T
    mm_rr(Xl, Kc, Tk, tid);            // Tk = X@K (K sym)
    __syncthreads();
    mm_rr(JT, Mtpl, W1T, tid);
    mm_rr(Tk, Xl, Kn, tid);            // X K X^T
    __syncthreads();
#pragma unroll
    for (int m = 0; m < 4; ++m) {
      const int ri = r0 + 8*m;
      float s = 0.f;
      for (int k = 0; k < 32; ++k) s += W1T[ri*33+k] * JT[j*33+k];
      Kn[ri*33+j] += Eml[ri*33+j] - 0.5f * s;
    }
    __syncthreads();
    float* tp = BTc; BTc = BTn; BTn = tp;
    tp = Kc; Kc = Kn; Kn = tp;
  }
  {
    const int r = tid >> 3, cc = (tid & 7) * 4;
    float* dst = ws + WS_CEA + (c+1)*2048;
    float4 v = make_float4(BTc[r*33+cc], BTc[r*33+cc+1], BTc[r*33+cc+2], BTc[r*33+cc+3]);
    *(float4*)(dst + r*32 + cc) = v;
    float4 w = make_float4(Kc[r*33+cc], Kc[r*33+cc+1], Kc[r*33+cc+2], Kc[r*33+cc+3]);
    *(float4*)(dst + 1024 + r*32 + cc) = w;
  }
  if (c == 0) {   // S-scan slot0 identity (CEA was clobbered by eta-scan)
    for (int e = tid; e < 2048; e += 256)
      ws[WS_CEA + e] = (e < 1024 && ((e >> 5) == (e & 31))) ? 1.f : 0.f;
  }
}

// ---------------- S-scan doubling level ----------------
__global__ __launch_bounds__(256) void ks_level(float* __restrict__ ws,
                                                int inoff, int outoff, int step) {
  const int c = blockIdx.x, tid = threadIdx.x;
  const float* in = ws + inoff;
  float* out = ws + outoff;
  if (c < step) {
    const int base = c*2048 + tid*8;
#pragma unroll
    for (int x = 0; x < 8; ++x) out[base + x] = in[base + x];
    return;
  }
  __shared__ float BTo[1056], Ko[1056], BTn[1056], tmp[1056], BTr[1056];
  stage_mat(in + (c-step)*2048, BTo, tid);
  stage_mat(in + (c-step)*2048 + 1024, Ko, tid);
  stage_mat(in + c*2048, BTn, tid);
  __syncthreads();
  mm_p(BTo, BTn, BTr, tid);   // BT' = BT_old @ BT_new
  mm_p(Ko, BTn, tmp, tid);    // tmp = K_old @ B_new^T
  __syncthreads();
  const int j = tid & 31, r0 = tid >> 5;
#pragma unroll
  for (int m = 0; m < 4; ++m) {
    const int ri = r0 + 8*m;
    float s = 0.f;
    for (int k = 0; k < 32; ++k) s += BTn[k*33+ri] * tmp[k*33+j];  // B_new @ tmp
    out[c*2048 + ri*32 + j] = BTr[ri*33+j];
    out[c*2048 + 1024 + ri*32 + j] = s + in[c*2048 + 1024 + ri*32 + j];
  }
}

// ---------------- K_S-C: expand chunks + trace terms ----------------
__global__ __launch_bounds__(256) void ksc(const float* __restrict__ mtw,
                                           float* __restrict__ ws) {
  __shared__ float S[1056], S2[1056], JT[1056], W1T[1056], T1[1056];
  __shared__ float Xl[1056], Bcl[1056], BTP[1056];
  __shared__ float Mtpl[1056], Eml[1056], TQl[1056], mtwl[1056];
  __shared__ float red[4];
  const int tid = threadIdx.x, c = blockIdx.x;
  const int j = tid & 31, r0 = tid >> 5;
  stage_mat(mtw, mtwl, tid);
  stage_mat(ws + WS_MTP, Mtpl, tid);
  stage_mat(ws + WS_EM, Eml, tid);
  stage_mat(ws + WS_TQ, TQl, tid);
  stage_mat(ws + WS_CEB + c*2048, BTP, tid);
  stage_mat(ws + WS_S1, S2, tid);      // S0
  __syncthreads();
  mm_p(S2, BTP, T1, tid);              // T1 = S0 @ B_P^T
  __syncthreads();
#pragma unroll
  for (int m = 0; m < 4; ++m) {        // S_start = B_P @ T1 + K_P
    const int ri = r0 + 8*m;
    float s = 0.f;
    for (int k = 0; k < 32; ++k) s += BTP[k*33+ri] * T1[k*33+j];
    S[ri*33+j] = s + ws[WS_CEB + c*2048 + 1024 + ri*32 + j];
  }
  __syncthreads();
  double accd = 0.0;
  for (int i = 0; i < 16; ++i) {
    const int t = 16*c + 1 + i;
    if (t >= TT) break;
    stage_mat(ws + WS_X + t*1024, Xl, tid);
    stage_mat(ws + WS_BCOV + t*1024, Bcl, tid);
    __syncthreads();
    mm_rr_mI(Xl, mtwl, JT, tid);
    mm_rr(Xl, S, T1, tid);             // T1 = X @ S
    float part = 0.f;
#pragma unroll
    for (int m = 0; m < 4; ++m) {      // trace((S - .5 TQ) @ bcov), bcov sym
      const int ri = r0 + 8*m;
      part += (S[ri*33+j] - 0.5f*TQl[ri*33+j]) * Bcl[ri*33+j];
    }
    const float r2 = block_reduce(part, red, tid);
    if (tid == 0) accd += (double)r2;
    mm_rr(JT, Mtpl, W1T, tid);
    mm_rr(T1, Xl, S2, tid);            // X S X^T
    __syncthreads();
#pragma unroll
    for (int m = 0; m < 4; ++m) {
      const int ri = r0 + 8*m;
      float s = 0.f;
      for (int k = 0; k < 32; ++k) s += W1T[ri*33+k] * JT[j*33+k];
      S[ri*33+j] = S2[ri*33+j] + Eml[ri*33+j] - 0.5f * s;
    }
    __syncthreads();
  }
  if (tid == 0) atomicAdd(((double*)(ws + WS_DACC)) + 2, accd);
}

// ---------------- K_G-A: compose affine suffix maps within each chunk ----------------
__global__ __launch_bounds__(256) void kga(float* __restrict__ ws) {
  __shared__ float ATa[1056], ATb[1056], XTl[1056];
  __shared__ float bb[2][32];
  const int tid = threadIdx.x, c = blockIdx.x + 1;  // c = 1..31
  const int t1 = 16*c + 1;
  const int t2 = (16*c + 16 < TT) ? 16*c + 16 : TT - 1;
  stage_mat(ws + WS_X + t2*1024, ATa, tid);         // AT = bA_{t2}^T = X_{t2}
  if (tid < 32) bb[0][tid] = ws[WS_BA + t2*32 + tid];
  __syncthreads();
  float *ATc = ATa, *ATn = ATb;
  int pb = 0;
  for (int t = t2 - 1; t >= t1; --t) {
    stage_matT(ws + WS_X + t*1024, XTl, tid);
    __syncthreads();
    mm_rr(ATc, XTl, ATn, tid);                      // AT' = AT @ X_t
    if (tid < 32) {
      float s = ws[WS_BA + t*32 + tid];
      for (int k = 0; k < 32; ++k) s += XTl[tid*33+k] * bb[pb][k];
      bb[pb^1][tid] = s;
    }
    __syncthreads();
    float* tp = ATc; ATc = ATn; ATn = tp; pb ^= 1;
  }
  {
    const int r = tid >> 3, cc = (tid & 7) * 4;
    float* dst = ws + WS_GEA + (c-1)*1056;
    float4 v = make_float4(ATc[r*33+cc], ATc[r*33+cc+1], ATc[r*33+cc+2], ATc[r*33+cc+3]);
    *(float4*)(dst + r*32 + cc) = v;
    if (tid < 32) dst[1024 + tid] = bb[pb][tid];
  }
}

// ---------------- G-scan doubling level (suffix) ----------------
__global__ __launch_bounds__(256) void kg_level(float* __restrict__ ws,
                                                int inoff, int outoff, int step) {
  const int c = blockIdx.x, tid = threadIdx.x;
  const float* in = ws + inoff;
  float* out = ws + outoff;
  if (c + step > 31) {
    const int base = c*1056;
    const int e = tid*4;
#pragma unroll
    for (int x = 0; x < 4; ++x) out[base + e + x] = in[base + e + x];
    if (tid < 32) out[base + 1024 + tid] = in[base + 1024 + tid];
    return;
  }
  __shared__ float AT1[1056], AT2[1056], ATr[1056];
  __shared__ float b2l[32];
  stage_mat(in + c*1056, AT1, tid);
  stage_mat(in + (c+step)*1056, AT2, tid);
  if (tid < 32) b2l[tid] = in[(c+step)*1056 + 1024 + tid];
  __syncthreads();
  mm_p(AT2, AT1, ATr, tid);           // AT' = AT_later @ AT_earlier
  if (tid < 32) {
    float s = in[c*1056 + 1024 + tid];
    for (int k = 0; k < 32; ++k) s += AT1[k*33+tid] * b2l[k];   // A1 @ b2 + b1
    out[c*1056 + 1024 + tid] = s;
  }
  __syncthreads();
  {
    const int j = tid & 31, r0 = tid >> 5;
#pragma unroll
    for (int m = 0; m < 4; ++m) {
      const int ri = r0 + 8*m;
      out[c*1056 + ri*32 + j] = ATr[ri*33+j];
    }
  }
}

// ---------------- K_G-B: expand suffix + evaluate final per-s terms ----------------
__global__ __launch_bounds__(256) void kgb(
    const float* __restrict__ obs, const float* __restrict__ mpm,
    const float* __restrict__ mtw, const float* __restrict__ mtb,
    const float* __restrict__ mew, const float* __restrict__ meb,
    float* __restrict__ ws) {
  __shared__ float ATa[1056], ATb[1056], XTl[1056];
  __shared__ float Y1[1056], Y2[1056], Jb[1056], M2T[1056], E1[1056];
  __shared__ float mewl[1056], EmLl[1056], fPl[1056], Mtpl[1056], Mepl[1056], mtwl[1056];
  __shared__ float fml[32], mebl[32], mtbl[32], mpml[32], yl[32], bal[32];
  __shared__ float gv[32], cme[32], cmo[32], bv[2][32];
  __shared__ float red[4];
  const int tid = threadIdx.x, c = blockIdx.x;
  const int j = tid & 31, r0 = tid >> 5;
  stage_mat(mew, mewl, tid);
  stage_mat(ws + WS_EML, EmLl, tid);
  stage_mat(ws + WS_FPT, fPl, tid);
  stage_mat(ws + WS_MTP, Mtpl, tid);
  stage_mat(ws + WS_MEP, Mepl, tid);
  stage_mat(mtw, mtwl, tid);
  stage_mat(ws + WS_GEB + c*1056, ATa, tid);
  if (tid < 32) {
    fml[tid] = ws[WS_FMT + tid];
    mebl[tid] = meb[tid]; mtbl[tid] = mtb[tid]; mpml[tid] = mpm[tid];
    bv[0][tid] = ws[WS_GEB + c*1056 + 1024 + tid];
  }
  __syncthreads();
  float *ATc = ATa, *ATo = ATb;
  int bc = 0;
  double accd = 0.0;
  for (int s = 16*c + 15; s >= 16*c; --s) {
    if (s < TT-1) stage_matT(ws + WS_X + (s+1)*1024, XTl, tid);
    if (s == 0)   stage_mat(ws + WS_MPP, Jb, tid);   // Jb repurposed = Mpp
    if (tid < 32) {
      yl[tid] = obs[s*32 + tid];
      if (s >= 1) bal[tid] = ws[WS_BA + s*32 + tid];
    }
    __syncthreads();
    if (s < TT-1) {
      mm_rr(ATc, XTl, ATo, tid);                 // AT' = AT @ X_{s+1}
      if (tid < 32) {
        float v = ws[WS_BA + (s+1)*32 + tid];
        for (int k = 0; k < 32; ++k) v += XTl[tid*33+k] * bv[bc][k];
        bv[bc^1][tid] = v;
      }
    }
    __syncthreads();
    const float* AT = (s < TT-1) ? ATo : ATc;    // = G(s)^T
    const float* bl = (s < TT-1) ? bv[bc^1] : bv[bc];
    mm_rr(mewl, AT, Y1, tid);                    // Mb = mew@G
    mm_rr(EmLl, AT, Y2, tid);                    // Ub = EmL@G
    if (s >= 1) {                                // Jb = mtw@X_s^T - I
      const float* Xg = ws + WS_X + s*1024;
      float s0 = 0.f, s1 = 0.f, s2 = 0.f, s3 = 0.f;
      for (int k = 0; k < 32; ++k) {
        const float b = Xg[j*32 + k];
        s0 += mtwl[(r0     )*33+k] * b;
        s1 += mtwl[(r0 +  8)*33+k] * b;
        s2 += mtwl[(r0 + 16)*33+k] * b;
        s3 += mtwl[(r0 + 24)*33+k] * b;
      }
      Jb[(r0     )*33+j] = s0 - ((r0      == j) ? 1.f : 0.f);
      Jb[(r0 +  8)*33+j] = s1 - ((r0 +  8 == j) ? 1.f : 0.f);
      Jb[(r0 + 16)*33+j] = s2 - ((r0 + 16 == j) ? 1.f : 0.f);
      Jb[(r0 + 24)*33+j] = s3 - ((r0 + 24 == j) ? 1.f : 0.f);
    }
    if (tid < 32) {
      float g = bl[tid];
      for (int k = 0; k < 32; ++k) g += AT[k*33+tid] * fml[k];
      gv[tid] = g;                               // g = G@fm + h
    }
    __syncthreads();
    if (s >= 1) mm_rr(AT, Jb, M2T, tid);         // M2^T = G^T @ Jb^T
    if (tid < 32) {
      float s1 = mebl[tid] - yl[tid];
      for (int k = 0; k < 32; ++k) s1 += mewl[tid*33+k] * gv[k];
      cme[tid] = s1;
      float s2;
      if (s >= 1) {
        s2 = mtbl[tid];
        for (int k = 0; k < 32; ++k)
          s2 += Jb[tid*33+k] * gv[k] + mtwl[tid*33+k] * bal[k];
      } else {
        s2 = gv[tid] - mpml[tid];
      }
      cmo[tid] = s2;
    }
    __syncthreads();
    const float* M2Tp = (s >= 1) ? M2T : AT;     // s=0: M2 = G
    const float* Mqp  = (s >= 1) ? Mtpl : Jb;    // s=0: Jb holds Mpp
    mm_rr(Mqp, M2Tp, E1, tid);                   // E1 = Mq @ M2
    __syncthreads();
    float part = 0.f;
#pragma unroll
    for (int m = 0; m < 4; ++m) {
      const int ri = r0 + 8*m;
      float y3 = 0.f, e2 = 0.f;
      for (int k = 0; k < 32; ++k) {
        y3 += Y2[ri*33+k] * fPl[j*33+k];
        e2 += fPl[j*33+k] * M2Tp[ri*33+k];       // E2[j][ri] = (fP@M2)[j][ri]
      }
      part += y3 * Y1[j*33+ri]
            - 0.5f * E1[ri*33+j] * e2
            - 0.5f * cme[ri] * Mepl[ri*33+j] * cme[j]
            - 0.5f * cmo[ri] * Mqp[ri*33+j] * cmo[j];
    }
    const float r2 = block_reduce(part, red, tid);
    if (tid == 0) accd += (double)r2;
    if (s < TT-1) { float* tp = ATc; ATc = ATo; ATo = tp; bc ^= 1; }
    __syncthreads();
  }
  if (tid == 0) atomicAdd(((double*)(ws + WS_DACC)) + 3, accd);
}

// ---------------- Kout ----------------
__global__ __launch_bounds__(64) void kout(const float* __restrict__ ws,
                                           float* __restrict__ out) {
  if (threadIdx.x == 0) {
    const double* d = (const double*)(ws + WS_DACC);
    out[0] = (float)(d[0] + d[1] + d[2] + d[3]);
  }
}

extern "C" void kernel_launch(void* const* d_in, const int* in_sizes, int n_in,
                              void* d_out, int out_size, void* d_ws, size_t ws_size,
                              hipStream_t stream) {
  (void)in_sizes; (void)n_in; (void)out_size; (void)ws_size;
  const float* obs = (const float*)d_in[0];
  const float* mpm = (const float*)d_in[1];
  const float* mpc = (const float*)d_in[2];
  const float* mtw = (const float*)d_in[3];
  const float* mtb = (const float*)d_in[4];
  const float* mtc = (const float*)d_in[5];
  const float* mew = (const float*)d_in[6];
  const float* meb = (const float*)d_in[7];
  const float* mec = (const float*)d_in[8];
  const float* vpm = (const float*)d_in[9];
  const float* vpc = (const float*)d_in[10];
  const float* vtw = (const float*)d_in[11];
  const float* vtb = (const float*)d_in[12];
  const float* vtc = (const float*)d_in[13];
  const float* vew = (const float*)d_in[14];
  const float* veb = (const float*)d_in[15];
  const float* vcc = (const float*)d_in[16];
  float* ws  = (float*)d_ws;
  float* out = (float*)d_out;

  k0_init<<<1, 256, 0, stream>>>(ws);
  k1_invert<<<6, 256, 0, stream>>>(mtc, mec, mpc, vtc, vcc, vpc, ws);
  k2_derived<<<1, 256, 0, stream>>>(obs, vpm, vtw, vtb, vew, veb, mtw, mew, ws);
  k3_yt<<<TT/8, 256, 0, stream>>>(obs, veb, ws);

  // Riccati: doubling + boundaries (1 block), then parallel chunk expansion
  kr_seq<<<1, 256, 0, stream>>>(ws);
  kr_exp<<<32, 256, 0, stream>>>(ws);

  // eta affine prefix scan (uses CEA/CEB 1056-stride; before S-scan machinery)
  keta_a<<<31, 256, 0, stream>>>(ws);
  keta_lvl<<<32, 256, 0, stream>>>(ws, WS_CEA, WS_CEB, 1);
  keta_lvl<<<32, 256, 0, stream>>>(ws, WS_CEB, WS_CEA, 2);
  keta_lvl<<<32, 256, 0, stream>>>(ws, WS_CEA, WS_CEB, 4);
  keta_lvl<<<32, 256, 0, stream>>>(ws, WS_CEB, WS_CEA, 8);
  keta_lvl<<<32, 256, 0, stream>>>(ws, WS_CEA, WS_CEB, 16);
  keta_b<<<32, 256, 0, stream>>>(ws);
  kfin<<<1, 64, 0, stream>>>(ws);

  // S-machinery: chunk compose -> exclusive prefix scan -> expand+trace
  ksa<<<31, 256, 0, stream>>>(mtw, ws);
  ks_level<<<32, 256, 0, stream>>>(ws, WS_CEA, WS_CEB, 1);
  ks_level<<<32, 256, 0, stream>>>(ws, WS_CEB, WS_CEA, 2);
  ks_level<<<32, 256, 0, stream>>>(ws, WS_CEA, WS_CEB, 4);
  ks_level<<<32, 256, 0, stream>>>(ws, WS_CEB, WS_CEA, 8);
  ks_level<<<32, 256, 0, stream>>>(ws, WS_CEA, WS_CEB, 16);
  ksc<<<32, 256, 0, stream>>>(mtw, ws);

  // G-machinery: chunk compose -> suffix scan -> expand + final terms
  kga<<<31, 256, 0, stream>>>(ws);
  kg_level<<<32, 256, 0, stream>>>(ws, WS_GEA, WS_GEB, 1);
  kg_level<<<32, 256, 0, stream>>>(ws, WS_GEB, WS_GEA, 2);
  kg_level<<<32, 256, 0, stream>>>(ws, WS_GEA, WS_GEB, 4);
  kg_level<<<32, 256, 0, stream>>>(ws, WS_GEB, WS_GEA, 8);
  kg_level<<<32, 256, 0, stream>>>(ws, WS_GEA, WS_GEB, 16);
  kgb<<<32, 256, 0, stream>>>(obs, mpm, mtw, mtb, mew, meb, ws);

  kout<<<1, 64, 0, stream>>>(ws, out);
}

// Round 4
// 838.183 us; speedup vs baseline: 40.6102x; 1.5009x over previous
//
#include <hip/hip_runtime.h>
#include <math.h>

#define TT 512
#define CH 8
#define NCH 64
#define NB 64
#define LOG2PI 1.8378770664093453

static_assert(TT == CH * NCH, "chunking");

// ---------------- workspace layout (float offsets) ----------------
enum : int {
  WS_X     = 0,                    // [TT][32][32] X_t (bA_t = X^T), t=1..511
  WS_BCOV  = WS_X    + TT*1024,    // [TT][32][32] bcov_t
  WS_BA    = WS_BCOV + TT*1024,    // [TT][32] ba_t
  WS_YT    = WS_BA   + TT*32,      // [TT][32] Wt = HtRi@(y_t-veb) + qivtb - ctb
  WS_MTP   = WS_YT   + TT*32,
  WS_MEP   = WS_MTP + 1024,
  WS_MPP   = WS_MEP + 1024,
  WS_QI    = WS_MPP + 1024,
  WS_RI    = WS_QI  + 1024,
  WS_P0I   = WS_RI  + 1024,
  WS_QIW   = WS_P0I + 1024,
  WS_CW    = WS_QIW + 1024,
  WS_HTRI  = WS_CW  + 1024,
  WS_HTRIH = WS_HTRI+ 1024,
  WS_TQ    = WS_HTRIH+1024,
  WS_EM    = WS_TQ  + 1024,
  WS_EML   = WS_EM  + 1024,
  WS_LAM0CW= WS_EML + 1024,        // Z_1
  WS_QHC   = WS_LAM0CW + 1024,
  WS_S1    = WS_QHC + 1024,
  WS_FPT   = WS_S1  + 1024,
  WS_ETA0  = WS_FPT + 1024,
  WS_CTB   = WS_ETA0 + 32,
  WS_QIVTB = WS_CTB + 32,
  WS_FMT   = WS_QIVTB + 32,
  WS_ETAF  = WS_FMT + 32,
  WS_LDS3  = WS_ETAF + 32,
  WS_DACC  = WS_LDS3 + 4,          // 4 doubles
  WS_Z512  = WS_DACC + 8,
  WS_OPS   = WS_Z512 + 1024,       // 6 ops x (K,A,G) x 1024
  WS_GBAR  = WS_OPS + 6*3072,      // 64 barrier counters
  WS_CEA   = WS_GBAR + 64,         // NCH*2048
  WS_CEB   = WS_CEA + NCH*2048,
  WS_END   = WS_CEB + NCH*2048
};
// time-disjoint aliases
enum : int {
  WS_ZB  = WS_CEB,     // boundary Z's (P2..P9, before any scan writes CEB)
  WS_GEA = WS_CEB,     // G-scan ping (P26+, after S-scan consumed)
  WS_GEB = WS_CEA
};
static_assert(WS_DACC % 2 == 0, "double alignment");

// ---------------- helpers ----------------
__device__ __forceinline__ float rlane(float v, int l) {
  return __uint_as_float(__builtin_amdgcn_readlane(__float_as_uint(v), l));
}

__device__ __forceinline__ double gj_inv32(float a[32]) {
  double pp = 1.0;
#pragma unroll
  for (int p = 0; p < 32; ++p) {
    const float piv = rlane(a[p], p);
    pp *= (double)piv;
    const float sc = a[p] * (1.0f / piv);
#pragma unroll
    for (int r = 0; r < 32; ++r) {
      if (r != p) a[r] -= rlane(a[r], p) * sc;
    }
    a[p] = sc;
  }
  return pp;
}

// invert 32x32 (stride-33 LDS) in place; call with tid<64 only
__device__ __forceinline__ double wave_inv33(float* M, int tid) {
  float a[32]; const int cc = tid & 31;
#pragma unroll
  for (int r = 0; r < 32; ++r)
    a[r] = (tid < 32) ? M[r*33 + cc] : ((r == tid - 32) ? 1.f : 0.f);
  const double pp = gj_inv32(a);
  if (tid >= 32) {
    const int c2 = tid - 32;
#pragma unroll
    for (int r = 0; r < 32; ++r) M[r*33 + c2] = a[r];
  }
  return pp;
}

__device__ __forceinline__ float block_reduce(float v, float* red, int tid) {
#pragma unroll
  for (int m = 32; m >= 1; m >>= 1) v += __shfl_xor(v, m, 64);
  if ((tid & 63) == 0) red[tid >> 6] = v;
  __syncthreads();
  return red[0] + red[1] + red[2] + red[3];
}

__device__ __forceinline__ void stage_mat(const float* __restrict__ g, float* L, int tid) {
  const int r = tid >> 3, c = (tid & 7) * 4;
  const float4 v = *(const float4*)(g + r*32 + c);
  L[r*33+c] = v.x; L[r*33+c+1] = v.y; L[r*33+c+2] = v.z; L[r*33+c+3] = v.w;
}
__device__ __forceinline__ void stage_matT(const float* __restrict__ g, float* L, int tid) {
  const int r = tid >> 3, c = (tid & 7) * 4;
  const float4 v = *(const float4*)(g + r*32 + c);
  L[(c  )*33+r] = v.x; L[(c+1)*33+r] = v.y; L[(c+2)*33+r] = v.z; L[(c+3)*33+r] = v.w;
}
__device__ __forceinline__ void destage_mat(const float* L, float* __restrict__ g, int tid) {
  const int r = tid >> 3, c = (tid & 7) * 4;
  float4 v = make_float4(L[r*33+c], L[r*33+c+1], L[r*33+c+2], L[r*33+c+3]);
  *(float4*)(g + r*32 + c) = v;
}

__device__ __forceinline__ void mm_rr(const float* A, const float* B, float* C, int tid) {
  const int j = tid & 31, r0 = tid >> 5;
#pragma unroll
  for (int m = 0; m < 4; ++m) {
    const int ri = r0 + 8*m;
    float s = 0.f;
    for (int k = 0; k < 32; ++k) s += A[ri*33+k] * B[j*33+k];
    C[ri*33+j] = s;
  }
}
__device__ __forceinline__ void mm_rr_mI(const float* A, const float* B, float* C, int tid) {
  const int j = tid & 31, r0 = tid >> 5;
#pragma unroll
  for (int m = 0; m < 4; ++m) {
    const int ri = r0 + 8*m;
    float s = 0.f;
    for (int k = 0; k < 32; ++k) s += A[ri*33+k] * B[j*33+k];
    C[ri*33+j] = s - ((ri == j) ? 1.f : 0.f);
  }
}
__device__ __forceinline__ void mm_p(const float* A, const float* B, float* C, int tid) {
  const int j = tid & 31, r0 = tid >> 5;
#pragma unroll
  for (int m = 0; m < 4; ++m) {
    const int ri = r0 + 8*m;
    float s = 0.f;
    for (int k = 0; k < 32; ++k) s += A[ri*33+k] * B[k*33+j];
    C[ri*33+j] = s;
  }
}
__device__ __forceinline__ void mm_tp(const float* A, const float* B, float* C, int tid) {
  const int j = tid & 31, r0 = tid >> 5;
#pragma unroll
  for (int m = 0; m < 4; ++m) {
    const int ri = r0 + 8*m;
    float s = 0.f;
    for (int k = 0; k < 32; ++k) s += A[k*33+ri] * B[k*33+j];
    C[ri*33+j] = s;
  }
}

// ---------------- grid barrier (device-scope, per-barrier counter) ----------------
__device__ __forceinline__ void gridbar(unsigned* bars, int idx) {
  __syncthreads();
  if (threadIdx.x == 0) {
    __threadfence();
    __hip_atomic_fetch_add(&bars[idx], 1u, __ATOMIC_RELEASE, __HIP_MEMORY_SCOPE_AGENT);
    while (__hip_atomic_load(&bars[idx], __ATOMIC_ACQUIRE, __HIP_MEMORY_SCOPE_AGENT)
           < (unsigned)NB)
      __builtin_amdgcn_s_sleep(1);
  }
  __syncthreads();
}

// ---------------- k2 body (block 0 only) ----------------
__device__ void dev_k2(const float* __restrict__ obs, const float* __restrict__ vpm,
                       const float* __restrict__ vtw, const float* __restrict__ vtb,
                       const float* __restrict__ vew, const float* __restrict__ veb,
                       const float* __restrict__ mtw, const float* __restrict__ mew,
                       float* __restrict__ ws, int tid) {
  const int j = tid & 31, r0 = tid >> 5;
#pragma unroll
  for (int m = 0; m < 4; ++m) {
    const int ri = r0 + 8*m;
    float s1 = 0.f, s2 = 0.f, s3 = 0.f, s4 = 0.f;
    for (int k = 0; k < 32; ++k) {
      s1 += ws[WS_QI  + ri*32 + k] * vtw[k*32 + j];
      s2 += vew[k*32 + ri] * ws[WS_RI + k*32 + j];
      s3 += ws[WS_MTP + ri*32 + k] * mtw[k*32 + j];
      s4 += ws[WS_MEP + ri*32 + k] * mew[k*32 + j];
    }
    ws[WS_QIW + ri*32 + j] = s1;
    ws[WS_HTRI + ri*32 + j] = s2;
    ws[WS_FPT + ri*32 + j] = s3;      // temp Mtp@mtw
    ws[WS_EML + ri*32 + j] = -0.5f * s4;
  }
  __syncthreads();
#pragma unroll
  for (int m = 0; m < 4; ++m) {
    const int ri = r0 + 8*m;
    float s1 = 0.f, s2 = 0.f, s3 = 0.f, s4 = 0.f;
    for (int k = 0; k < 32; ++k) {
      s1 += vtw[k*32 + ri] * ws[WS_QIW + k*32 + j];
      s2 += ws[WS_HTRI + ri*32 + k] * vew[k*32 + j];
      s3 += mtw[k*32 + ri] * ws[WS_FPT + k*32 + j];
      s4 += mew[k*32 + ri] * ws[WS_EML + k*32 + j];
    }
    ws[WS_CW + ri*32 + j] = s1;
    ws[WS_HTRIH + ri*32 + j] = s2;
    ws[WS_LAM0CW + ri*32 + j] = ws[WS_P0I + ri*32 + j] + s1 + s2;
    ws[WS_QHC    + ri*32 + j] = ws[WS_QI  + ri*32 + j] + s1 + s2;
    ws[WS_TQ + ri*32 + j] = s3;
    ws[WS_EM + ri*32 + j] = s4;
    ws[WS_S1 + ri*32 + j] = s4 - 0.5f * ws[WS_MPP + ri*32 + j];
  }
  if (tid < 32) {
    float s1 = 0.f, s2 = 0.f, s3 = 0.f;
    for (int k = 0; k < 32; ++k) {
      s1 += ws[WS_QIW + k*32 + tid] * vtb[k];
      s2 += ws[WS_P0I + tid*32 + k] * vpm[k]
          + ws[WS_HTRI + tid*32 + k] * (obs[k] - veb[k]);
      s3 += ws[WS_QI + tid*32 + k] * vtb[k];
    }
    ws[WS_CTB + tid] = s1;
    ws[WS_ETA0 + tid] = s2;
    ws[WS_QIVTB + tid] = s3;
  }
  __syncthreads();
  if (tid == 0) {
    const double ldmt = (double)ws[WS_LDS3 + 0];
    const double ldme = (double)ws[WS_LDS3 + 1];
    const double ldmp = (double)ws[WS_LDS3 + 2];
    const double ct_me = -0.5 * (32.0 * LOG2PI + ldme);
    const double ct_mt = -0.5 * (32.0 * LOG2PI + ldmt);
    const double ct_mp = -0.5 * (32.0 * LOG2PI + ldmp);
    double c = ct_mp + ct_me;
    c += (double)(TT - 1) * (ct_me + ct_mt + 0.5 * 32.0 * LOG2PI + 16.0);
    c += 0.5 * 32.0 * LOG2PI + 16.0;
    ((double*)(ws + WS_DACC))[0] = c;
  }
}

// ---------------- Riccati operator squaring (block 0) ----------------
__device__ void dev_compose(float* __restrict__ ws, float* sm, int tid) {
  float *Kc = sm,       *Ac = sm+1056,  *Gc = sm+2112;
  float *Kn = sm+3168,  *An = sm+4224,  *Gn = sm+5280;
  float *Mi = sm+6336,  *V1 = sm+7392,  *Wm = sm+8448;
  const int j = tid & 31, r0 = tid >> 5;
  stage_mat(ws + WS_QHC, Kc, tid);
  stage_mat(ws + WS_QIW, Ac, tid);
  for (int e = tid; e < 1056; e += 256) Gc[e] = 0.f;
  __syncthreads();
  for (int d = 0; d < 8; ++d) {          // builds Phi^{2^{d+1}}
    for (int e = tid; e < 1056; e += 256) Mi[e] = Kc[e] + Gc[e];
    __syncthreads();
    if (tid < 64) wave_inv33(Mi, tid);
    __syncthreads();
    mm_rr(Ac, Mi, V1, tid);   // A M^-1 (M^-1 sym)
    mm_tp(Ac, Mi, Wm, tid);   // A^T M^-1
    __syncthreads();
#pragma unroll
    for (int m = 0; m < 4; ++m) {
      const int ri = r0 + 8*m;
      float s1 = 0.f, s2 = 0.f, s3 = 0.f;
      for (int k = 0; k < 32; ++k) {
        const float v = V1[ri*33+k];
        s1 += v * Ac[j*33+k];
        s2 += v * Ac[k*33+j];
        s3 += Wm[ri*33+k] * Ac[k*33+j];
      }
      Kn[ri*33+j] = Kc[ri*33+j] - s1;
      An[ri*33+j] = s2;
      Gn[ri*33+j] = Gc[ri*33+j] - s3;
    }
    __syncthreads();
    float* tp;
    tp=Kc; Kc=Kn; Kn=tp;  tp=Ac; Ac=An; An=tp;  tp=Gc; Gc=Gn; Gn=tp;
    if (d >= 2) {                         // save Phi^8 .. Phi^256
      float* op = ws + WS_OPS + (d-2)*3072;
      destage_mat(Kc, op, tid);
      destage_mat(Ac, op + 1024, tid);
      destage_mat(Gc, op + 2048, tid);
    }
  }
  __syncthreads();
  const int e = tid * 4;                  // ZB[0] = Z_1
  *(float4*)(ws + WS_ZB + e) = *(const float4*)(ws + WS_LAM0CW + e);
}

// ---------------- eta machinery ----------------
__device__ void dev_keta_a(float* __restrict__ ws, float* sm, int tid, int c) {
  float *Aa = sm, *Ab = sm+1056, *Xl = sm+2112, *bb = sm+3168;
  const int t1 = CH*c + 1;
  stage_mat(ws + WS_X + t1*1024, Aa, tid);
  if (tid < 32) bb[tid] = ws[WS_YT + t1*32 + tid];
  __syncthreads();
  float *Acur = Aa, *Anew = Ab; int pb = 0;
  for (int t = t1 + 1; t <= t1 + CH - 1; ++t) {
    stage_mat(ws + WS_X + t*1024, Xl, tid);
    __syncthreads();
    mm_p(Xl, Acur, Anew, tid);
    if (tid < 32) {
      float s = ws[WS_YT + t*32 + tid];
      for (int k = 0; k < 32; ++k) s += Xl[tid*33+k] * bb[pb*32 + k];
      bb[(pb^1)*32 + tid] = s;
    }
    __syncthreads();
    float* tp = Acur; Acur = Anew; Anew = tp; pb ^= 1;
  }
  float* dst = ws + WS_CEA + (c+1)*1056;
  destage_mat(Acur, dst, tid);
  if (tid < 32) dst[1024 + tid] = bb[pb*32 + tid];
}

__device__ void dev_eta_lvl(float* __restrict__ ws, float* sm,
                            int inoff, int outoff, int step, int tid, int c) {
  const float* in = ws + inoff;
  float* out = ws + outoff;
  if (c < step) {
    for (int e = tid; e < 1056; e += 256) out[c*1056 + e] = in[c*1056 + e];
    return;
  }
  float *A1 = sm, *A0 = sm+1056, *Ar = sm+2112, *b0l = sm+3168;
  stage_mat(in + c*1056, A1, tid);
  stage_mat(in + (c-step)*1056, A0, tid);
  if (tid < 32) b0l[tid] = in[(c-step)*1056 + 1024 + tid];
  __syncthreads();
  mm_p(A1, A0, Ar, tid);
  if (tid < 32) {
    float s = in[c*1056 + 1024 + tid];
    for (int k = 0; k < 32; ++k) s += A1[tid*33+k] * b0l[k];
    out[c*1056 + 1024 + tid] = s;
  }
  __syncthreads();
  destage_mat(Ar, out + c*1056, tid);
}

__device__ void dev_keta_b(float* __restrict__ ws, float* sm, int tid, int c) {
  float *Ap = sm, *Bl = sm+1056, *Xl = sm+2112, *zeta = sm+3168, *zn = sm+3200;
  const int nst = (c == NCH-1) ? CH-1 : CH;
  stage_mat(ws + WS_CEA + c*1056, Ap, tid);
  __syncthreads();
  if (tid < 32) {
    float s = ws[WS_CEA + c*1056 + 1024 + tid];
    for (int k = 0; k < 32; ++k)
      s += Ap[tid*33+k] * (ws[WS_ETA0 + k] - ws[WS_CTB + k]);
    zeta[tid] = s;
  }
  __syncthreads();
  for (int i = 0; i < nst; ++i) {
    const int t = CH*c + 1 + i;
    stage_mat(ws + WS_BCOV + t*1024, Bl, tid);
    stage_mat(ws + WS_X + t*1024, Xl, tid);
    __syncthreads();
    if (tid < 32) {
      float s = 0.f;
      for (int k = 0; k < 32; ++k) s += Bl[tid*33+k] * zeta[k];
      ws[WS_BA + t*32 + tid] = s;
    } else if (tid < 64) {
      const int i2 = tid - 32;
      float s = ws[WS_YT + t*32 + i2];
      for (int k = 0; k < 32; ++k) s += Xl[i2*33+k] * zeta[k];
      zn[i2] = s;
    }
    __syncthreads();
    if (tid < 32) zeta[tid] = zn[tid];
    __syncthreads();
  }
  if (c == NCH-1 && tid < 32)
    ws[WS_ETAF + tid] = zeta[tid] + ws[WS_CTB + tid];
}

// ---------------- S machinery ----------------
__device__ void dev_ksa(const float* __restrict__ mtw, float* __restrict__ ws,
                        float* sm, int tid, int c) {
  float *BTa=sm,      *BTb=sm+1056,  *Ka=sm+2112,  *Kb=sm+3168, *JT=sm+4224,
        *W1T=sm+5280, *Tk=sm+6336,   *Xl=sm+7392,  *mtwl=sm+8448,
        *Mtpl=sm+9504,*Eml=sm+10560;
  const int t1 = CH*c + 1, t2 = CH*c + CH;
  const int j = tid & 31, r0 = tid >> 5;
  stage_mat(mtw, mtwl, tid);
  stage_mat(ws + WS_MTP, Mtpl, tid);
  stage_mat(ws + WS_EM, Eml, tid);
  stage_mat(ws + WS_X + t1*1024, Xl, tid);
  stage_matT(ws + WS_X + t1*1024, BTa, tid);
  __syncthreads();
  mm_rr_mI(Xl, mtwl, JT, tid);  __syncthreads();
  mm_rr(JT, Mtpl, W1T, tid);    __syncthreads();
#pragma unroll
  for (int m = 0; m < 4; ++m) {
    const int ri = r0 + 8*m;
    float s = 0.f;
    for (int k = 0; k < 32; ++k) s += W1T[ri*33+k] * JT[j*33+k];
    Ka[ri*33+j] = Eml[ri*33+j] - 0.5f * s;
  }
  __syncthreads();
  float *BTc = BTa, *BTn = BTb, *Kc = Ka, *Kn = Kb;
  for (int t = t1 + 1; t <= t2; ++t) {
    stage_mat(ws + WS_X + t*1024, Xl, tid);
    __syncthreads();
    mm_rr_mI(Xl, mtwl, JT, tid);
    mm_rr(BTc, Xl, BTn, tid);
    mm_rr(Xl, Kc, Tk, tid);
    __syncthreads();
    mm_rr(JT, Mtpl, W1T, tid);
    mm_rr(Tk, Xl, Kn, tid);
    __syncthreads();
#pragma unroll
    for (int m = 0; m < 4; ++m) {
      const int ri = r0 + 8*m;
      float s = 0.f;
      for (int k = 0; k < 32; ++k) s += W1T[ri*33+k] * JT[j*33+k];
      Kn[ri*33+j] += Eml[ri*33+j] - 0.5f * s;
    }
    __syncthreads();
    float* tp = BTc; BTc = BTn; BTn = tp;
    tp = Kc; Kc = Kn; Kn = tp;
  }
  float* dst = ws + WS_CEA + (c+1)*2048;
  destage_mat(BTc, dst, tid);
  destage_mat(Kc, dst + 1024, tid);
}

__device__ void dev_ks_level(float* __restrict__ ws, float* sm,
                             int inoff, int outoff, int step, int tid, int c) {
  const float* in = ws + inoff;
  float* out = ws + outoff;
  if (c < step) {
    const int base = c*2048 + tid*8;
#pragma unroll
    for (int x = 0; x < 8; ++x) out[base + x] = in[base + x];
    return;
  }
  float *BTo=sm, *Ko=sm+1056, *BTn=sm+2112, *tmp=sm+3168, *BTr=sm+4224;
  stage_mat(in + (c-step)*2048, BTo, tid);
  stage_mat(in + (c-step)*2048 + 1024, Ko, tid);
  stage_mat(in + c*2048, BTn, tid);
  __syncthreads();
  mm_p(BTo, BTn, BTr, tid);
  mm_p(Ko, BTn, tmp, tid);
  __syncthreads();
  const int j = tid & 31, r0 = tid >> 5;
#pragma unroll
  for (int m = 0; m < 4; ++m) {
    const int ri = r0 + 8*m;
    float s = 0.f;
    for (int k = 0; k < 32; ++k) s += BTn[k*33+ri] * tmp[k*33+j];
    out[c*2048 + ri*32 + j] = BTr[ri*33+j];
    out[c*2048 + 1024 + ri*32 + j] = s + in[c*2048 + 1024 + ri*32 + j];
  }
}

__device__ void dev_ksc(const float* __restrict__ mtw, float* __restrict__ ws,
                        float* sm, float* red, int tid, int c) {
  float *S=sm,        *S2=sm+1056,  *JT=sm+2112,  *W1T=sm+3168, *T1=sm+4224,
        *Xl=sm+5280,  *Bcl=sm+6336, *BTP=sm+7392, *Mtpl=sm+8448,
        *Eml=sm+9504, *TQl=sm+10560,*mtwl=sm+11616;
  const int j = tid & 31, r0 = tid >> 5;
  stage_mat(mtw, mtwl, tid);
  stage_mat(ws + WS_MTP, Mtpl, tid);
  stage_mat(ws + WS_EM, Eml, tid);
  stage_mat(ws + WS_TQ, TQl, tid);
  stage_mat(ws + WS_CEA + c*2048, BTP, tid);
  stage_mat(ws + WS_S1, S2, tid);
  __syncthreads();
  mm_p(S2, BTP, T1, tid);
  __syncthreads();
#pragma unroll
  for (int m = 0; m < 4; ++m) {
    const int ri = r0 + 8*m;
    float s = 0.f;
    for (int k = 0; k < 32; ++k) s += BTP[k*33+ri] * T1[k*33+j];
    S[ri*33+j] = s + ws[WS_CEA + c*2048 + 1024 + ri*32 + j];
  }
  __syncthreads();
  double accd = 0.0;
  for (int i = 0; i < CH; ++i) {
    const int t = CH*c + 1 + i;
    if (t >= TT) break;
    stage_mat(ws + WS_X + t*1024, Xl, tid);
    stage_mat(ws + WS_BCOV + t*1024, Bcl, tid);
    __syncthreads();
    mm_rr_mI(Xl, mtwl, JT, tid);
    mm_rr(Xl, S, T1, tid);
    float part = 0.f;
#pragma unroll
    for (int m = 0; m < 4; ++m) {
      const int ri = r0 + 8*m;
      part += (S[ri*33+j] - 0.5f*TQl[ri*33+j]) * Bcl[ri*33+j];
    }
    const float r2 = block_reduce(part, red, tid);
    if (tid == 0) accd += (double)r2;
    mm_rr(JT, Mtpl, W1T, tid);
    mm_rr(T1, Xl, S2, tid);
    __syncthreads();
#pragma unroll
    for (int m = 0; m < 4; ++m) {
      const int ri = r0 + 8*m;
      float s = 0.f;
      for (int k = 0; k < 32; ++k) s += W1T[ri*33+k] * JT[j*33+k];
      S[ri*33+j] = S2[ri*33+j] + Eml[ri*33+j] - 0.5f * s;
    }
    __syncthreads();
  }
  if (tid == 0) atomicAdd(((double*)(ws + WS_DACC)) + 2, accd);
}

// ---------------- G machinery ----------------
__device__ void dev_kga(float* __restrict__ ws, float* sm, int tid, int c) {
  float *ATa = sm, *ATb = sm+1056, *XTl = sm+2112, *bb = sm+3168;
  const int t1 = CH*c + 1;
  const int t2 = (CH*c + CH < TT) ? CH*c + CH : TT - 1;
  stage_mat(ws + WS_X + t2*1024, ATa, tid);
  if (tid < 32) bb[tid] = ws[WS_BA + t2*32 + tid];
  __syncthreads();
  float *ATc = ATa, *ATn = ATb;
  int pb = 0;
  for (int t = t2 - 1; t >= t1; --t) {
    stage_matT(ws + WS_X + t*1024, XTl, tid);
    __syncthreads();
    mm_rr(ATc, XTl, ATn, tid);
    if (tid < 32) {
      float s = ws[WS_BA + t*32 + tid];
      for (int k = 0; k < 32; ++k) s += XTl[tid*33+k] * bb[pb*32 + k];
      bb[(pb^1)*32 + tid] = s;
    }
    __syncthreads();
    float* tp = ATc; ATc = ATn; ATn = tp; pb ^= 1;
  }
  float* dst = ws + WS_GEA + (c-1)*1056;
  destage_mat(ATc, dst, tid);
  if (tid < 32) dst[1024 + tid] = bb[pb*32 + tid];
}

__device__ void dev_kg_level(float* __restrict__ ws, float* sm,
                             int inoff, int outoff, int step, int tid, int c) {
  const float* in = ws + inoff;
  float* out = ws + outoff;
  if (c + step > NCH - 1) {
    const int base = c*1056;
    const int e = tid*4;
#pragma unroll
    for (int x = 0; x < 4; ++x) out[base + e + x] = in[base + e + x];
    if (tid < 32) out[base + 1024 + tid] = in[base + 1024 + tid];
    return;
  }
  float *AT1 = sm, *AT2 = sm+1056, *ATr = sm+2112, *b2l = sm+3168;
  stage_mat(in + c*1056, AT1, tid);
  stage_mat(in + (c+step)*1056, AT2, tid);
  if (tid < 32) b2l[tid] = in[(c+step)*1056 + 1024 + tid];
  __syncthreads();
  mm_p(AT2, AT1, ATr, tid);
  if (tid < 32) {
    float s = in[c*1056 + 1024 + tid];
    for (int k = 0; k < 32; ++k) s += AT1[k*33+tid] * b2l[k];
    out[c*1056 + 1024 + tid] = s;
  }
  __syncthreads();
  destage_mat(ATr, out + c*1056, tid);
}

__device__ void dev_kgb(const float* __restrict__ obs, const float* __restrict__ mpm,
                        const float* __restrict__ mtw, const float* __restrict__ mtb,
                        const float* __restrict__ mew, const float* __restrict__ meb,
                        float* __restrict__ ws, float* sm, float* red, int tid, int c) {
  float *ATa=sm,       *ATb=sm+1056,  *XTl=sm+2112,  *Y1=sm+3168,  *Y2=sm+4224,
        *Jb=sm+5280,   *M2T=sm+6336,  *E1=sm+7392,   *mewl=sm+8448,*EmLl=sm+9504,
        *fPl=sm+10560, *Mtpl=sm+11616,*Mepl=sm+12672,*mtwl=sm+13728;
  float *vec = sm + 14784;
  float *fml=vec, *mebl=vec+32, *mtbl=vec+64, *mpml=vec+96, *yl=vec+128,
        *bal=vec+160, *gv=vec+192, *cme=vec+224, *cmo=vec+256, *bv=vec+288;
  const int j = tid & 31, r0 = tid >> 5;
  stage_mat(mew, mewl, tid);
  stage_mat(ws + WS_EML, EmLl, tid);
  stage_mat(ws + WS_FPT, fPl, tid);
  stage_mat(ws + WS_MTP, Mtpl, tid);
  stage_mat(ws + WS_MEP, Mepl, tid);
  stage_mat(mtw, mtwl, tid);
  stage_mat(ws + WS_GEA + c*1056, ATa, tid);
  if (tid < 32) {
    fml[tid] = ws[WS_FMT + tid];
    mebl[tid] = meb[tid]; mtbl[tid] = mtb[tid]; mpml[tid] = mpm[tid];
    bv[tid] = ws[WS_GEA + c*1056 + 1024 + tid];
  }
  __syncthreads();
  float *ATc = ATa, *ATo = ATb;
  int bc = 0;
  double accd = 0.0;
  for (int s = CH*c + CH - 1; s >= CH*c; --s) {
    if (s < TT-1) stage_matT(ws + WS_X + (s+1)*1024, XTl, tid);
    if (s == 0)   stage_mat(ws + WS_MPP, Jb, tid);
    if (tid < 32) {
      yl[tid] = obs[s*32 + tid];
      if (s >= 1) bal[tid] = ws[WS_BA + s*32 + tid];
    }
    __syncthreads();
    if (s < TT-1) {
      mm_rr(ATc, XTl, ATo, tid);
      if (tid < 32) {
        float v = ws[WS_BA + (s+1)*32 + tid];
        for (int k = 0; k < 32; ++k) v += XTl[tid*33+k] * bv[bc*32 + k];
        bv[(bc^1)*32 + tid] = v;
      }
    }
    __syncthreads();
    const float* AT = (s < TT-1) ? ATo : ATc;
    const float* bl = (s < TT-1) ? (bv + (bc^1)*32) : (bv + bc*32);
    mm_rr(mewl, AT, Y1, tid);
    mm_rr(EmLl, AT, Y2, tid);
    if (s >= 1) {
      const float* Xg = ws + WS_X + s*1024;
      float s0 = 0.f, s1 = 0.f, s2 = 0.f, s3 = 0.f;
      for (int k = 0; k < 32; ++k) {
        const float b = Xg[j*32 + k];
        s0 += mtwl[(r0     )*33+k] * b;
        s1 += mtwl[(r0 +  8)*33+k] * b;
        s2 += mtwl[(r0 + 16)*33+k] * b;
        s3 += mtwl[(r0 + 24)*33+k] * b;
      }
      Jb[(r0     )*33+j] = s0 - ((r0      == j) ? 1.f : 0.f);
      Jb[(r0 +  8)*33+j] = s1 - ((r0 +  8 == j) ? 1.f : 0.f);
      Jb[(r0 + 16)*33+j] = s2 - ((r0 + 16 == j) ? 1.f : 0.f);
      Jb[(r0 + 24)*33+j] = s3 - ((r0 + 24 == j) ? 1.f : 0.f);
    }
    if (tid < 32) {
      float g = bl[tid];
      for (int k = 0; k < 32; ++k) g += AT[k*33+tid] * fml[k];
      gv[tid] = g;
    }
    __syncthreads();
    if (s >= 1) mm_rr(AT, Jb, M2T, tid);
    if (tid < 32) {
      float s1v = mebl[tid] - yl[tid];
      for (int k = 0; k < 32; ++k) s1v += mewl[tid*33+k] * gv[k];
      cme[tid] = s1v;
      float s2v;
      if (s >= 1) {
        s2v = mtbl[tid];
        for (int k = 0; k < 32; ++k)
          s2v += Jb[tid*33+k] * gv[k] + mtwl[tid*33+k] * bal[k];
      } else {
        s2v = gv[tid] - mpml[tid];
      }
      cmo[tid] = s2v;
    }
    __syncthreads();
    const float* M2Tp = (s >= 1) ? M2T : AT;
    const float* Mqp  = (s >= 1) ? Mtpl : Jb;
    mm_rr(Mqp, M2Tp, E1, tid);
    __syncthreads();
    float part = 0.f;
#pragma unroll
    for (int m = 0; m < 4; ++m) {
      const int ri = r0 + 8*m;
      float y3 = 0.f, e2 = 0.f;
      for (int k = 0; k < 32; ++k) {
        y3 += Y2[ri*33+k] * fPl[j*33+k];
        e2 += fPl[j*33+k] * M2Tp[ri*33+k];
      }
      part += y3 * Y1[j*33+ri]
            - 0.5f * E1[ri*33+j] * e2
            - 0.5f * cme[ri] * Mepl[ri*33+j] * cme[j]
            - 0.5f * cmo[ri] * Mqp[ri*33+j] * cmo[j];
    }
    const float r2 = block_reduce(part, red, tid);
    if (tid == 0) accd += (double)r2;
    if (s < TT-1) { float* tp = ATc; ATc = ATo; ATo = tp; bc ^= 1; }
    __syncthreads();
  }
  if (tid == 0) atomicAdd(((double*)(ws + WS_DACC)) + 3, accd);
}

// ---------------- k0: zero barriers + accumulators ----------------
__global__ __launch_bounds__(128) void k0_init(float* __restrict__ ws) {
  const int tid = threadIdx.x;
  if (tid < 64) ((unsigned*)(ws + WS_GBAR))[tid] = 0u;
  if (tid == 64) ((double*)(ws + WS_DACC))[1] = 0.0;
  if (tid == 65) ((double*)(ws + WS_DACC))[2] = 0.0;
  if (tid == 66) ((double*)(ws + WS_DACC))[3] = 0.0;
}

// ---------------- the fused kernel ----------------
__global__ __launch_bounds__(256) void mega(
    const float* __restrict__ obs, const float* __restrict__ mpm,
    const float* __restrict__ mpc, const float* __restrict__ mtw,
    const float* __restrict__ mtb, const float* __restrict__ mtc,
    const float* __restrict__ mew, const float* __restrict__ meb,
    const float* __restrict__ mec, const float* __restrict__ vpm,
    const float* __restrict__ vpc, const float* __restrict__ vtw,
    const float* __restrict__ vtb, const float* __restrict__ vtc,
    const float* __restrict__ vew, const float* __restrict__ veb,
    const float* __restrict__ vcc, float* __restrict__ ws,
    float* __restrict__ out) {
  __shared__ float sm[15232];
  __shared__ float red[4];
  const int tid = threadIdx.x, blk = blockIdx.x;
  unsigned* bars = (unsigned*)(ws + WS_GBAR);
  int bix = 0;

  // ---- P0: 6 constant SPD inverses ----
  if (blk < 6) {
    const float* src = blk==0?mtc : blk==1?mec : blk==2?mpc : blk==3?vtc : blk==4?vcc : vpc;
    float* dst = ws + (blk==0?WS_MTP : blk==1?WS_MEP : blk==2?WS_MPP :
                       blk==3?WS_QI  : blk==4?WS_RI  : WS_P0I);
    if (tid < 64) {
      float a[32]; const int cc = tid & 31;
#pragma unroll
      for (int r = 0; r < 32; ++r)
        a[r] = (tid < 32) ? src[r*32 + cc] : ((r == tid - 32) ? 1.f : 0.f);
      const double pp = gj_inv32(a);
      if (tid >= 32) {
        const int c2 = tid - 32;
#pragma unroll
        for (int r = 0; r < 32; ++r) dst[r*32 + c2] = a[r];
      }
      if (tid == 0 && blk < 3) ws[WS_LDS3 + blk] = (float)log(pp);
    }
  }
  gridbar(bars, bix++);

  // ---- P1: derived constants ----
  if (blk == 0) dev_k2(obs, vpm, vtw, vtb, vew, veb, mtw, mew, ws, tid);
  gridbar(bars, bix++);

  // ---- P2: b0 operator squarings; others YT ----
  if (blk == 0) {
    dev_compose(ws, sm, tid);
  } else {
    for (int tb = blk - 1; tb < NCH; tb += NB - 1) {
      const int t = tb*CH + (tid >> 5), i = tid & 31;
      float s = ws[WS_QIVTB + i] - ws[WS_CTB + i];
      for (int k = 0; k < 32; ++k)
        s += ws[WS_HTRI + i*32 + k] * (obs[t*32 + k] - veb[k]);
      ws[WS_YT + t*32 + i] = s;
    }
  }
  gridbar(bars, bix++);

  // ---- boundary tree: levels h=5..0 ----
  for (int h = 5; h >= 0; --h) {
    const int width = 32 >> h;
    if (blk < width) {
      const int stride = 1 << h;
      const int csrc = 2*blk*stride, cdst = csrc + stride;
      const float* OP = ws + WS_OPS + h*3072;     // (K,A,G) of Phi^{8*2^h}
      float *Mi = sm, *Al = sm + 1056, *V1 = sm + 2112;
      const int r = tid >> 3, c4 = (tid & 7) * 4;
#pragma unroll
      for (int x = 0; x < 4; ++x)
        Mi[r*33 + c4 + x] = ws[WS_ZB + csrc*1024 + r*32 + c4 + x]
                          + OP[2048 + r*32 + c4 + x];
      stage_mat(OP + 1024, Al, tid);
      __syncthreads();
      if (tid < 64) wave_inv33(Mi, tid);
      __syncthreads();
      mm_rr(Al, Mi, V1, tid);
      __syncthreads();
      const int j = tid & 31, r0 = tid >> 5;
#pragma unroll
      for (int m = 0; m < 4; ++m) {
        const int ri = r0 + 8*m;
        float s = 0.f;
        for (int k = 0; k < 32; ++k) s += V1[ri*33+k] * Al[j*33+k];
        ws[WS_ZB + cdst*1024 + ri*32 + j] = OP[ri*32 + j] - s;
      }
    }
    gridbar(bars, bix++);
  }

  // ---- P9: chunk expansion (bcov_t, X_t, logdets) ----
  {
    float *Zl = sm, *Bcv = sm+1056, *Xs = sm+2112, *QiWl = sm+3168, *QHCl = sm+4224;
    const int c = blk, nst = (c == NCH-1) ? CH-1 : CH;
    const int j = tid & 31, r0 = tid >> 5;
    stage_mat(ws + WS_QIW, QiWl, tid);
    stage_mat(ws + WS_QHC, QHCl, tid);
    stage_mat(ws + WS_ZB + c*1024, Zl, tid);
    __syncthreads();
    double acc = 0.0;
    for (int i = 0; i < nst; ++i) {
      const int t = CH*c + 1 + i;
      if (tid < 64) {
        float a[32]; const int cc = tid & 31;
#pragma unroll
        for (int r = 0; r < 32; ++r)
          a[r] = (tid < 32) ? Zl[r*33+cc] : ((r == tid - 32) ? 1.f : 0.f);
        const double pp = gj_inv32(a);
        if (tid >= 32) {
          const int c2 = tid - 32;
#pragma unroll
          for (int r = 0; r < 32; ++r) {
            Bcv[r*33 + c2] = a[r];
            ws[WS_BCOV + t*1024 + r*32 + c2] = a[r];
          }
        }
        if (tid == 0) acc += -log(pp);
      }
      __syncthreads();
      mm_rr(QiWl, Bcv, Xs, tid);
      __syncthreads();
      destage_mat(Xs, ws + WS_X + t*1024, tid);
#pragma unroll
      for (int m = 0; m < 4; ++m) {
        const int ri = r0 + 8*m;
        float s = 0.f;
        for (int k = 0; k < 32; ++k) s += Xs[ri*33+k] * QiWl[j*33+k];
        Zl[ri*33+j] = QHCl[ri*33+j] - s;
      }
      __syncthreads();
    }
    if (c == NCH-1) destage_mat(Zl, ws + WS_Z512, tid);
    if (tid == 0) atomicAdd(((double*)(ws + WS_DACC)) + 1, acc);
  }
  gridbar(bars, bix++);

  // ---- P10: eta chunk compose ----
  if (blk < NCH-1) {
    dev_keta_a(ws, sm, tid, blk);
  } else {
    for (int e = tid; e < 1056; e += 256)
      ws[WS_CEA + e] = (e < 1024 && ((e >> 5) == (e & 31))) ? 1.f : 0.f;
  }
  gridbar(bars, bix++);

  // ---- eta prefix-scan: 6 levels ----
  dev_eta_lvl(ws, sm, WS_CEA, WS_CEB,  1, tid, blk); gridbar(bars, bix++);
  dev_eta_lvl(ws, sm, WS_CEB, WS_CEA,  2, tid, blk); gridbar(bars, bix++);
  dev_eta_lvl(ws, sm, WS_CEA, WS_CEB,  4, tid, blk); gridbar(bars, bix++);
  dev_eta_lvl(ws, sm, WS_CEB, WS_CEA,  8, tid, blk); gridbar(bars, bix++);
  dev_eta_lvl(ws, sm, WS_CEA, WS_CEB, 16, tid, blk); gridbar(bars, bix++);
  dev_eta_lvl(ws, sm, WS_CEB, WS_CEA, 32, tid, blk); gridbar(bars, bix++);

  // ---- P17: eta expand (ba_t, eta_511) ----
  dev_keta_b(ws, sm, tid, blk);
  gridbar(bars, bix++);

  // ---- P18: b0 kfin + S-scan slot0; others S chunk compose ----
  if (blk == 0) {
    if (tid < 64) {
      float a[32]; const int cc = tid & 31;
#pragma unroll
      for (int r = 0; r < 32; ++r) {
        const float v = ws[WS_Z512 + r*32 + cc] - ws[WS_CW + r*32 + cc];
        a[r] = (tid < 32) ? v : ((r == tid - 32) ? 1.f : 0.f);
      }
      const double pp = gj_inv32(a);
      if (tid >= 32) {
        const int c2 = tid - 32;
        float fmv = 0.f;
#pragma unroll
        for (int r = 0; r < 32; ++r) {
          ws[WS_FPT + r*32 + c2] = a[r];
          fmv += a[r] * ws[WS_ETAF + r];
        }
        ws[WS_FMT + c2] = fmv;
      }
      if (tid == 0) {
        double* d = (double*)(ws + WS_DACC);
        d[1] = 0.5 * (d[1] + (-log(pp)));
      }
    }
    for (int e = tid; e < 2048; e += 256)
      ws[WS_CEA + e] = (e < 1024 && ((e >> 5) == (e & 31))) ? 1.f : 0.f;
  } else {
    dev_ksa(mtw, ws, sm, tid, blk - 1);
  }
  gridbar(bars, bix++);

  // ---- S prefix-scan: 6 levels ----
  dev_ks_level(ws, sm, WS_CEA, WS_CEB,  1, tid, blk); gridbar(bars, bix++);
  dev_ks_level(ws, sm, WS_CEB, WS_CEA,  2, tid, blk); gridbar(bars, bix++);
  dev_ks_level(ws, sm, WS_CEA, WS_CEB,  4, tid, blk); gridbar(bars, bix++);
  dev_ks_level(ws, sm, WS_CEB, WS_CEA,  8, tid, blk); gridbar(bars, bix++);
  dev_ks_level(ws, sm, WS_CEA, WS_CEB, 16, tid, blk); gridbar(bars, bix++);
  dev_ks_level(ws, sm, WS_CEB, WS_CEA, 32, tid, blk); gridbar(bars, bix++);

  // ---- P25: S expand + trace terms ----
  dev_ksc(mtw, ws, sm, red, tid, blk);
  gridbar(bars, bix++);

  // ---- P26: G chunk compose ----
  if (blk < NCH-1) {
    dev_kga(ws, sm, tid, blk + 1);
  } else {
    for (int e = tid; e < 1056; e += 256)
      ws[WS_GEA + (NCH-1)*1056 + e] = (e < 1024 && ((e >> 5) == (e & 31))) ? 1.f : 0.f;
  }
  gridbar(bars, bix++);

  // ---- G suffix-scan: 6 levels ----
  dev_kg_level(ws, sm, WS_GEA, WS_GEB,  1, tid, blk); gridbar(bars, bix++);
  dev_kg_level(ws, sm, WS_GEB, WS_GEA,  2, tid, blk); gridbar(bars, bix++);
  dev_kg_level(ws, sm, WS_GEA, WS_GEB,  4, tid, blk); gridbar(bars, bix++);
  dev_kg_level(ws, sm, WS_GEB, WS_GEA,  8, tid, blk); gridbar(bars, bix++);
  dev_kg_level(ws, sm, WS_GEA, WS_GEB, 16, tid, blk); gridbar(bars, bix++);
  dev_kg_level(ws, sm, WS_GEB, WS_GEA, 32, tid, blk); gridbar(bars, bix++);

  // ---- P33: G expand + final per-s terms ----
  dev_kgb(obs, mpm, mtw, mtb, mew, meb, ws, sm, red, tid, blk);
  gridbar(bars, bix++);

  // ---- out ----
  if (blk == 0 && tid == 0) {
    const double* d = (const double*)(ws + WS_DACC);
    out[0] = (float)(d[0] + d[1] + d[2] + d[3]);
  }
}

extern "C" void kernel_launch(void* const* d_in, const int* in_sizes, int n_in,
                              void* d_out, int out_size, void* d_ws, size_t ws_size,
                              hipStream_t stream) {
  (void)in_sizes; (void)n_in; (void)out_size; (void)ws_size;
  const float* obs = (const float*)d_in[0];
  const float* mpm = (const float*)d_in[1];
  const float* mpc = (const float*)d_in[2];
  const float* mtw = (const float*)d_in[3];
  const float* mtb = (const float*)d_in[4];
  const float* mtc = (const float*)d_in[5];
  const float* mew = (const float*)d_in[6];
  const float* meb = (const float*)d_in[7];
  const float* mec = (const float*)d_in[8];
  const float* vpm = (const float*)d_in[9];
  const float* vpc = (const float*)d_in[10];
  const float* vtw = (const float*)d_in[11];
  const float* vtb = (const float*)d_in[12];
  const float* vtc = (const float*)d_in[13];
  const float* vew = (const float*)d_in[14];
  const float* veb = (const float*)d_in[15];
  const float* vcc = (const float*)d_in[16];
  float* ws  = (float*)d_ws;
  float* out = (float*)d_out;

  k0_init<<<1, 128, 0, stream>>>(ws);
  mega<<<NB, 256, 0, stream>>>(obs, mpm, mpc, mtw, mtb, mtc, mew, meb, mec,
                               vpm, vpc, vtw, vtb, vtc, vew, veb, vcc, ws, out);
}

// Round 5
// 834.056 us; speedup vs baseline: 40.8112x; 1.0049x over previous
//
#include <hip/hip_runtime.h>
#include <math.h>

#define TT 512
#define CH 8
#define NCH 64
#define NB 64
#define LOG2PI 1.8378770664093453

static_assert(TT == CH * NCH, "chunking");

// ---------------- workspace layout (float offsets) ----------------
enum : int {
  WS_X     = 0,                    // [TT][32][32] X_t (bA_t = X^T), t=1..511
  WS_BCOV  = WS_X    + TT*1024,    // [TT][32][32] bcov_t
  WS_BA    = WS_BCOV + TT*1024,    // [TT][32] ba_t
  WS_YT    = WS_BA   + TT*32,      // [TT][32] Wt = HtRi@(y_t-veb) + qivtb - ctb
  WS_MTP   = WS_YT   + TT*32,
  WS_MEP   = WS_MTP + 1024,
  WS_MPP   = WS_MEP + 1024,
  WS_QI    = WS_MPP + 1024,
  WS_RI    = WS_QI  + 1024,
  WS_P0I   = WS_RI  + 1024,
  WS_QIW   = WS_P0I + 1024,
  WS_CW    = WS_QIW + 1024,
  WS_HTRI  = WS_CW  + 1024,
  WS_HTRIH = WS_HTRI+ 1024,
  WS_TQ    = WS_HTRIH+1024,
  WS_EM    = WS_TQ  + 1024,
  WS_EML   = WS_EM  + 1024,
  WS_LAM0CW= WS_EML + 1024,        // Z_1
  WS_QHC   = WS_LAM0CW + 1024,
  WS_S1    = WS_QHC + 1024,
  WS_FPT   = WS_S1  + 1024,
  WS_ETA0  = WS_FPT + 1024,
  WS_CTB   = WS_ETA0 + 32,
  WS_QIVTB = WS_CTB + 32,
  WS_FMT   = WS_QIVTB + 32,
  WS_ETAF  = WS_FMT + 32,
  WS_LDS3  = WS_ETAF + 32,
  WS_DACC  = WS_LDS3 + 4,          // 4 doubles
  WS_Z512  = WS_DACC + 8,
  WS_OPS   = WS_Z512 + 1024,       // 6 ops x (K,A,G) x 1024
  WS_GBAR  = WS_OPS + 6*3072,      // 64 barrier counters
  WS_CEA   = WS_GBAR + 64,         // NCH*2048
  WS_CEB   = WS_CEA + NCH*2048,
  WS_END   = WS_CEB + NCH*2048
};
// time-disjoint aliases
enum : int {
  WS_ZB  = WS_CEB,     // boundary Z's (P2..P9, before any scan writes CEB)
  WS_GEA = WS_CEB,     // G-scan ping (P26+, after S-scan consumed)
  WS_GEB = WS_CEA
};
static_assert(WS_DACC % 2 == 0, "double alignment");

// ---------------- helpers ----------------
__device__ __forceinline__ float rlane(float v, int l) {
  return __uint_as_float(__builtin_amdgcn_readlane(__float_as_uint(v), l));
}

__device__ __forceinline__ double gj_inv32(float a[32]) {
  double pp = 1.0;
#pragma unroll
  for (int p = 0; p < 32; ++p) {
    const float piv = rlane(a[p], p);
    pp *= (double)piv;
    const float sc = a[p] * (1.0f / piv);
#pragma unroll
    for (int r = 0; r < 32; ++r) {
      if (r != p) a[r] -= rlane(a[r], p) * sc;
    }
    a[p] = sc;
  }
  return pp;
}

// invert 32x32 (stride-33 LDS) in place; call with tid<64 only
__device__ __forceinline__ double wave_inv33(float* M, int tid) {
  float a[32]; const int cc = tid & 31;
#pragma unroll
  for (int r = 0; r < 32; ++r)
    a[r] = (tid < 32) ? M[r*33 + cc] : ((r == tid - 32) ? 1.f : 0.f);
  const double pp = gj_inv32(a);
  if (tid >= 32) {
    const int c2 = tid - 32;
#pragma unroll
    for (int r = 0; r < 32; ++r) M[r*33 + c2] = a[r];
  }
  return pp;
}

__device__ __forceinline__ float block_reduce(float v, float* red, int tid) {
#pragma unroll
  for (int m = 32; m >= 1; m >>= 1) v += __shfl_xor(v, m, 64);
  if ((tid & 63) == 0) red[tid >> 6] = v;
  __syncthreads();
  return red[0] + red[1] + red[2] + red[3];
}

__device__ __forceinline__ void stage_mat(const float* __restrict__ g, float* L, int tid) {
  const int r = tid >> 3, c = (tid & 7) * 4;
  const float4 v = *(const float4*)(g + r*32 + c);
  L[r*33+c] = v.x; L[r*33+c+1] = v.y; L[r*33+c+2] = v.z; L[r*33+c+3] = v.w;
}
__device__ __forceinline__ void stage_matT(const float* __restrict__ g, float* L, int tid) {
  const int r = tid >> 3, c = (tid & 7) * 4;
  const float4 v = *(const float4*)(g + r*32 + c);
  L[(c  )*33+r] = v.x; L[(c+1)*33+r] = v.y; L[(c+2)*33+r] = v.z; L[(c+3)*33+r] = v.w;
}
__device__ __forceinline__ void destage_mat(const float* L, float* __restrict__ g, int tid) {
  const int r = tid >> 3, c = (tid & 7) * 4;
  float4 v = make_float4(L[r*33+c], L[r*33+c+1], L[r*33+c+2], L[r*33+c+3]);
  *(float4*)(g + r*32 + c) = v;
}

__device__ __forceinline__ void mm_rr(const float* A, const float* B, float* C, int tid) {
  const int j = tid & 31, r0 = tid >> 5;
#pragma unroll
  for (int m = 0; m < 4; ++m) {
    const int ri = r0 + 8*m;
    float s = 0.f;
    for (int k = 0; k < 32; ++k) s += A[ri*33+k] * B[j*33+k];
    C[ri*33+j] = s;
  }
}
__device__ __forceinline__ void mm_rr_mI(const float* A, const float* B, float* C, int tid) {
  const int j = tid & 31, r0 = tid >> 5;
#pragma unroll
  for (int m = 0; m < 4; ++m) {
    const int ri = r0 + 8*m;
    float s = 0.f;
    for (int k = 0; k < 32; ++k) s += A[ri*33+k] * B[j*33+k];
    C[ri*33+j] = s - ((ri == j) ? 1.f : 0.f);
  }
}
__device__ __forceinline__ void mm_p(const float* A, const float* B, float* C, int tid) {
  const int j = tid & 31, r0 = tid >> 5;
#pragma unroll
  for (int m = 0; m < 4; ++m) {
    const int ri = r0 + 8*m;
    float s = 0.f;
    for (int k = 0; k < 32; ++k) s += A[ri*33+k] * B[k*33+j];
    C[ri*33+j] = s;
  }
}
__device__ __forceinline__ void mm_tp(const float* A, const float* B, float* C, int tid) {
  const int j = tid & 31, r0 = tid >> 5;
#pragma unroll
  for (int m = 0; m < 4; ++m) {
    const int ri = r0 + 8*m;
    float s = 0.f;
    for (int k = 0; k < 32; ++k) s += A[k*33+ri] * B[k*33+j];
    C[ri*33+j] = s;
  }
}

// ---------------- grid barrier (device-scope, per-barrier counter) ----------------
__device__ __forceinline__ void gridbar(unsigned* bars, int idx) {
  __syncthreads();
  if (threadIdx.x == 0) {
    __threadfence();
    __hip_atomic_fetch_add(&bars[idx], 1u, __ATOMIC_RELEASE, __HIP_MEMORY_SCOPE_AGENT);
    while (__hip_atomic_load(&bars[idx], __ATOMIC_ACQUIRE, __HIP_MEMORY_SCOPE_AGENT)
           < (unsigned)NB)
      __builtin_amdgcn_s_sleep(1);
  }
  __syncthreads();
}

// ---------------- k2 body (block 0 only) ----------------
__device__ void dev_k2(const float* __restrict__ obs, const float* __restrict__ vpm,
                       const float* __restrict__ vtw, const float* __restrict__ vtb,
                       const float* __restrict__ vew, const float* __restrict__ veb,
                       const float* __restrict__ mtw, const float* __restrict__ mew,
                       float* __restrict__ ws, int tid) {
  const int j = tid & 31, r0 = tid >> 5;
#pragma unroll
  for (int m = 0; m < 4; ++m) {
    const int ri = r0 + 8*m;
    float s1 = 0.f, s2 = 0.f, s3 = 0.f, s4 = 0.f;
    for (int k = 0; k < 32; ++k) {
      s1 += ws[WS_QI  + ri*32 + k] * vtw[k*32 + j];
      s2 += vew[k*32 + ri] * ws[WS_RI + k*32 + j];
      s3 += ws[WS_MTP + ri*32 + k] * mtw[k*32 + j];
      s4 += ws[WS_MEP + ri*32 + k] * mew[k*32 + j];
    }
    ws[WS_QIW + ri*32 + j] = s1;
    ws[WS_HTRI + ri*32 + j] = s2;
    ws[WS_FPT + ri*32 + j] = s3;      // temp Mtp@mtw
    ws[WS_EML + ri*32 + j] = -0.5f * s4;
  }
  __syncthreads();
#pragma unroll
  for (int m = 0; m < 4; ++m) {
    const int ri = r0 + 8*m;
    float s1 = 0.f, s2 = 0.f, s3 = 0.f, s4 = 0.f;
    for (int k = 0; k < 32; ++k) {
      s1 += vtw[k*32 + ri] * ws[WS_QIW + k*32 + j];
      s2 += ws[WS_HTRI + ri*32 + k] * vew[k*32 + j];
      s3 += mtw[k*32 + ri] * ws[WS_FPT + k*32 + j];
      s4 += mew[k*32 + ri] * ws[WS_EML + k*32 + j];
    }
    ws[WS_CW + ri*32 + j] = s1;
    ws[WS_HTRIH + ri*32 + j] = s2;
    ws[WS_LAM0CW + ri*32 + j] = ws[WS_P0I + ri*32 + j] + s1 + s2;
    ws[WS_QHC    + ri*32 + j] = ws[WS_QI  + ri*32 + j] + s1 + s2;
    ws[WS_TQ + ri*32 + j] = s3;
    ws[WS_EM + ri*32 + j] = s4;
    ws[WS_S1 + ri*32 + j] = s4 - 0.5f * ws[WS_MPP + ri*32 + j];
  }
  if (tid < 32) {
    float s1 = 0.f, s2 = 0.f, s3 = 0.f;
    for (int k = 0; k < 32; ++k) {
      s1 += ws[WS_QIW + k*32 + tid] * vtb[k];
      s2 += ws[WS_P0I + tid*32 + k] * vpm[k]
          + ws[WS_HTRI + tid*32 + k] * (obs[k] - veb[k]);
      s3 += ws[WS_QI + tid*32 + k] * vtb[k];
    }
    ws[WS_CTB + tid] = s1;
    ws[WS_ETA0 + tid] = s2;
    ws[WS_QIVTB + tid] = s3;
  }
  __syncthreads();
  if (tid == 0) {
    const double ldmt = (double)ws[WS_LDS3 + 0];
    const double ldme = (double)ws[WS_LDS3 + 1];
    const double ldmp = (double)ws[WS_LDS3 + 2];
    const double ct_me = -0.5 * (32.0 * LOG2PI + ldme);
    const double ct_mt = -0.5 * (32.0 * LOG2PI + ldmt);
    const double ct_mp = -0.5 * (32.0 * LOG2PI + ldmp);
    double c = ct_mp + ct_me;
    c += (double)(TT - 1) * (ct_me + ct_mt + 0.5 * 32.0 * LOG2PI + 16.0);
    c += 0.5 * 32.0 * LOG2PI + 16.0;
    ((double*)(ws + WS_DACC))[0] = c;
  }
}

// ---------------- Riccati operator squaring (block 0) ----------------
__device__ void dev_compose(float* __restrict__ ws, float* sm, int tid) {
  float *Kc = sm,       *Ac = sm+1056,  *Gc = sm+2112;
  float *Kn = sm+3168,  *An = sm+4224,  *Gn = sm+5280;
  float *Mi = sm+6336,  *V1 = sm+7392,  *Wm = sm+8448;
  const int j = tid & 31, r0 = tid >> 5;
  stage_mat(ws + WS_QHC, Kc, tid);
  stage_mat(ws + WS_QIW, Ac, tid);
  for (int e = tid; e < 1056; e += 256) Gc[e] = 0.f;
  __syncthreads();
  for (int d = 0; d < 8; ++d) {          // builds Phi^{2^{d+1}}
    for (int e = tid; e < 1056; e += 256) Mi[e] = Kc[e] + Gc[e];
    __syncthreads();
    if (tid < 64) wave_inv33(Mi, tid);
    __syncthreads();
    mm_rr(Ac, Mi, V1, tid);   // A M^-1 (M^-1 sym)
    mm_tp(Ac, Mi, Wm, tid);   // A^T M^-1
    __syncthreads();
#pragma unroll
    for (int m = 0; m < 4; ++m) {
      const int ri = r0 + 8*m;
      float s1 = 0.f, s2 = 0.f, s3 = 0.f;
      for (int k = 0; k < 32; ++k) {
        const float v = V1[ri*33+k];
        s1 += v * Ac[j*33+k];
        s2 += v * Ac[k*33+j];
        s3 += Wm[ri*33+k] * Ac[k*33+j];
      }
      Kn[ri*33+j] = Kc[ri*33+j] - s1;
      An[ri*33+j] = s2;
      Gn[ri*33+j] = Gc[ri*33+j] - s3;
    }
    __syncthreads();
    float* tp;
    tp=Kc; Kc=Kn; Kn=tp;  tp=Ac; Ac=An; An=tp;  tp=Gc; Gc=Gn; Gn=tp;
    if (d >= 2) {                         // save Phi^8 .. Phi^256
      float* op = ws + WS_OPS + (d-2)*3072;
      destage_mat(Kc, op, tid);
      destage_mat(Ac, op + 1024, tid);
      destage_mat(Gc, op + 2048, tid);
    }
  }
  __syncthreads();
  const int e = tid * 4;                  // ZB[0] = Z_1
  *(float4*)(ws + WS_ZB + e) = *(const float4*)(ws + WS_LAM0CW + e);
}

// ---------------- eta machinery ----------------
__device__ void dev_keta_a(float* __restrict__ ws, float* sm, int tid, int c) {
  float *Aa = sm, *Ab = sm+1056, *Xl = sm+2112, *bb = sm+3168;
  const int t1 = CH*c + 1;
  stage_mat(ws + WS_X + t1*1024, Aa, tid);
  if (tid < 32) bb[tid] = ws[WS_YT + t1*32 + tid];
  __syncthreads();
  float *Acur = Aa, *Anew = Ab; int pb = 0;
  for (int t = t1 + 1; t <= t1 + CH - 1; ++t) {
    stage_mat(ws + WS_X + t*1024, Xl, tid);
    __syncthreads();
    mm_p(Xl, Acur, Anew, tid);
    if (tid < 32) {
      float s = ws[WS_YT + t*32 + tid];
      for (int k = 0; k < 32; ++k) s += Xl[tid*33+k] * bb[pb*32 + k];
      bb[(pb^1)*32 + tid] = s;
    }
    __syncthreads();
    float* tp = Acur; Acur = Anew; Anew = tp; pb ^= 1;
  }
  float* dst = ws + WS_CEA + (c+1)*1056;
  destage_mat(Acur, dst, tid);
  if (tid < 32) dst[1024 + tid] = bb[pb*32 + tid];
}

__device__ void dev_eta_lvl(float* __restrict__ ws, float* sm,
                            int inoff, int outoff, int step, int tid, int c) {
  const float* in = ws + inoff;
  float* out = ws + outoff;
  if (c < step) {
    for (int e = tid; e < 1056; e += 256) out[c*1056 + e] = in[c*1056 + e];
    return;
  }
  float *A1 = sm, *A0 = sm+1056, *Ar = sm+2112, *b0l = sm+3168;
  stage_mat(in + c*1056, A1, tid);
  stage_mat(in + (c-step)*1056, A0, tid);
  if (tid < 32) b0l[tid] = in[(c-step)*1056 + 1024 + tid];
  __syncthreads();
  mm_p(A1, A0, Ar, tid);
  if (tid < 32) {
    float s = in[c*1056 + 1024 + tid];
    for (int k = 0; k < 32; ++k) s += A1[tid*33+k] * b0l[k];
    out[c*1056 + 1024 + tid] = s;
  }
  __syncthreads();
  destage_mat(Ar, out + c*1056, tid);
}

__device__ void dev_keta_b(float* __restrict__ ws, float* sm, int tid, int c) {
  float *Ap = sm, *Bl = sm+1056, *Xl = sm+2112, *zeta = sm+3168, *zn = sm+3200;
  const int nst = (c == NCH-1) ? CH-1 : CH;
  stage_mat(ws + WS_CEA + c*1056, Ap, tid);
  __syncthreads();
  if (tid < 32) {
    float s = ws[WS_CEA + c*1056 + 1024 + tid];
    for (int k = 0; k < 32; ++k)
      s += Ap[tid*33+k] * (ws[WS_ETA0 + k] - ws[WS_CTB + k]);
    zeta[tid] = s;
  }
  __syncthreads();
  for (int i = 0; i < nst; ++i) {
    const int t = CH*c + 1 + i;
    stage_mat(ws + WS_BCOV + t*1024, Bl, tid);
    stage_mat(ws + WS_X + t*1024, Xl, tid);
    __syncthreads();
    if (tid < 32) {
      float s = 0.f;
      for (int k = 0; k < 32; ++k) s += Bl[tid*33+k] * zeta[k];
      ws[WS_BA + t*32 + tid] = s;
    } else if (tid < 64) {
      const int i2 = tid - 32;
      float s = ws[WS_YT + t*32 + i2];
      for (int k = 0; k < 32; ++k) s += Xl[i2*33+k] * zeta[k];
      zn[i2] = s;
    }
    __syncthreads();
    if (tid < 32) zeta[tid] = zn[tid];
    __syncthreads();
  }
  if (c == NCH-1 && tid < 32)
    ws[WS_ETAF + tid] = zeta[tid] + ws[WS_CTB + tid];
}

// ---------------- S machinery ----------------
__device__ void dev_ksa(const float* __restrict__ mtw, float* __restrict__ ws,
                        float* sm, int tid, int c) {
  float *BTa=sm,      *BTb=sm+1056,  *Ka=sm+2112,  *Kb=sm+3168, *JT=sm+4224,
        *W1T=sm+5280, *Tk=sm+6336,   *Xl=sm+7392,  *mtwl=sm+8448,
        *Mtpl=sm+9504,*Eml=sm+10560;
  const int t1 = CH*c + 1, t2 = CH*c + CH;
  const int j = tid & 31, r0 = tid >> 5;
  stage_mat(mtw, mtwl, tid);
  stage_mat(ws + WS_MTP, Mtpl, tid);
  stage_mat(ws + WS_EM, Eml, tid);
  stage_mat(ws + WS_X + t1*1024, Xl, tid);
  stage_matT(ws + WS_X + t1*1024, BTa, tid);
  __syncthreads();
  mm_rr_mI(Xl, mtwl, JT, tid);  __syncthreads();
  mm_rr(JT, Mtpl, W1T, tid);    __syncthreads();
#pragma unroll
  for (int m = 0; m < 4; ++m) {
    const int ri = r0 + 8*m;
    float s = 0.f;
    for (int k = 0; k < 32; ++k) s += W1T[ri*33+k] * JT[j*33+k];
    Ka[ri*33+j] = Eml[ri*33+j] - 0.5f * s;
  }
  __syncthreads();
  float *BTc = BTa, *BTn = BTb, *Kc = Ka, *Kn = Kb;
  for (int t = t1 + 1; t <= t2; ++t) {
    stage_mat(ws + WS_X + t*1024, Xl, tid);
    __syncthreads();
    mm_rr_mI(Xl, mtwl, JT, tid);
    mm_rr(BTc, Xl, BTn, tid);
    mm_rr(Xl, Kc, Tk, tid);
    __syncthreads();
    mm_rr(JT, Mtpl, W1T, tid);
    mm_rr(Tk, Xl, Kn, tid);
    __syncthreads();
#pragma unroll
    for (int m = 0; m < 4; ++m) {
      const int ri = r0 + 8*m;
      float s = 0.f;
      for (int k = 0; k < 32; ++k) s += W1T[ri*33+k] * JT[j*33+k];
      Kn[ri*33+j] += Eml[ri*33+j] - 0.5f * s;
    }
    __syncthreads();
    float* tp = BTc; BTc = BTn; BTn = tp;
    tp = Kc; Kc = Kn; Kn = tp;
  }
  float* dst = ws + WS_CEA + (c+1)*2048;
  destage_mat(BTc, dst, tid);
  destage_mat(Kc, dst + 1024, tid);
}

__device__ void dev_ks_level(float* __restrict__ ws, float* sm,
                             int inoff, int outoff, int step, int tid, int c) {
  const float* in = ws + inoff;
  float* out = ws + outoff;
  if (c < step) {
    const int base = c*2048 + tid*8;
#pragma unroll
    for (int x = 0; x < 8; ++x) out[base + x] = in[base + x];
    return;
  }
  float *BTo=sm, *Ko=sm+1056, *BTn=sm+2112, *tmp=sm+3168, *BTr=sm+4224;
  stage_mat(in + (c-step)*2048, BTo, tid);
  stage_mat(in + (c-step)*2048 + 1024, Ko, tid);
  stage_mat(in + c*2048, BTn, tid);
  __syncthreads();
  mm_p(BTo, BTn, BTr, tid);
  mm_p(Ko, BTn, tmp, tid);
  __syncthreads();
  const int j = tid & 31, r0 = tid >> 5;
#pragma unroll
  for (int m = 0; m < 4; ++m) {
    const int ri = r0 + 8*m;
    float s = 0.f;
    for (int k = 0; k < 32; ++k) s += BTn[k*33+ri] * tmp[k*33+j];
    out[c*2048 + ri*32 + j] = BTr[ri*33+j];
    out[c*2048 + 1024 + ri*32 + j] = s + in[c*2048 + 1024 + ri*32 + j];
  }
}

__device__ void dev_ksc(const float* __restrict__ mtw, float* __restrict__ ws,
                        float* sm, float* red, int tid, int c) {
  float *S=sm,        *S2=sm+1056,  *JT=sm+2112,  *W1T=sm+3168, *T1=sm+4224,
        *Xl=sm+5280,  *Bcl=sm+6336, *BTP=sm+7392, *Mtpl=sm+8448,
        *Eml=sm+9504, *TQl=sm+10560,*mtwl=sm+11616;
  const int j = tid & 31, r0 = tid >> 5;
  stage_mat(mtw, mtwl, tid);
  stage_mat(ws + WS_MTP, Mtpl, tid);
  stage_mat(ws + WS_EM, Eml, tid);
  stage_mat(ws + WS_TQ, TQl, tid);
  stage_mat(ws + WS_CEA + c*2048, BTP, tid);
  stage_mat(ws + WS_S1, S2, tid);
  __syncthreads();
  mm_p(S2, BTP, T1, tid);
  __syncthreads();
#pragma unroll
  for (int m = 0; m < 4; ++m) {
    const int ri = r0 + 8*m;
    float s = 0.f;
    for (int k = 0; k < 32; ++k) s += BTP[k*33+ri] * T1[k*33+j];
    S[ri*33+j] = s + ws[WS_CEA + c*2048 + 1024 + ri*32 + j];
  }
  __syncthreads();
  double accd = 0.0;
  for (int i = 0; i < CH; ++i) {
    const int t = CH*c + 1 + i;
    if (t >= TT) break;
    stage_mat(ws + WS_X + t*1024, Xl, tid);
    stage_mat(ws + WS_BCOV + t*1024, Bcl, tid);
    __syncthreads();
    mm_rr_mI(Xl, mtwl, JT, tid);
    mm_rr(Xl, S, T1, tid);
    float part = 0.f;
#pragma unroll
    for (int m = 0; m < 4; ++m) {
      const int ri = r0 + 8*m;
      part += (S[ri*33+j] - 0.5f*TQl[ri*33+j]) * Bcl[ri*33+j];
    }
    const float r2 = block_reduce(part, red, tid);
    if (tid == 0) accd += (double)r2;
    mm_rr(JT, Mtpl, W1T, tid);
    mm_rr(T1, Xl, S2, tid);
    __syncthreads();
#pragma unroll
    for (int m = 0; m < 4; ++m) {
      const int ri = r0 + 8*m;
      float s = 0.f;
      for (int k = 0; k < 32; ++k) s += W1T[ri*33+k] * JT[j*33+k];
      S[ri*33+j] = S2[ri*33+j] + Eml[ri*33+j] - 0.5f * s;
    }
    __syncthreads();
  }
  if (tid == 0) atomicAdd(((double*)(ws + WS_DACC)) + 2, accd);
}

// ---------------- G machinery ----------------
__device__ void dev_kga(float* __restrict__ ws, float* sm, int tid, int c) {
  float *ATa = sm, *ATb = sm+1056, *XTl = sm+2112, *bb = sm+3168;
  const int t1 = CH*c + 1;
  const int t2 = (CH*c + CH < TT) ? CH*c + CH : TT - 1;
  stage_mat(ws + WS_X + t2*1024, ATa, tid);
  if (tid < 32) bb[tid] = ws[WS_BA + t2*32 + tid];
  __syncthreads();
  float *ATc = ATa, *ATn = ATb;
  int pb = 0;
  for (int t = t2 - 1; t >= t1; --t) {
    stage_matT(ws + WS_X + t*1024, XTl, tid);
    __syncthreads();
    mm_rr(ATc, XTl, ATn, tid);
    if (tid < 32) {
      float s = ws[WS_BA + t*32 + tid];
      for (int k = 0; k < 32; ++k) s += XTl[tid*33+k] * bb[pb*32 + k];
      bb[(pb^1)*32 + tid] = s;
    }
    __syncthreads();
    float* tp = ATc; ATc = ATn; ATn = tp; pb ^= 1;
  }
  float* dst = ws + WS_GEA + (c-1)*1056;
  destage_mat(ATc, dst, tid);
  if (tid < 32) dst[1024 + tid] = bb[pb*32 + tid];
}

__device__ void dev_kg_level(float* __restrict__ ws, float* sm,
                             int inoff, int outoff, int step, int tid, int c) {
  const float* in = ws + inoff;
  float* out = ws + outoff;
  if (c + step > NCH - 1) {
    const int base = c*1056;
    const int e = tid*4;
#pragma unroll
    for (int x = 0; x < 4; ++x) out[base + e + x] = in[base + e + x];
    if (tid < 32) out[base + 1024 + tid] = in[base + 1024 + tid];
    return;
  }
  float *AT1 = sm, *AT2 = sm+1056, *ATr = sm+2112, *b2l = sm+3168;
  stage_mat(in + c*1056, AT1, tid);
  stage_mat(in + (c+step)*1056, AT2, tid);
  if (tid < 32) b2l[tid] = in[(c+step)*1056 + 1024 + tid];
  __syncthreads();
  mm_p(AT2, AT1, ATr, tid);
  if (tid < 32) {
    float s = in[c*1056 + 1024 + tid];
    for (int k = 0; k < 32; ++k) s += AT1[k*33+tid] * b2l[k];
    out[c*1056 + 1024 + tid] = s;
  }
  __syncthreads();
  destage_mat(ATr, out + c*1056, tid);
}

__device__ void dev_kgb(const float* __restrict__ obs, const float* __restrict__ mpm,
                        const float* __restrict__ mtw, const float* __restrict__ mtb,
                        const float* __restrict__ mew, const float* __restrict__ meb,
                        float* __restrict__ ws, float* sm, float* red, int tid, int c) {
  float *ATa=sm,       *ATb=sm+1056,  *XTl=sm+2112,  *Y1=sm+3168,  *Y2=sm+4224,
        *Jb=sm+5280,   *M2T=sm+6336,  *E1=sm+7392,   *mewl=sm+8448,*EmLl=sm+9504,
        *fPl=sm+10560, *Mtpl=sm+11616,*Mepl=sm+12672,*mtwl=sm+13728;
  float *vec = sm + 14784;
  float *fml=vec, *mebl=vec+32, *mtbl=vec+64, *mpml=vec+96, *yl=vec+128,
        *bal=vec+160, *gv=vec+192, *cme=vec+224, *cmo=vec+256, *bv=vec+288;
  const int j = tid & 31, r0 = tid >> 5;
  stage_mat(mew, mewl, tid);
  stage_mat(ws + WS_EML, EmLl, tid);
  stage_mat(ws + WS_FPT, fPl, tid);
  stage_mat(ws + WS_MTP, Mtpl, tid);
  stage_mat(ws + WS_MEP, Mepl, tid);
  stage_mat(mtw, mtwl, tid);
  stage_mat(ws + WS_GEA + c*1056, ATa, tid);
  if (tid < 32) {
    fml[tid] = ws[WS_FMT + tid];
    mebl[tid] = meb[tid]; mtbl[tid] = mtb[tid]; mpml[tid] = mpm[tid];
    bv[tid] = ws[WS_GEA + c*1056 + 1024 + tid];
  }
  __syncthreads();
  float *ATc = ATa, *ATo = ATb;
  int bc = 0;
  double accd = 0.0;
  for (int s = CH*c + CH - 1; s >= CH*c; --s) {
    if (s < TT-1) stage_matT(ws + WS_X + (s+1)*1024, XTl, tid);
    if (s == 0)   stage_mat(ws + WS_MPP, Jb, tid);
    if (tid < 32) {
      yl[tid] = obs[s*32 + tid];
      if (s >= 1) bal[tid] = ws[WS_BA + s*32 + tid];
    }
    __syncthreads();
    if (s < TT-1) {
      mm_rr(ATc, XTl, ATo, tid);
      if (tid < 32) {
        float v = ws[WS_BA + (s+1)*32 + tid];
        for (int k = 0; k < 32; ++k) v += XTl[tid*33+k] * bv[bc*32 + k];
        bv[(bc^1)*32 + tid] = v;
      }
    }
    __syncthreads();
    const float* AT = (s < TT-1) ? ATo : ATc;
    const float* bl = (s < TT-1) ? (bv + (bc^1)*32) : (bv + bc*32);
    mm_rr(mewl, AT, Y1, tid);
    mm_rr(EmLl, AT, Y2, tid);
    if (s >= 1) {
      const float* Xg = ws + WS_X + s*1024;
      float s0 = 0.f, s1 = 0.f, s2 = 0.f, s3 = 0.f;
      for (int k = 0; k < 32; ++k) {
        const float b = Xg[j*32 + k];
        s0 += mtwl[(r0     )*33+k] * b;
        s1 += mtwl[(r0 +  8)*33+k] * b;
        s2 += mtwl[(r0 + 16)*33+k] * b;
        s3 += mtwl[(r0 + 24)*33+k] * b;
      }
      Jb[(r0     )*33+j] = s0 - ((r0      == j) ? 1.f : 0.f);
      Jb[(r0 +  8)*33+j] = s1 - ((r0 +  8 == j) ? 1.f : 0.f);
      Jb[(r0 + 16)*33+j] = s2 - ((r0 + 16 == j) ? 1.f : 0.f);
      Jb[(r0 + 24)*33+j] = s3 - ((r0 + 24 == j) ? 1.f : 0.f);
    }
    if (tid < 32) {
      float g = bl[tid];
      for (int k = 0; k < 32; ++k) g += AT[k*33+tid] * fml[k];
      gv[tid] = g;
    }
    __syncthreads();
    if (s >= 1) mm_rr(AT, Jb, M2T, tid);
    if (tid < 32) {
      float s1v = mebl[tid] - yl[tid];
      for (int k = 0; k < 32; ++k) s1v += mewl[tid*33+k] * gv[k];
      cme[tid] = s1v;
      float s2v;
      if (s >= 1) {
        s2v = mtbl[tid];
        for (int k = 0; k < 32; ++k)
          s2v += Jb[tid*33+k] * gv[k] + mtwl[tid*33+k] * bal[k];
      } else {
        s2v = gv[tid] - mpml[tid];
      }
      cmo[tid] = s2v;
    }
    __syncthreads();
    const float* M2Tp = (s >= 1) ? M2T : AT;
    const float* Mqp  = (s >= 1) ? Mtpl : Jb;
    mm_rr(Mqp, M2Tp, E1, tid);
    __syncthreads();
    float part = 0.f;
#pragma unroll
    for (int m = 0; m < 4; ++m) {
      const int ri = r0 + 8*m;
      float y3 = 0.f, e2 = 0.f;
      for (int k = 0; k < 32; ++k) {
        y3 += Y2[ri*33+k] * fPl[j*33+k];
        e2 += fPl[j*33+k] * M2Tp[ri*33+k];
      }
      part += y3 * Y1[j*33+ri]
            - 0.5f * E1[ri*33+j] * e2
            - 0.5f * cme[ri] * Mepl[ri*33+j] * cme[j]
            - 0.5f * cmo[ri] * Mqp[ri*33+j] * cmo[j];
    }
    const float r2 = block_reduce(part, red, tid);
    if (tid == 0) accd += (double)r2;
    if (s < TT-1) { float* tp = ATc; ATc = ATo; ATo = tp; bc ^= 1; }
    __syncthreads();
  }
  if (tid == 0) atomicAdd(((double*)(ws + WS_DACC)) + 3, accd);
}

// ---------------- k0: zero barriers + accumulators ----------------
__global__ __launch_bounds__(128) void k0_init(float* __restrict__ ws) {
  const int tid = threadIdx.x;
  if (tid < 64) ((unsigned*)(ws + WS_GBAR))[tid] = 0u;
  if (tid == 64) ((double*)(ws + WS_DACC))[1] = 0.0;
  if (tid == 65) ((double*)(ws + WS_DACC))[2] = 0.0;
  if (tid == 66) ((double*)(ws + WS_DACC))[3] = 0.0;
}

// ---------------- the fused kernel ----------------
__global__ __launch_bounds__(256) void mega(
    const float* __restrict__ obs, const float* __restrict__ mpm,
    const float* __restrict__ mpc, const float* __restrict__ mtw,
    const float* __restrict__ mtb, const float* __restrict__ mtc,
    const float* __restrict__ mew, const float* __restrict__ meb,
    const float* __restrict__ mec, const float* __restrict__ vpm,
    const float* __restrict__ vpc, const float* __restrict__ vtw,
    const float* __restrict__ vtb, const float* __restrict__ vtc,
    const float* __restrict__ vew, const float* __restrict__ veb,
    const float* __restrict__ vcc, float* __restrict__ ws,
    float* __restrict__ out) {
  __shared__ float sm[15232];
  __shared__ float red[4];
  const int tid = threadIdx.x, blk = blockIdx.x;
  unsigned* bars = (unsigned*)(ws + WS_GBAR);
  int bix = 0;

  // ---- P0: 6 constant SPD inverses ----
  if (blk < 6) {
    const float* src = blk==0?mtc : blk==1?mec : blk==2?mpc : blk==3?vtc : blk==4?vcc : vpc;
    float* dst = ws + (blk==0?WS_MTP : blk==1?WS_MEP : blk==2?WS_MPP :
                       blk==3?WS_QI  : blk==4?WS_RI  : WS_P0I);
    if (tid < 64) {
      float a[32]; const int cc = tid & 31;
#pragma unroll
      for (int r = 0; r < 32; ++r)
        a[r] = (tid < 32) ? src[r*32 + cc] : ((r == tid - 32) ? 1.f : 0.f);
      const double pp = gj_inv32(a);
      if (tid >= 32) {
        const int c2 = tid - 32;
#pragma unroll
        for (int r = 0; r < 32; ++r) dst[r*32 + c2] = a[r];
      }
      if (tid == 0 && blk < 3) ws[WS_LDS3 + blk] = (float)log(pp);
    }
  }
  gridbar(bars, bix++);

  // ---- P1: derived constants ----
  if (blk == 0) dev_k2(obs, vpm, vtw, vtb, vew, veb, mtw, mew, ws, tid);
  gridbar(bars, bix++);

  // ---- P2: b0 operator squarings; others YT ----
  if (blk == 0) {
    dev_compose(ws, sm, tid);
  } else {
    for (int tb = blk - 1; tb < NCH; tb += NB - 1) {
      const int t = tb*CH + (tid >> 5), i = tid & 31;
      float s = ws[WS_QIVTB + i] - ws[WS_CTB + i];
      for (int k = 0; k < 32; ++k)
        s += ws[WS_HTRI + i*32 + k] * (obs[t*32 + k] - veb[k]);
      ws[WS_YT + t*32 + i] = s;
    }
  }
  gridbar(bars, bix++);

  // ---- boundary tree: levels h=5..0 ----
  for (int h = 5; h >= 0; --h) {
    const int width = 32 >> h;
    if (blk < width) {
      const int stride = 1 << h;
      const int csrc = 2*blk*stride, cdst = csrc + stride;
      const float* OP = ws + WS_OPS + h*3072;     // (K,A,G) of Phi^{8*2^h}
      float *Mi = sm, *Al = sm + 1056, *V1 = sm + 2112;
      const int r = tid >> 3, c4 = (tid & 7) * 4;
#pragma unroll
      for (int x = 0; x < 4; ++x)
        Mi[r*33 + c4 + x] = ws[WS_ZB + csrc*1024 + r*32 + c4 + x]
                          + OP[2048 + r*32 + c4 + x];
      stage_mat(OP + 1024, Al, tid);
      __syncthreads();
      if (tid < 64) wave_inv33(Mi, tid);
      __syncthreads();
      mm_rr(Al, Mi, V1, tid);
      __syncthreads();
      const int j = tid & 31, r0 = tid >> 5;
#pragma unroll
      for (int m = 0; m < 4; ++m) {
        const int ri = r0 + 8*m;
        float s = 0.f;
        for (int k = 0; k < 32; ++k) s += V1[ri*33+k] * Al[j*33+k];
        ws[WS_ZB + cdst*1024 + ri*32 + j] = OP[ri*32 + j] - s;
      }
    }
    gridbar(bars, bix++);
  }

  // ---- P9: chunk expansion (bcov_t, X_t, logdets) ----
  {
    float *Zl = sm, *Bcv = sm+1056, *Xs = sm+2112, *QiWl = sm+3168, *QHCl = sm+4224;
    const int c = blk, nst = (c == NCH-1) ? CH-1 : CH;
    const int j = tid & 31, r0 = tid >> 5;
    stage_mat(ws + WS_QIW, QiWl, tid);
    stage_mat(ws + WS_QHC, QHCl, tid);
    stage_mat(ws + WS_ZB + c*1024, Zl, tid);
    __syncthreads();
    double acc = 0.0;
    for (int i = 0; i < nst; ++i) {
      const int t = CH*c + 1 + i;
      if (tid < 64) {
        float a[32]; const int cc = tid & 31;
#pragma unroll
        for (int r = 0; r < 32; ++r)
          a[r] = (tid < 32) ? Zl[r*33+cc] : ((r == tid - 32) ? 1.f : 0.f);
        const double pp = gj_inv32(a);
        if (tid >= 32) {
          const int c2 = tid - 32;
#pragma unroll
          for (int r = 0; r < 32; ++r) {
            Bcv[r*33 + c2] = a[r];
            ws[WS_BCOV + t*1024 + r*32 + c2] = a[r];
          }
        }
        if (tid == 0) acc += -log(pp);
      }
      __syncthreads();
      mm_rr(QiWl, Bcv, Xs, tid);
      __syncthreads();
      destage_mat(Xs, ws + WS_X + t*1024, tid);
#pragma unroll
      for (int m = 0; m < 4; ++m) {
        const int ri = r0 + 8*m;
        float s = 0.f;
        for (int k = 0; k < 32; ++k) s += Xs[ri*33+k] * QiWl[j*33+k];
        Zl[ri*33+j] = QHCl[ri*33+j] - s;
      }
      __syncthreads();
    }
    if (c == NCH-1) destage_mat(Zl, ws + WS_Z512, tid);
    if (tid == 0) atomicAdd(((double*)(ws + WS_DACC)) + 1, acc);
  }
  gridbar(bars, bix++);

  // ---- P10: eta chunk compose ----
  if (blk < NCH-1) {
    dev_keta_a(ws, sm, tid, blk);
  } else {
    for (int e = tid; e < 1056; e += 256)
      ws[WS_CEA + e] = (e < 1024 && ((e >> 5) == (e & 31))) ? 1.f : 0.f;
  }
  gridbar(bars, bix++);

  // ---- eta prefix-scan: 6 levels ----
  dev_eta_lvl(ws, sm, WS_CEA, WS_CEB,  1, tid, blk); gridbar(bars, bix++);
  dev_eta_lvl(ws, sm, WS_CEB, WS_CEA,  2, tid, blk); gridbar(bars, bix++);
  dev_eta_lvl(ws, sm, WS_CEA, WS_CEB,  4, tid, blk); gridbar(bars, bix++);
  dev_eta_lvl(ws, sm, WS_CEB, WS_CEA,  8, tid, blk); gridbar(bars, bix++);
  dev_eta_lvl(ws, sm, WS_CEA, WS_CEB, 16, tid, blk); gridbar(bars, bix++);
  dev_eta_lvl(ws, sm, WS_CEB, WS_CEA, 32, tid, blk); gridbar(bars, bix++);

  // ---- P17: eta expand (ba_t, eta_511) ----
  dev_keta_b(ws, sm, tid, blk);
  gridbar(bars, bix++);

  // ---- P18: b0 kfin + S-scan slot0; others S chunk compose ----
  if (blk == 0) {
    if (tid < 64) {
      float a[32]; const int cc = tid & 31;
#pragma unroll
      for (int r = 0; r < 32; ++r) {
        const float v = ws[WS_Z512 + r*32 + cc] - ws[WS_CW + r*32 + cc];
        a[r] = (tid < 32) ? v : ((r == tid - 32) ? 1.f : 0.f);
      }
      const double pp = gj_inv32(a);
      if (tid >= 32) {
        const int c2 = tid - 32;
        float fmv = 0.f;
#pragma unroll
        for (int r = 0; r < 32; ++r) {
          ws[WS_FPT + r*32 + c2] = a[r];
          fmv += a[r] * ws[WS_ETAF + r];
        }
        ws[WS_FMT + c2] = fmv;
      }
      if (tid == 0) {
        double* d = (double*)(ws + WS_DACC);
        d[1] = 0.5 * (d[1] + (-log(pp)));
      }
    }
    for (int e = tid; e < 2048; e += 256)
      ws[WS_CEA + e] = (e < 1024 && ((e >> 5) == (e & 31))) ? 1.f : 0.f;
  } else {
    dev_ksa(mtw, ws, sm, tid, blk - 1);
  }
  gridbar(bars, bix++);

  // ---- S prefix-scan: 6 levels ----
  dev_ks_level(ws, sm, WS_CEA, WS_CEB,  1, tid, blk); gridbar(bars, bix++);
  dev_ks_level(ws, sm, WS_CEB, WS_CEA,  2, tid, blk); gridbar(bars, bix++);
  dev_ks_level(ws, sm, WS_CEA, WS_CEB,  4, tid, blk); gridbar(bars, bix++);
  dev_ks_level(ws, sm, WS_CEB, WS_CEA,  8, tid, blk); gridbar(bars, bix++);
  dev_ks_level(ws, sm, WS_CEA, WS_CEB, 16, tid, blk); gridbar(bars, bix++);
  dev_ks_level(ws, sm, WS_CEB, WS_CEA, 32, tid, blk); gridbar(bars, bix++);

  // ---- P25: S expand + trace terms ----
  dev_ksc(mtw, ws, sm, red, tid, blk);
  gridbar(bars, bix++);

  // ---- P26: G chunk compose ----
  if (blk < NCH-1) {
    dev_kga(ws, sm, tid, blk + 1);
  } else {
    for (int e = tid; e < 1056; e += 256)
      ws[WS_GEA + (NCH-1)*1056 + e] = (e < 1024 && ((e >> 5) == (e & 31))) ? 1.f : 0.f;
  }
  gridbar(bars, bix++);

  // ---- G suffix-scan: 6 levels ----
  dev_kg_level(ws, sm, WS_GEA, WS_GEB,  1, tid, blk); gridbar(bars, bix++);
  dev_kg_level(ws, sm, WS_GEB, WS_GEA,  2, tid, blk); gridbar(bars, bix++);
  dev_kg_level(ws, sm, WS_GEA, WS_GEB,  4, tid, blk); gridbar(bars, bix++);
  dev_kg_level(ws, sm, WS_GEB, WS_GEA,  8, tid, blk); gridbar(bars, bix++);
  dev_kg_level(ws, sm, WS_GEA, WS_GEB, 16, tid, blk); gridbar(bars, bix++);
  dev_kg_level(ws, sm, WS_GEB, WS_GEA, 32, tid, blk); gridbar(bars, bix++);

  // ---- P33: G expand + final per-s terms ----
  dev_kgb(obs, mpm, mtw, mtb, mew, meb, ws, sm, red, tid, blk);
  gridbar(bars, bix++);

  // ---- out ----
  if (blk == 0 && tid == 0) {
    const double* d = (const double*)(ws + WS_DACC);
    out[0] = (float)(d[0] + d[1] + d[2] + d[3]);
  }
}

extern "C" void kernel_launch(void* const* d_in, const int* in_sizes, int n_in,
                              void* d_out, int out_size, void* d_ws, size_t ws_size,
                              hipStream_t stream) {
  (void)in_sizes; (void)n_in; (void)out_size; (void)ws_size;
  const float* obs = (const float*)d_in[0];
  const float* mpm = (const float*)d_in[1];
  const float* mpc = (const float*)d_in[2];
  const float* mtw = (const float*)d_in[3];
  const float* mtb = (const float*)d_in[4];
  const float* mtc = (const float*)d_in[5];
  const float* mew = (const float*)d_in[6];
  const float* meb = (const float*)d_in[7];
  const float* mec = (const float*)d_in[8];
  const float* vpm = (const float*)d_in[9];
  const float* vpc = (const float*)d_in[10];
  const float* vtw = (const float*)d_in[11];
  const float* vtb = (const float*)d_in[12];
  const float* vtc = (const float*)d_in[13];
  const float* vew = (const float*)d_in[14];
  const float* veb = (const float*)d_in[15];
  const float* vcc = (const float*)d_in[16];
  float* ws  = (float*)d_ws;
  float* out = (float*)d_out;

  k0_init<<<1, 128, 0, stream>>>(ws);
  mega<<<NB, 256, 0, stream>>>(obs, mpm, mpc, mtw, mtb, mtc, mew, meb, mec,
                               vpm, vpc, vtw, vtb, vtc, vew, veb, vcc, ws, out);
}

// Round 6
// 822.676 us; speedup vs baseline: 41.3757x; 1.0138x over previous
//
#include <hip/hip_runtime.h>
#include <math.h>

#define TT 512
#define CH 8
#define NCH 64
#define NB 128
#define LOG2PI 1.8378770664093453

static_assert(TT == CH * NCH, "chunking");

// ---------------- workspace layout (float offsets) ----------------
enum : int {
  WS_X     = 0,                    // [TT][32][32] X_t (bA_t = X^T), t=1..511
  WS_BCOV  = WS_X    + TT*1024,    // [TT][32][32] bcov_t
  WS_BA    = WS_BCOV + TT*1024,    // [TT][32] ba_t
  WS_YT    = WS_BA   + TT*32,      // [TT][32] Wt
  WS_MTP   = WS_YT   + TT*32,
  WS_MEP   = WS_MTP + 1024,
  WS_MPP   = WS_MEP + 1024,
  WS_QI    = WS_MPP + 1024,
  WS_RI    = WS_QI  + 1024,
  WS_P0I   = WS_RI  + 1024,
  WS_QIW   = WS_P0I + 1024,
  WS_CW    = WS_QIW + 1024,
  WS_HTRI  = WS_CW  + 1024,
  WS_HTRIH = WS_HTRI+ 1024,
  WS_TQ    = WS_HTRIH+1024,        // mtw^T Mtp mtw
  WS_EM    = WS_TQ  + 1024,        // -0.5 mew^T Mep mew
  WS_EML   = WS_EM  + 1024,        // -0.5 Mep mew
  WS_LAM0CW= WS_EML + 1024,        // Z_1
  WS_QHC   = WS_LAM0CW + 1024,
  WS_C1    = WS_QHC + 1024,        // mtw^T Mtp
  WS_EMM   = WS_C1  + 1024,        // Em - 0.5 Mtp
  WS_S1    = WS_EMM + 1024,
  WS_FPT   = WS_S1  + 1024,
  WS_ETA0  = WS_FPT + 1024,
  WS_CTB   = WS_ETA0 + 32,
  WS_QIVTB = WS_CTB + 32,
  WS_FMT   = WS_QIVTB + 32,
  WS_ETAF  = WS_FMT + 32,
  WS_LDS3  = WS_ETAF + 32,
  WS_DACC  = WS_LDS3 + 4,          // 4 doubles
  WS_Z512  = WS_DACC + 8,
  WS_OPS   = WS_Z512 + 1024,       // 6 ops x (K,A,G) x 1024
  WS_GBAR  = WS_OPS + 6*3072,      // 64 barrier counters
  WS_ETA_A = WS_GBAR + 64,         // NCH x 1056 (eta scan ping)
  WS_ETA_B = WS_ETA_A + NCH*1056,
  WS_CEA   = WS_ETA_B + NCH*1056,  // NCH x 2048 (S scan ping)
  WS_CEB   = WS_CEA + NCH*2048,
  WS_END   = WS_CEB + NCH*2048
};
// time-disjoint aliases: G-scan uses CE regions after S consumed (P12+)
enum : int { WS_GEA = WS_CEB, WS_GEB = WS_CEA };
static_assert(WS_DACC % 2 == 0, "double alignment");

// ---------------- helpers ----------------
__device__ __forceinline__ float rlane(float v, int l) {
  return __uint_as_float(__builtin_amdgcn_readlane(__float_as_uint(v), l));
}

__device__ __forceinline__ double gj_inv32(float a[32]) {
  double pp = 1.0;
#pragma unroll
  for (int p = 0; p < 32; ++p) {
    const float piv = rlane(a[p], p);
    pp *= (double)piv;
    const float sc = a[p] * (1.0f / piv);
#pragma unroll
    for (int r = 0; r < 32; ++r) {
      if (r != p) a[r] -= rlane(a[r], p) * sc;
    }
    a[p] = sc;
  }
  return pp;
}

// invert 32x32 (stride-33 LDS) in place; call with tid<64 only
__device__ __forceinline__ double wave_inv33(float* M, int tid) {
  float a[32]; const int cc = tid & 31;
#pragma unroll
  for (int r = 0; r < 32; ++r)
    a[r] = (tid < 32) ? M[r*33 + cc] : ((r == tid - 32) ? 1.f : 0.f);
  const double pp = gj_inv32(a);
  if (tid >= 32) {
    const int c2 = tid - 32;
#pragma unroll
    for (int r = 0; r < 32; ++r) M[r*33 + c2] = a[r];
  }
  return pp;
}

__device__ __forceinline__ float block_reduce(float v, float* red, int tid) {
#pragma unroll
  for (int m = 32; m >= 1; m >>= 1) v += __shfl_xor(v, m, 64);
  if ((tid & 63) == 0) red[tid >> 6] = v;
  __syncthreads();
  return red[0] + red[1] + red[2] + red[3];
}

__device__ __forceinline__ void stage_mat(const float* __restrict__ g, float* L, int tid) {
  const int r = tid >> 3, c = (tid & 7) * 4;
  const float4 v = *(const float4*)(g + r*32 + c);
  L[r*33+c] = v.x; L[r*33+c+1] = v.y; L[r*33+c+2] = v.z; L[r*33+c+3] = v.w;
}
__device__ __forceinline__ void stage_matT(const float* __restrict__ g, float* L, int tid) {
  const int r = tid >> 3, c = (tid & 7) * 4;
  const float4 v = *(const float4*)(g + r*32 + c);
  L[(c  )*33+r] = v.x; L[(c+1)*33+r] = v.y; L[(c+2)*33+r] = v.z; L[(c+3)*33+r] = v.w;
}
__device__ __forceinline__ void destage_mat(const float* L, float* __restrict__ g, int tid) {
  const int r = tid >> 3, c = (tid & 7) * 4;
  float4 v = make_float4(L[r*33+c], L[r*33+c+1], L[r*33+c+2], L[r*33+c+3]);
  *(float4*)(g + r*32 + c) = v;
}

__device__ __forceinline__ void mm_rr(const float* A, const float* B, float* C, int tid) {
  const int j = tid & 31, r0 = tid >> 5;
#pragma unroll
  for (int m = 0; m < 4; ++m) {
    const int ri = r0 + 8*m;
    float s = 0.f;
    for (int k = 0; k < 32; ++k) s += A[ri*33+k] * B[j*33+k];
    C[ri*33+j] = s;
  }
}
__device__ __forceinline__ void mm_p(const float* A, const float* B, float* C, int tid) {
  const int j = tid & 31, r0 = tid >> 5;
#pragma unroll
  for (int m = 0; m < 4; ++m) {
    const int ri = r0 + 8*m;
    float s = 0.f;
    for (int k = 0; k < 32; ++k) s += A[ri*33+k] * B[k*33+j];
    C[ri*33+j] = s;
  }
}
__device__ __forceinline__ void mm_tp(const float* A, const float* B, float* C, int tid) {
  const int j = tid & 31, r0 = tid >> 5;
#pragma unroll
  for (int m = 0; m < 4; ++m) {
    const int ri = r0 + 8*m;
    float s = 0.f;
    for (int k = 0; k < 32; ++k) s += A[k*33+ri] * B[k*33+j];
    C[ri*33+j] = s;
  }
}

// ---------------- grid barrier ----------------
__device__ __forceinline__ void gridbar(unsigned* bars, int idx) {
  __syncthreads();
  if (threadIdx.x == 0) {
    __threadfence();
    __hip_atomic_fetch_add(&bars[idx], 1u, __ATOMIC_RELEASE, __HIP_MEMORY_SCOPE_AGENT);
    while (__hip_atomic_load(&bars[idx], __ATOMIC_ACQUIRE, __HIP_MEMORY_SCOPE_AGENT)
           < (unsigned)NB)
      __builtin_amdgcn_s_sleep(2);
  }
  __syncthreads();
}

// ---------------- k2 body (block 0 only) ----------------
__device__ void dev_k2(const float* __restrict__ obs, const float* __restrict__ vpm,
                       const float* __restrict__ vtw, const float* __restrict__ vtb,
                       const float* __restrict__ vew, const float* __restrict__ veb,
                       const float* __restrict__ mtw, const float* __restrict__ mew,
                       float* __restrict__ ws, int tid) {
  const int j = tid & 31, r0 = tid >> 5;
#pragma unroll
  for (int m = 0; m < 4; ++m) {
    const int ri = r0 + 8*m;
    float s1 = 0.f, s2 = 0.f, s3 = 0.f, s4 = 0.f;
    for (int k = 0; k < 32; ++k) {
      s1 += ws[WS_QI  + ri*32 + k] * vtw[k*32 + j];
      s2 += vew[k*32 + ri] * ws[WS_RI + k*32 + j];
      s3 += ws[WS_MTP + ri*32 + k] * mtw[k*32 + j];
      s4 += ws[WS_MEP + ri*32 + k] * mew[k*32 + j];
    }
    ws[WS_QIW + ri*32 + j] = s1;
    ws[WS_HTRI + ri*32 + j] = s2;
    ws[WS_FPT + ri*32 + j] = s3;      // temp Mtp@mtw
    ws[WS_EML + ri*32 + j] = -0.5f * s4;
  }
  __syncthreads();
#pragma unroll
  for (int m = 0; m < 4; ++m) {
    const int ri = r0 + 8*m;
    float s1 = 0.f, s2 = 0.f, s3 = 0.f, s4 = 0.f;
    for (int k = 0; k < 32; ++k) {
      s1 += vtw[k*32 + ri] * ws[WS_QIW + k*32 + j];
      s2 += ws[WS_HTRI + ri*32 + k] * vew[k*32 + j];
      s3 += mtw[k*32 + ri] * ws[WS_FPT + k*32 + j];
      s4 += mew[k*32 + ri] * ws[WS_EML + k*32 + j];
    }
    ws[WS_CW + ri*32 + j] = s1;
    ws[WS_HTRIH + ri*32 + j] = s2;
    ws[WS_LAM0CW + ri*32 + j] = ws[WS_P0I + ri*32 + j] + s1 + s2;
    ws[WS_QHC    + ri*32 + j] = ws[WS_QI  + ri*32 + j] + s1 + s2;
    ws[WS_TQ + ri*32 + j] = s3;
    ws[WS_EM + ri*32 + j] = s4;
    ws[WS_S1 + ri*32 + j] = s4 - 0.5f * ws[WS_MPP + ri*32 + j];
    ws[WS_C1 + ri*32 + j] = ws[WS_FPT + j*32 + ri];           // (Mtp@mtw)^T
    ws[WS_EMM + ri*32 + j] = s4 - 0.5f * ws[WS_MTP + ri*32 + j];
  }
  if (tid < 32) {
    float s1 = 0.f, s2 = 0.f, s3 = 0.f;
    for (int k = 0; k < 32; ++k) {
      s1 += ws[WS_QIW + k*32 + tid] * vtb[k];
      s2 += ws[WS_P0I + tid*32 + k] * vpm[k]
          + ws[WS_HTRI + tid*32 + k] * (obs[k] - veb[k]);
      s3 += ws[WS_QI + tid*32 + k] * vtb[k];
    }
    ws[WS_CTB + tid] = s1;
    ws[WS_ETA0 + tid] = s2;
    ws[WS_QIVTB + tid] = s3;
  }
  __syncthreads();
  if (tid == 0) {
    const double ldmt = (double)ws[WS_LDS3 + 0];
    const double ldme = (double)ws[WS_LDS3 + 1];
    const double ldmp = (double)ws[WS_LDS3 + 2];
    const double ct_me = -0.5 * (32.0 * LOG2PI + ldme);
    const double ct_mt = -0.5 * (32.0 * LOG2PI + ldmt);
    const double ct_mp = -0.5 * (32.0 * LOG2PI + ldmp);
    double c = ct_mp + ct_me;
    c += (double)(TT - 1) * (ct_me + ct_mt + 0.5 * 32.0 * LOG2PI + 16.0);
    c += 0.5 * 32.0 * LOG2PI + 16.0;
    ((double*)(ws + WS_DACC))[0] = c;
  }
}

// ---------------- Riccati operator squaring (block 0) ----------------
__device__ void dev_compose(float* __restrict__ ws, float* sm, int tid) {
  float *Kc = sm,       *Ac = sm+1056,  *Gc = sm+2112;
  float *Kn = sm+3168,  *An = sm+4224,  *Gn = sm+5280;
  float *Mi = sm+6336,  *V1 = sm+7392,  *Wm = sm+8448;
  const int j = tid & 31, r0 = tid >> 5;
  stage_mat(ws + WS_QHC, Kc, tid);
  stage_mat(ws + WS_QIW, Ac, tid);
  for (int e = tid; e < 1056; e += 256) Gc[e] = 0.f;
  __syncthreads();
  for (int d = 0; d < 8; ++d) {          // builds Phi^{2^{d+1}}
    for (int e = tid; e < 1056; e += 256) Mi[e] = Kc[e] + Gc[e];
    __syncthreads();
    if (tid < 64) wave_inv33(Mi, tid);
    __syncthreads();
    mm_rr(Ac, Mi, V1, tid);   // A M^-1 (M^-1 sym)
    mm_tp(Ac, Mi, Wm, tid);   // A^T M^-1
    __syncthreads();
#pragma unroll
    for (int m = 0; m < 4; ++m) {
      const int ri = r0 + 8*m;
      float s1 = 0.f, s2 = 0.f, s3 = 0.f;
      for (int k = 0; k < 32; ++k) {
        const float v = V1[ri*33+k];
        s1 += v * Ac[j*33+k];
        s2 += v * Ac[k*33+j];
        s3 += Wm[ri*33+k] * Ac[k*33+j];
      }
      Kn[ri*33+j] = Kc[ri*33+j] - s1;
      An[ri*33+j] = s2;
      Gn[ri*33+j] = Gc[ri*33+j] - s3;
    }
    __syncthreads();
    float* tp;
    tp=Kc; Kc=Kn; Kn=tp;  tp=Ac; Ac=An; An=tp;  tp=Gc; Gc=Gn; Gn=tp;
    if (d >= 2) {                         // save Phi^8 .. Phi^256 (ops 0..5)
      float* op = ws + WS_OPS + (d-2)*3072;
      destage_mat(Kc, op, tid);
      destage_mat(Ac, op + 1024, tid);
      destage_mat(Gc, op + 2048, tid);
    }
  }
}

// ---------------- eta machinery ----------------
__device__ void dev_keta_a(float* __restrict__ ws, float* sm, int tid, int c) {
  float *Aa = sm, *Ab = sm+1056, *Xl = sm+2112, *bb = sm+3168;
  const int t1 = CH*c + 1;
  stage_mat(ws + WS_X + t1*1024, Aa, tid);
  if (tid < 32) bb[tid] = ws[WS_YT + t1*32 + tid];
  __syncthreads();
  float *Acur = Aa, *Anew = Ab; int pb = 0;
  for (int t = t1 + 1; t <= t1 + CH - 1; ++t) {
    stage_mat(ws + WS_X + t*1024, Xl, tid);
    __syncthreads();
    mm_p(Xl, Acur, Anew, tid);
    if (tid < 32) {
      float s = ws[WS_YT + t*32 + tid];
      for (int k = 0; k < 32; ++k) s += Xl[tid*33+k] * bb[pb*32 + k];
      bb[(pb^1)*32 + tid] = s;
    }
    __syncthreads();
    float* tp = Acur; Acur = Anew; Anew = tp; pb ^= 1;
  }
  float* dst = ws + WS_ETA_A + (c+1)*1056;
  destage_mat(Acur, dst, tid);
  if (tid < 32) dst[1024 + tid] = bb[pb*32 + tid];
}

__device__ void dev_eta_lvl(float* __restrict__ ws, float* sm,
                            int inoff, int outoff, int step, int tid, int c) {
  const float* in = ws + inoff;
  float* out = ws + outoff;
  if (c < step) {
    for (int e = tid; e < 1056; e += 256) out[c*1056 + e] = in[c*1056 + e];
    return;
  }
  float *A1 = sm, *A0 = sm+1056, *Ar = sm+2112, *b0l = sm+3168;
  stage_mat(in + c*1056, A1, tid);
  stage_mat(in + (c-step)*1056, A0, tid);
  if (tid < 32) b0l[tid] = in[(c-step)*1056 + 1024 + tid];
  __syncthreads();
  mm_p(A1, A0, Ar, tid);
  if (tid < 32) {
    float s = in[c*1056 + 1024 + tid];
    for (int k = 0; k < 32; ++k) s += A1[tid*33+k] * b0l[k];
    out[c*1056 + 1024 + tid] = s;
  }
  __syncthreads();
  destage_mat(Ar, out + c*1056, tid);
}

__device__ void dev_keta_b(float* __restrict__ ws, float* sm, int tid, int c) {
  float *Ap = sm, *Bl = sm+1056, *Xl = sm+2112, *zeta = sm+3168, *zn = sm+3200;
  const int nst = (c == NCH-1) ? CH-1 : CH;
  stage_mat(ws + WS_ETA_A + c*1056, Ap, tid);
  __syncthreads();
  if (tid < 32) {
    float s = ws[WS_ETA_A + c*1056 + 1024 + tid];
    for (int k = 0; k < 32; ++k)
      s += Ap[tid*33+k] * (ws[WS_ETA0 + k] - ws[WS_CTB + k]);
    zeta[tid] = s;
  }
  __syncthreads();
  for (int i = 0; i < nst; ++i) {
    const int t = CH*c + 1 + i;
    stage_mat(ws + WS_BCOV + t*1024, Bl, tid);
    stage_mat(ws + WS_X + t*1024, Xl, tid);
    __syncthreads();
    if (tid < 32) {
      float s = 0.f;
      for (int k = 0; k < 32; ++k) s += Bl[tid*33+k] * zeta[k];
      ws[WS_BA + t*32 + tid] = s;
    } else if (tid < 64) {
      const int i2 = tid - 32;
      float s = ws[WS_YT + t*32 + i2];
      for (int k = 0; k < 32; ++k) s += Xl[i2*33+k] * zeta[k];
      zn[i2] = s;
    }
    __syncthreads();
    if (tid < 32) zeta[tid] = zn[tid];
    __syncthreads();
  }
  if (c == NCH-1 && tid < 32)
    ws[WS_ETAF + tid] = zeta[tid] + ws[WS_CTB + tid];
}

// ---------------- S machinery (4-matmul form) ----------------
// per-step map: S -> X S X^T + K_t,
// K_t = X(-1/2 TQ)X^T + 1/2(X C1 + (X C1)^T) + EMM   [EMM = Em - 1/2 Mtp]
__device__ void dev_ksa(float* __restrict__ ws, float* sm, int tid, int c) {
  float *BTa=sm,      *BTb=sm+1056,  *Ka=sm+2112,  *Kb=sm+3168,
        *Tk=sm+4224,  *XC1=sm+5280,  *Xl=sm+6336,  *KmTQ=sm+7392,
        *TQl=sm+8448, *EMMl=sm+9504, *C1l=sm+10560;
  const int t1 = CH*c + 1, t2 = CH*c + CH;
  const int j = tid & 31, r0 = tid >> 5;
  stage_mat(ws + WS_TQ, TQl, tid);
  stage_mat(ws + WS_EMM, EMMl, tid);
  stage_mat(ws + WS_C1, C1l, tid);
  for (int e = tid; e < 1056; e += 256) {
    const int r = e / 33, cc = e - 33*r;
    BTa[e] = (r < 32 && cc == r) ? 1.f : 0.f;   // BT = I
    Ka[e] = 0.f;                                 // K = 0
  }
  __syncthreads();
  float *BTc = BTa, *BTn = BTb, *Kc = Ka, *Kn = Kb;
  for (int t = t1; t <= t2; ++t) {
    stage_mat(ws + WS_X + t*1024, Xl, tid);
    for (int e = tid; e < 1056; e += 256) KmTQ[e] = Kc[e] - 0.5f * TQl[e];
    __syncthreads();
    mm_rr(BTc, Xl, BTn, tid);          // BT' = BT @ X^T
    mm_rr(Xl, KmTQ, Tk, tid);          // X @ (K - 1/2 TQ)   (sym)
    mm_p(Xl, C1l, XC1, tid);           // X @ C1
    __syncthreads();
#pragma unroll
    for (int m = 0; m < 4; ++m) {
      const int ri = r0 + 8*m;
      float s = 0.f;
      for (int k = 0; k < 32; ++k) s += Tk[ri*33+k] * Xl[j*33+k];
      Kn[ri*33+j] = s + 0.5f*(XC1[ri*33+j] + XC1[j*33+ri]) + EMMl[ri*33+j];
    }
    __syncthreads();
    float* tp = BTc; BTc = BTn; BTn = tp;
    tp = Kc; Kc = Kn; Kn = tp;
  }
  float* dst = ws + WS_CEA + (c+1)*2048;
  destage_mat(BTc, dst, tid);
  destage_mat(Kc, dst + 1024, tid);
}

__device__ void dev_ks_level(float* __restrict__ ws, float* sm,
                             int inoff, int outoff, int step, int tid, int c) {
  const float* in = ws + inoff;
  float* out = ws + outoff;
  if (c < step) {
    const int base = c*2048 + tid*8;
#pragma unroll
    for (int x = 0; x < 8; ++x) out[base + x] = in[base + x];
    return;
  }
  float *BTo=sm, *Ko=sm+1056, *BTn=sm+2112, *tmp=sm+3168, *BTr=sm+4224;
  stage_mat(in + (c-step)*2048, BTo, tid);
  stage_mat(in + (c-step)*2048 + 1024, Ko, tid);
  stage_mat(in + c*2048, BTn, tid);
  __syncthreads();
  mm_p(BTo, BTn, BTr, tid);
  mm_p(Ko, BTn, tmp, tid);
  __syncthreads();
  const int j = tid & 31, r0 = tid >> 5;
#pragma unroll
  for (int m = 0; m < 4; ++m) {
    const int ri = r0 + 8*m;
    float s = 0.f;
    for (int k = 0; k < 32; ++k) s += BTn[k*33+ri] * tmp[k*33+j];
    out[c*2048 + ri*32 + j] = BTr[ri*33+j];
    out[c*2048 + 1024 + ri*32 + j] = s + in[c*2048 + 1024 + ri*32 + j];
  }
}

__device__ void dev_ksc(float* __restrict__ ws, float* sm, float* red,
                        int tid, int c) {
  float *S=sm,        *SmTQ=sm+1056, *T1=sm+2112,  *XC1=sm+3168,
        *Xl=sm+4224,  *Bcl=sm+5280,  *BTP=sm+6336, *S2=sm+7392,
        *TQl=sm+8448, *EMMl=sm+9504, *C1l=sm+10560;
  const int j = tid & 31, r0 = tid >> 5;
  stage_mat(ws + WS_TQ, TQl, tid);
  stage_mat(ws + WS_EMM, EMMl, tid);
  stage_mat(ws + WS_C1, C1l, tid);
  stage_mat(ws + WS_CEA + c*2048, BTP, tid);
  stage_mat(ws + WS_S1, S2, tid);
  __syncthreads();
  mm_p(S2, BTP, T1, tid);              // S0 @ B_P^T
  __syncthreads();
#pragma unroll
  for (int m = 0; m < 4; ++m) {        // S_start = B_P @ T1 + K_P
    const int ri = r0 + 8*m;
    float s = 0.f;
    for (int k = 0; k < 32; ++k) s += BTP[k*33+ri] * T1[k*33+j];
    S[ri*33+j] = s + ws[WS_CEA + c*2048 + 1024 + ri*32 + j];
  }
  __syncthreads();
  double accd = 0.0;
  for (int i = 0; i < CH; ++i) {
    const int t = CH*c + 1 + i;
    if (t >= TT) break;
    stage_mat(ws + WS_X + t*1024, Xl, tid);
    stage_mat(ws + WS_BCOV + t*1024, Bcl, tid);
#pragma unroll
    for (int m = 0; m < 4; ++m) {
      const int ri = r0 + 8*m;
      SmTQ[ri*33+j] = S[ri*33+j] - 0.5f * TQl[ri*33+j];
    }
    float part = 0.f;
#pragma unroll
    for (int m = 0; m < 4; ++m) {      // trace((S - 1/2 TQ) bcov), bcov sym
      const int ri = r0 + 8*m;
      part += SmTQ[ri*33+j] * Bcl[ri*33+j];
    }
    const float r2 = block_reduce(part, red, tid);   // syncs: SmTQ/Xl/Bcl ready
    if (tid == 0) accd += (double)r2;
    mm_rr(Xl, SmTQ, T1, tid);          // X @ (S - 1/2 TQ)
    mm_p(Xl, C1l, XC1, tid);           // X @ C1
    __syncthreads();
#pragma unroll
    for (int m = 0; m < 4; ++m) {
      const int ri = r0 + 8*m;
      float s = 0.f;
      for (int k = 0; k < 32; ++k) s += T1[ri*33+k] * Xl[j*33+k];
      S[ri*33+j] = s + 0.5f*(XC1[ri*33+j] + XC1[j*33+ri]) + EMMl[ri*33+j];
    }
    __syncthreads();
  }
  if (tid == 0) atomicAdd(((double*)(ws + WS_DACC)) + 2, accd);
}

// ---------------- G machinery ----------------
__device__ void dev_kga(float* __restrict__ ws, float* sm, int tid, int c) {
  float *ATa = sm, *ATb = sm+1056, *XTl = sm+2112, *bb = sm+3168;
  const int t1 = CH*c + 1;
  const int t2 = (CH*c + CH < TT) ? CH*c + CH : TT - 1;
  stage_mat(ws + WS_X + t2*1024, ATa, tid);
  if (tid < 32) bb[tid] = ws[WS_BA + t2*32 + tid];
  __syncthreads();
  float *ATc = ATa, *ATn = ATb;
  int pb = 0;
  for (int t = t2 - 1; t >= t1; --t) {
    stage_matT(ws + WS_X + t*1024, XTl, tid);
    __syncthreads();
    mm_rr(ATc, XTl, ATn, tid);
    if (tid < 32) {
      float s = ws[WS_BA + t*32 + tid];
      for (int k = 0; k < 32; ++k) s += XTl[tid*33+k] * bb[pb*32 + k];
      bb[(pb^1)*32 + tid] = s;
    }
    __syncthreads();
    float* tp = ATc; ATc = ATn; ATn = tp; pb ^= 1;
  }
  float* dst = ws + WS_GEA + (c-1)*1056;
  destage_mat(ATc, dst, tid);
  if (tid < 32) dst[1024 + tid] = bb[pb*32 + tid];
}

__device__ void dev_kg_level(float* __restrict__ ws, float* sm,
                             int inoff, int outoff, int step, int tid, int c) {
  const float* in = ws + inoff;
  float* out = ws + outoff;
  if (c + step > NCH - 1) {
    const int base = c*1056;
    const int e = tid*4;
#pragma unroll
    for (int x = 0; x < 4; ++x) out[base + e + x] = in[base + e + x];
    if (tid < 32) out[base + 1024 + tid] = in[base + 1024 + tid];
    return;
  }
  float *AT1 = sm, *AT2 = sm+1056, *ATr = sm+2112, *b2l = sm+3168;
  stage_mat(in + c*1056, AT1, tid);
  stage_mat(in + (c+step)*1056, AT2, tid);
  if (tid < 32) b2l[tid] = in[(c+step)*1056 + 1024 + tid];
  __syncthreads();
  mm_p(AT2, AT1, ATr, tid);
  if (tid < 32) {
    float s = in[c*1056 + 1024 + tid];
    for (int k = 0; k < 32; ++k) s += AT1[k*33+tid] * b2l[k];
    out[c*1056 + 1024 + tid] = s;
  }
  __syncthreads();
  destage_mat(ATr, out + c*1056, tid);
}

__device__ void dev_kgb(const float* __restrict__ obs, const float* __restrict__ mpm,
                        const float* __restrict__ mtw, const float* __restrict__ mtb,
                        const float* __restrict__ mew, const float* __restrict__ meb,
                        float* __restrict__ ws, float* sm, float* red, int tid, int c) {
  float *ATa=sm,       *ATb=sm+1056,  *XTl=sm+2112,  *Y1=sm+3168,  *Y2=sm+4224,
        *Jb=sm+5280,   *M2T=sm+6336,  *E1=sm+7392,   *mewl=sm+8448,*EmLl=sm+9504,
        *fPl=sm+10560, *Mtpl=sm+11616,*Mepl=sm+12672,*mtwl=sm+13728;
  float *vec = sm + 14784;
  float *fml=vec, *mebl=vec+32, *mtbl=vec+64, *mpml=vec+96, *yl=vec+128,
        *bal=vec+160, *gv=vec+192, *cme=vec+224, *cmo=vec+256, *bv=vec+288;
  const int j = tid & 31, r0 = tid >> 5;
  stage_mat(mew, mewl, tid);
  stage_mat(ws + WS_EML, EmLl, tid);
  stage_mat(ws + WS_FPT, fPl, tid);
  stage_mat(ws + WS_MTP, Mtpl, tid);
  stage_mat(ws + WS_MEP, Mepl, tid);
  stage_mat(mtw, mtwl, tid);
  stage_mat(ws + WS_GEA + c*1056, ATa, tid);
  if (tid < 32) {
    fml[tid] = ws[WS_FMT + tid];
    mebl[tid] = meb[tid]; mtbl[tid] = mtb[tid]; mpml[tid] = mpm[tid];
    bv[tid] = ws[WS_GEA + c*1056 + 1024 + tid];
  }
  __syncthreads();
  float *ATc = ATa, *ATo = ATb;
  int bc = 0;
  double accd = 0.0;
  for (int s = CH*c + CH - 1; s >= CH*c; --s) {
    if (s < TT-1) stage_matT(ws + WS_X + (s+1)*1024, XTl, tid);
    if (s == 0)   stage_mat(ws + WS_MPP, Jb, tid);
    if (tid < 32) {
      yl[tid] = obs[s*32 + tid];
      if (s >= 1) bal[tid] = ws[WS_BA + s*32 + tid];
    }
    __syncthreads();
    if (s < TT-1) {
      mm_rr(ATc, XTl, ATo, tid);
      if (tid < 32) {
        float v = ws[WS_BA + (s+1)*32 + tid];
        for (int k = 0; k < 32; ++k) v += XTl[tid*33+k] * bv[bc*32 + k];
        bv[(bc^1)*32 + tid] = v;
      }
    }
    __syncthreads();
    const float* AT = (s < TT-1) ? ATo : ATc;
    const float* bl = (s < TT-1) ? (bv + (bc^1)*32) : (bv + bc*32);
    mm_rr(mewl, AT, Y1, tid);
    mm_rr(EmLl, AT, Y2, tid);
    if (s >= 1) {
      const float* Xg = ws + WS_X + s*1024;
      float s0 = 0.f, s1 = 0.f, s2 = 0.f, s3 = 0.f;
      for (int k = 0; k < 32; ++k) {
        const float b = Xg[j*32 + k];
        s0 += mtwl[(r0     )*33+k] * b;
        s1 += mtwl[(r0 +  8)*33+k] * b;
        s2 += mtwl[(r0 + 16)*33+k] * b;
        s3 += mtwl[(r0 + 24)*33+k] * b;
      }
      Jb[(r0     )*33+j] = s0 - ((r0      == j) ? 1.f : 0.f);
      Jb[(r0 +  8)*33+j] = s1 - ((r0 +  8 == j) ? 1.f : 0.f);
      Jb[(r0 + 16)*33+j] = s2 - ((r0 + 16 == j) ? 1.f : 0.f);
      Jb[(r0 + 24)*33+j] = s3 - ((r0 + 24 == j) ? 1.f : 0.f);
    }
    if (tid < 32) {
      float g = bl[tid];
      for (int k = 0; k < 32; ++k) g += AT[k*33+tid] * fml[k];
      gv[tid] = g;
    }
    __syncthreads();
    if (s >= 1) mm_rr(AT, Jb, M2T, tid);
    if (tid < 32) {
      float s1v = mebl[tid] - yl[tid];
      for (int k = 0; k < 32; ++k) s1v += mewl[tid*33+k] * gv[k];
      cme[tid] = s1v;
      float s2v;
      if (s >= 1) {
        s2v = mtbl[tid];
        for (int k = 0; k < 32; ++k)
          s2v += Jb[tid*33+k] * gv[k] + mtwl[tid*33+k] * bal[k];
      } else {
        s2v = gv[tid] - mpml[tid];
      }
      cmo[tid] = s2v;
    }
    __syncthreads();
    const float* M2Tp = (s >= 1) ? M2T : AT;
    const float* Mqp  = (s >= 1) ? Mtpl : Jb;
    mm_rr(Mqp, M2Tp, E1, tid);
    __syncthreads();
    float part = 0.f;
#pragma unroll
    for (int m = 0; m < 4; ++m) {
      const int ri = r0 + 8*m;
      float y3 = 0.f, e2 = 0.f;
      for (int k = 0; k < 32; ++k) {
        y3 += Y2[ri*33+k] * fPl[j*33+k];
        e2 += fPl[j*33+k] * M2Tp[ri*33+k];
      }
      part += y3 * Y1[j*33+ri]
            - 0.5f * E1[ri*33+j] * e2
            - 0.5f * cme[ri] * Mepl[ri*33+j] * cme[j]
            - 0.5f * cmo[ri] * Mqp[ri*33+j] * cmo[j];
    }
    const float r2 = block_reduce(part, red, tid);
    if (tid == 0) accd += (double)r2;
    if (s < TT-1) { float* tp = ATc; ATc = ATo; ATo = tp; bc ^= 1; }
    __syncthreads();
  }
  if (tid == 0) atomicAdd(((double*)(ws + WS_DACC)) + 3, accd);
}

// ---------------- k0: zero barriers + accumulators ----------------
__global__ __launch_bounds__(128) void k0_init(float* __restrict__ ws) {
  const int tid = threadIdx.x;
  if (tid < 64) ((unsigned*)(ws + WS_GBAR))[tid] = 0u;
  if (tid == 64) ((double*)(ws + WS_DACC))[1] = 0.0;
  if (tid == 65) ((double*)(ws + WS_DACC))[2] = 0.0;
  if (tid == 66) ((double*)(ws + WS_DACC))[3] = 0.0;
}

// ---------------- the fused kernel ----------------
__global__ __launch_bounds__(256) void mega(
    const float* __restrict__ obs, const float* __restrict__ mpm,
    const float* __restrict__ mpc, const float* __restrict__ mtw,
    const float* __restrict__ mtb, const float* __restrict__ mtc,
    const float* __restrict__ mew, const float* __restrict__ meb,
    const float* __restrict__ mec, const float* __restrict__ vpm,
    const float* __restrict__ vpc, const float* __restrict__ vtw,
    const float* __restrict__ vtb, const float* __restrict__ vtc,
    const float* __restrict__ vew, const float* __restrict__ veb,
    const float* __restrict__ vcc, float* __restrict__ ws,
    float* __restrict__ out) {
  __shared__ float sm[15232];
  __shared__ float red[4];
  const int tid = threadIdx.x, blk = blockIdx.x;
  unsigned* bars = (unsigned*)(ws + WS_GBAR);
  int bix = 0;

  // ---- P0: 6 constant SPD inverses ----
  if (blk < 6) {
    const float* src = blk==0?mtc : blk==1?mec : blk==2?mpc : blk==3?vtc : blk==4?vcc : vpc;
    float* dst = ws + (blk==0?WS_MTP : blk==1?WS_MEP : blk==2?WS_MPP :
                       blk==3?WS_QI  : blk==4?WS_RI  : WS_P0I);
    if (tid < 64) {
      float a[32]; const int cc = tid & 31;
#pragma unroll
      for (int r = 0; r < 32; ++r)
        a[r] = (tid < 32) ? src[r*32 + cc] : ((r == tid - 32) ? 1.f : 0.f);
      const double pp = gj_inv32(a);
      if (tid >= 32) {
        const int c2 = tid - 32;
#pragma unroll
        for (int r = 0; r < 32; ++r) dst[r*32 + c2] = a[r];
      }
      if (tid == 0 && blk < 3) ws[WS_LDS3 + blk] = (float)log(pp);
    }
  }
  gridbar(bars, bix++);

  // ---- P1: derived constants ----
  if (blk == 0) dev_k2(obs, vpm, vtw, vtb, vew, veb, mtw, mew, ws, tid);
  gridbar(bars, bix++);

  // ---- P2: b0 operator squarings; others YT ----
  if (blk == 0) {
    dev_compose(ws, sm, tid);
  } else {
    for (int tb = blk - 1; tb < NCH; tb += NB - 1) {
      const int t = tb*CH + (tid >> 5), i = tid & 31;
      float s = ws[WS_QIVTB + i] - ws[WS_CTB + i];
      for (int k = 0; k < 32; ++k)
        s += ws[WS_HTRI + i*32 + k] * (obs[t*32 + k] - veb[k]);
      ws[WS_YT + t*32 + i] = s;
    }
  }
  gridbar(bars, bix++);

  // ---- P3: per-block boundary via bit-decomposition + chunk expansion ----
  if (blk < NCH) {
    float *Zl=sm, *Mi=sm+1056, *Aol=sm+2112, *V1=sm+3168;
    float *Bcv=sm+4224, *Xs=sm+5280, *QiWl=sm+6336, *QHCl=sm+7392;
    const int c = blk;
    const int j = tid & 31, r0 = tid >> 5;
    stage_mat(ws + WS_LAM0CW, Zl, tid);
    stage_mat(ws + WS_QIW, QiWl, tid);
    stage_mat(ws + WS_QHC, QHCl, tid);
    __syncthreads();
    for (int k = 0; k < 6; ++k) {
      if (!((c >> k) & 1)) continue;           // block-uniform
      const float* OP = ws + WS_OPS + k*3072;  // (K,A,G) of Phi^{8*2^k}
      const int r = tid >> 3, c4 = (tid & 7) * 4;
#pragma unroll
      for (int x = 0; x < 4; ++x)
        Mi[r*33 + c4 + x] = Zl[r*33 + c4 + x] + OP[2048 + r*32 + c4 + x];
      stage_mat(OP + 1024, Aol, tid);
      __syncthreads();
      if (tid < 64) wave_inv33(Mi, tid);
      __syncthreads();
      mm_rr(Aol, Mi, V1, tid);                 // A M^-1 (sym)
      __syncthreads();
#pragma unroll
      for (int m = 0; m < 4; ++m) {
        const int ri = r0 + 8*m;
        float s = 0.f;
        for (int kk = 0; kk < 32; ++kk) s += V1[ri*33+kk] * Aol[j*33+kk];
        Zl[ri*33+j] = OP[ri*32+j] - s;         // Z' = K - A M^-1 A^T
      }
      __syncthreads();
    }
    // chunk expansion
    const int nst = (c == NCH-1) ? CH-1 : CH;
    double acc = 0.0;
    for (int i = 0; i < nst; ++i) {
      const int t = CH*c + 1 + i;
      if (tid < 64) {
        float a[32]; const int cc = tid & 31;
#pragma unroll
        for (int r = 0; r < 32; ++r)
          a[r] = (tid < 32) ? Zl[r*33+cc] : ((r == tid - 32) ? 1.f : 0.f);
        const double pp = gj_inv32(a);
        if (tid >= 32) {
          const int c2 = tid - 32;
#pragma unroll
          for (int r = 0; r < 32; ++r) {
            Bcv[r*33 + c2] = a[r];
            ws[WS_BCOV + t*1024 + r*32 + c2] = a[r];
          }
        }
        if (tid == 0) acc += -log(pp);
      }
      __syncthreads();
      mm_rr(QiWl, Bcv, Xs, tid);
      __syncthreads();
      destage_mat(Xs, ws + WS_X + t*1024, tid);
#pragma unroll
      for (int m = 0; m < 4; ++m) {
        const int ri = r0 + 8*m;
        float s = 0.f;
        for (int kk = 0; kk < 32; ++kk) s += Xs[ri*33+kk] * QiWl[j*33+kk];
        Zl[ri*33+j] = QHCl[ri*33+j] - s;
      }
      __syncthreads();
    }
    if (c == NCH-1) destage_mat(Zl, ws + WS_Z512, tid);
    if (tid == 0) atomicAdd(((double*)(ws + WS_DACC)) + 1, acc);
  }
  gridbar(bars, bix++);

  // ---- P4: eta chunk compose (blk<64) || S chunk compose (blk>=64) ----
  if (blk < NCH) {
    if (blk < NCH-1) {
      dev_keta_a(ws, sm, tid, blk);
    } else {
      for (int e = tid; e < 1056; e += 256)
        ws[WS_ETA_A + e] = (e < 1024 && ((e >> 5) == (e & 31))) ? 1.f : 0.f;
    }
  } else {
    const int c = blk - NCH;
    if (c < NCH-1) {
      dev_ksa(ws, sm, tid, c);
    } else {
      for (int e = tid; e < 2048; e += 256)
        ws[WS_CEA + e] = (e < 1024 && ((e >> 5) == (e & 31))) ? 1.f : 0.f;
    }
  }
  gridbar(bars, bix++);

  // ---- P5-P10: eta scan (blk<64) || S scan (blk>=64), 6 levels ----
  {
    const int steps[6] = {1, 2, 4, 8, 16, 32};
#pragma unroll
    for (int L = 0; L < 6; ++L) {
      const int inA = (L & 1) == 0;
      if (blk < NCH) {
        dev_eta_lvl(ws, sm, inA ? WS_ETA_A : WS_ETA_B,
                    inA ? WS_ETA_B : WS_ETA_A, steps[L], tid, blk);
      } else {
        dev_ks_level(ws, sm, inA ? WS_CEA : WS_CEB,
                     inA ? WS_CEB : WS_CEA, steps[L], tid, blk - NCH);
      }
      gridbar(bars, bix++);
    }
  }

  // ---- P11: eta expand (blk<64) || S expand + traces (blk>=64) ----
  if (blk < NCH) dev_keta_b(ws, sm, tid, blk);
  else           dev_ksc(ws, sm, red, tid, blk - NCH);
  gridbar(bars, bix++);

  // ---- P12: kfin (blk0) || G chunk compose (blk 1..63) || identity (blk64) ----
  if (blk == 0) {
    if (tid < 64) {
      float a[32]; const int cc = tid & 31;
#pragma unroll
      for (int r = 0; r < 32; ++r) {
        const float v = ws[WS_Z512 + r*32 + cc] - ws[WS_CW + r*32 + cc];
        a[r] = (tid < 32) ? v : ((r == tid - 32) ? 1.f : 0.f);
      }
      const double pp = gj_inv32(a);
      if (tid >= 32) {
        const int c2 = tid - 32;
        float fmv = 0.f;
#pragma unroll
        for (int r = 0; r < 32; ++r) {
          ws[WS_FPT + r*32 + c2] = a[r];
          fmv += a[r] * ws[WS_ETAF + r];
        }
        ws[WS_FMT + c2] = fmv;
      }
      if (tid == 0) {
        double* d = (double*)(ws + WS_DACC);
        d[1] = 0.5 * (d[1] + (-log(pp)));
      }
    }
  } else if (blk < NCH) {
    dev_kga(ws, sm, tid, blk);       // c = 1..63 -> GEA slots 0..62
  } else if (blk == NCH) {
    for (int e = tid; e < 1056; e += 256)
      ws[WS_GEA + (NCH-1)*1056 + e] = (e < 1024 && ((e >> 5) == (e & 31))) ? 1.f : 0.f;
  }
  gridbar(bars, bix++);

  // ---- P13-P18: G suffix scan, 6 levels (blk<64) ----
  {
    const int steps[6] = {1, 2, 4, 8, 16, 32};
#pragma unroll
    for (int L = 0; L < 6; ++L) {
      const int inA = (L & 1) == 0;
      if (blk < NCH) {
        dev_kg_level(ws, sm, inA ? WS_GEA : WS_GEB,
                     inA ? WS_GEB : WS_GEA, steps[L], tid, blk);
      }
      gridbar(bars, bix++);
    }
  }

  // ---- P19: G expand + final per-s terms (blk<64) ----
  if (blk < NCH) dev_kgb(obs, mpm, mtw, mtb, mew, meb, ws, sm, red, tid, blk);
  gridbar(bars, bix++);

  // ---- out ----
  if (blk == 0 && tid == 0) {
    const double* d = (const double*)(ws + WS_DACC);
    out[0] = (float)(d[0] + d[1] + d[2] + d[3]);
  }
}

extern "C" void kernel_launch(void* const* d_in, const int* in_sizes, int n_in,
                              void* d_out, int out_size, void* d_ws, size_t ws_size,
                              hipStream_t stream) {
  (void)in_sizes; (void)n_in; (void)out_size; (void)ws_size;
  const float* obs = (const float*)d_in[0];
  const float* mpm = (const float*)d_in[1];
  const float* mpc = (const float*)d_in[2];
  const float* mtw = (const float*)d_in[3];
  const float* mtb = (const float*)d_in[4];
  const float* mtc = (const float*)d_in[5];
  const float* mew = (const float*)d_in[6];
  const float* meb = (const float*)d_in[7];
  const float* mec = (const float*)d_in[8];
  const float* vpm = (const float*)d_in[9];
  const float* vpc = (const float*)d_in[10];
  const float* vtw = (const float*)d_in[11];
  const float* vtb = (const float*)d_in[12];
  const float* vtc = (const float*)d_in[13];
  const float* vew = (const float*)d_in[14];
  const float* veb = (const float*)d_in[15];
  const float* vcc = (const float*)d_in[16];
  float* ws  = (float*)d_ws;
  float* out = (float*)d_out;

  k0_init<<<1, 128, 0, stream>>>(ws);
  mega<<<NB, 256, 0, stream>>>(obs, mpm, mpc, mtw, mtb, mtc, mew, meb, mec,
                               vpm, vpc, vtw, vtb, vtc, vew, veb, vcc, ws, out);
}

// Round 7
// 618.537 us; speedup vs baseline: 55.0312x; 1.3300x over previous
//
#include <hip/hip_runtime.h>
#include <math.h>

#define TT 512
#define CH 8
#define NCH 64
#define NB 128
#define ST 36
#define MS 1152
#define LOG2PI 1.8378770664093453

static_assert(TT == CH * NCH, "chunking");

// ---------------- workspace layout (float offsets, global stride 32) ----------------
enum : int {
  WS_X     = 0,                    // [TT][32][32] X_t (bA_t = X^T), t=1..511
  WS_BCOV  = WS_X    + TT*1024,
  WS_BA    = WS_BCOV + TT*1024,    // [TT][32] ba_t
  WS_YT    = WS_BA   + TT*32,      // [TT][32] Wt
  WS_MTP   = WS_YT   + TT*32,
  WS_MEP   = WS_MTP + 1024,
  WS_MPP   = WS_MEP + 1024,
  WS_QI    = WS_MPP + 1024,
  WS_RI    = WS_QI  + 1024,
  WS_P0I   = WS_RI  + 1024,
  WS_QIW   = WS_P0I + 1024,
  WS_CW    = WS_QIW + 1024,
  WS_HTRI  = WS_CW  + 1024,
  WS_HTRIH = WS_HTRI+ 1024,
  WS_TQ    = WS_HTRIH+1024,
  WS_EM    = WS_TQ  + 1024,
  WS_EML   = WS_EM  + 1024,
  WS_LAM0CW= WS_EML + 1024,        // Z_1
  WS_QHC   = WS_LAM0CW + 1024,
  WS_C1    = WS_QHC + 1024,        // mtw^T Mtp
  WS_EMM   = WS_C1  + 1024,        // Em - 0.5 Mtp
  WS_S1    = WS_EMM + 1024,
  WS_FPT   = WS_S1  + 1024,
  WS_ETA0  = WS_FPT + 1024,
  WS_CTB   = WS_ETA0 + 32,
  WS_QIVTB = WS_CTB + 32,
  WS_FMT   = WS_QIVTB + 32,
  WS_ETAF  = WS_FMT + 32,
  WS_LDS3  = WS_ETAF + 32,
  WS_DACC  = WS_LDS3 + 4,          // 4 doubles
  WS_Z512  = WS_DACC + 8,
  WS_OPS   = WS_Z512 + 1024,       // 6 ops x (K,A,G) x 1024
  WS_GBAR  = WS_OPS + 6*3072,      // 64 barrier counters
  WS_ETA_A = WS_GBAR + 64,         // NCH x 1056
  WS_ETA_B = WS_ETA_A + NCH*1056,
  WS_CEA   = WS_ETA_B + NCH*1056,  // NCH x 2048
  WS_CEB   = WS_CEA + NCH*2048,
  WS_END   = WS_CEB + NCH*2048
};
// G-scan aliases S-scan buffers (time-disjoint: S data in CEB consumed at P8;
// kga writes CEA at P8; G levels ping CEA->CEB->CEA->CEB; kgb reads CEB)
enum : int { WS_GEA = WS_CEA, WS_GEB = WS_CEB };
static_assert(WS_DACC % 2 == 0, "double alignment");

// ---------------- helpers ----------------
__device__ __forceinline__ float rlane(float v, int l) {
  return __uint_as_float(__builtin_amdgcn_readlane(__float_as_uint(v), l));
}
__device__ __forceinline__ float dot4(const float4 a, const float4 b) {
  return a.x*b.x + a.y*b.y + a.z*b.z + a.w*b.w;
}

__device__ __forceinline__ double gj_inv32(float a[32]) {
  double pp = 1.0;
#pragma unroll
  for (int p = 0; p < 32; ++p) {
    const float piv = rlane(a[p], p);
    pp *= (double)piv;
    const float sc = a[p] * (1.0f / piv);
#pragma unroll
    for (int r = 0; r < 32; ++r) {
      if (r != p) a[r] -= rlane(a[r], p) * sc;
    }
    a[p] = sc;
  }
  return pp;
}

// invert 32x32 (stride-ST LDS) in place; call with tid<64 only
__device__ __forceinline__ double wave_inv36(float* M, int tid) {
  float a[32]; const int cc = tid & 31;
#pragma unroll
  for (int r = 0; r < 32; ++r)
    a[r] = (tid < 32) ? M[r*ST + cc] : ((r == tid - 32) ? 1.f : 0.f);
  const double pp = gj_inv32(a);
  if (tid >= 32) {
    const int c2 = tid - 32;
#pragma unroll
    for (int r = 0; r < 32; ++r) M[r*ST + c2] = a[r];
  }
  return pp;
}

__device__ __forceinline__ float block_reduce(float v, float* red, int tid) {
#pragma unroll
  for (int m = 32; m >= 1; m >>= 1) v += __shfl_xor(v, m, 64);
  if ((tid & 63) == 0) red[tid >> 6] = v;
  __syncthreads();
  return red[0] + red[1] + red[2] + red[3];
}

// global (stride 32) <-> LDS (stride ST), float4
__device__ __forceinline__ void stage_mat(const float* __restrict__ g, float* L, int tid) {
  const int r = tid >> 3, c = (tid & 7) * 4;
  *(float4*)(L + r*ST + c) = *(const float4*)(g + r*32 + c);
}
__device__ __forceinline__ void destage_mat(const float* L, float* __restrict__ g, int tid) {
  const int r = tid >> 3, c = (tid & 7) * 4;
  *(float4*)(g + r*32 + c) = *(const float4*)(L + r*ST + c);
}

// ---- vectorized matmul family (all LDS stride ST, rows 16B-aligned) ----
// C = A @ B^T
__device__ __forceinline__ void mm_rr(const float* A, const float* B, float* C, int tid) {
  const int j = tid & 31, r0 = tid >> 5;
  float4 b[8];
#pragma unroll
  for (int kk = 0; kk < 8; ++kk) b[kk] = *(const float4*)(B + j*ST + 4*kk);
#pragma unroll
  for (int m = 0; m < 4; ++m) {
    const int ri = r0 + 8*m;
    float s = 0.f;
#pragma unroll
    for (int kk = 0; kk < 8; ++kk)
      s += dot4(*(const float4*)(A + ri*ST + 4*kk), b[kk]);
    C[ri*ST+j] = s;
  }
}
// C = Base - A @ B^T (Base LDS)
__device__ __forceinline__ void mm_rr_sub(const float* A, const float* B,
                                          const float* Base, float* C, int tid) {
  const int j = tid & 31, r0 = tid >> 5;
  float4 b[8];
#pragma unroll
  for (int kk = 0; kk < 8; ++kk) b[kk] = *(const float4*)(B + j*ST + 4*kk);
#pragma unroll
  for (int m = 0; m < 4; ++m) {
    const int ri = r0 + 8*m;
    float s = 0.f;
#pragma unroll
    for (int kk = 0; kk < 8; ++kk)
      s += dot4(*(const float4*)(A + ri*ST + 4*kk), b[kk]);
    C[ri*ST+j] = Base[ri*ST+j] - s;
  }
}
// C = gBase - A @ B^T (Base global stride 32)
__device__ __forceinline__ void mm_rr_subg(const float* A, const float* B,
                                           const float* __restrict__ gBase,
                                           float* C, int tid) {
  const int j = tid & 31, r0 = tid >> 5;
  float4 b[8];
#pragma unroll
  for (int kk = 0; kk < 8; ++kk) b[kk] = *(const float4*)(B + j*ST + 4*kk);
#pragma unroll
  for (int m = 0; m < 4; ++m) {
    const int ri = r0 + 8*m;
    float s = 0.f;
#pragma unroll
    for (int kk = 0; kk < 8; ++kk)
      s += dot4(*(const float4*)(A + ri*ST + 4*kk), b[kk]);
    C[ri*ST+j] = gBase[ri*32+j] - s;
  }
}
// C = A @ B
__device__ __forceinline__ void mm_p(const float* A, const float* B, float* C, int tid) {
  const int ri = tid >> 3, j4 = (tid & 7) * 4;
  float4 acc = {0.f,0.f,0.f,0.f};
#pragma unroll 8
  for (int k = 0; k < 32; ++k) {
    const float a = A[ri*ST + k];
    const float4 b = *(const float4*)(B + k*ST + j4);
    acc.x += a*b.x; acc.y += a*b.y; acc.z += a*b.z; acc.w += a*b.w;
  }
  *(float4*)(C + ri*ST + j4) = acc;
}
// C = Base - A @ B (Base LDS)
__device__ __forceinline__ void mm_p_sub(const float* A, const float* B,
                                         const float* Base, float* C, int tid) {
  const int ri = tid >> 3, j4 = (tid & 7) * 4;
  float4 acc = *(const float4*)(Base + ri*ST + j4);
#pragma unroll 8
  for (int k = 0; k < 32; ++k) {
    const float a = A[ri*ST + k];
    const float4 b = *(const float4*)(B + k*ST + j4);
    acc.x -= a*b.x; acc.y -= a*b.y; acc.z -= a*b.z; acc.w -= a*b.w;
  }
  *(float4*)(C + ri*ST + j4) = acc;
}
// C = A^T @ B
__device__ __forceinline__ void mm_tp(const float* A, const float* B, float* C, int tid) {
  const int ri = tid >> 3, j4 = (tid & 7) * 4;
  float4 acc = {0.f,0.f,0.f,0.f};
#pragma unroll 8
  for (int k = 0; k < 32; ++k) {
    const float a = A[k*ST + ri];
    const float4 b = *(const float4*)(B + k*ST + j4);
    acc.x += a*b.x; acc.y += a*b.y; acc.z += a*b.z; acc.w += a*b.w;
  }
  *(float4*)(C + ri*ST + j4) = acc;
}
// C = A^T @ B + AddL (LDS)
__device__ __forceinline__ void mm_tp_addL(const float* A, const float* B,
                                           const float* AddL, float* C, int tid) {
  const int ri = tid >> 3, j4 = (tid & 7) * 4;
  float4 acc = *(const float4*)(AddL + ri*ST + j4);
#pragma unroll 8
  for (int k = 0; k < 32; ++k) {
    const float a = A[k*ST + ri];
    const float4 b = *(const float4*)(B + k*ST + j4);
    acc.x += a*b.x; acc.y += a*b.y; acc.z += a*b.z; acc.w += a*b.w;
  }
  *(float4*)(C + ri*ST + j4) = acc;
}
// C = A^T @ B + gAdd (global stride 32)
__device__ __forceinline__ void mm_tp_addg(const float* A, const float* B,
                                           const float* __restrict__ gAdd,
                                           float* C, int tid) {
  const int ri = tid >> 3, j4 = (tid & 7) * 4;
  float4 acc = *(const float4*)(gAdd + ri*32 + j4);
#pragma unroll 8
  for (int k = 0; k < 32; ++k) {
    const float a = A[k*ST + ri];
    const float4 b = *(const float4*)(B + k*ST + j4);
    acc.x += a*b.x; acc.y += a*b.y; acc.z += a*b.z; acc.w += a*b.w;
  }
  *(float4*)(C + ri*ST + j4) = acc;
}

// ---------------- grid barrier ----------------
__device__ __forceinline__ void gridbar(unsigned* bars, int idx) {
  __syncthreads();
  if (threadIdx.x == 0) {
    __threadfence();
    __hip_atomic_fetch_add(&bars[idx], 1u, __ATOMIC_RELEASE, __HIP_MEMORY_SCOPE_AGENT);
    while (__hip_atomic_load(&bars[idx], __ATOMIC_ACQUIRE, __HIP_MEMORY_SCOPE_AGENT)
           < (unsigned)NB)
      __builtin_amdgcn_s_sleep(2);
  }
  __syncthreads();
}

// ---------------- k2 body (block 0, global stride 32 — unchanged from R6) ----------------
__device__ void dev_k2(const float* __restrict__ obs, const float* __restrict__ vpm,
                       const float* __restrict__ vtw, const float* __restrict__ vtb,
                       const float* __restrict__ vew, const float* __restrict__ veb,
                       const float* __restrict__ mtw, const float* __restrict__ mew,
                       float* __restrict__ ws, int tid) {
  const int j = tid & 31, r0 = tid >> 5;
#pragma unroll
  for (int m = 0; m < 4; ++m) {
    const int ri = r0 + 8*m;
    float s1 = 0.f, s2 = 0.f, s3 = 0.f, s4 = 0.f;
    for (int k = 0; k < 32; ++k) {
      s1 += ws[WS_QI  + ri*32 + k] * vtw[k*32 + j];
      s2 += vew[k*32 + ri] * ws[WS_RI + k*32 + j];
      s3 += ws[WS_MTP + ri*32 + k] * mtw[k*32 + j];
      s4 += ws[WS_MEP + ri*32 + k] * mew[k*32 + j];
    }
    ws[WS_QIW + ri*32 + j] = s1;
    ws[WS_HTRI + ri*32 + j] = s2;
    ws[WS_FPT + ri*32 + j] = s3;      // temp Mtp@mtw
    ws[WS_EML + ri*32 + j] = -0.5f * s4;
  }
  __syncthreads();
#pragma unroll
  for (int m = 0; m < 4; ++m) {
    const int ri = r0 + 8*m;
    float s1 = 0.f, s2 = 0.f, s3 = 0.f, s4 = 0.f;
    for (int k = 0; k < 32; ++k) {
      s1 += vtw[k*32 + ri] * ws[WS_QIW + k*32 + j];
      s2 += ws[WS_HTRI + ri*32 + k] * vew[k*32 + j];
      s3 += mtw[k*32 + ri] * ws[WS_FPT + k*32 + j];
      s4 += mew[k*32 + ri] * ws[WS_EML + k*32 + j];
    }
    ws[WS_CW + ri*32 + j] = s1;
    ws[WS_HTRIH + ri*32 + j] = s2;
    ws[WS_LAM0CW + ri*32 + j] = ws[WS_P0I + ri*32 + j] + s1 + s2;
    ws[WS_QHC    + ri*32 + j] = ws[WS_QI  + ri*32 + j] + s1 + s2;
    ws[WS_TQ + ri*32 + j] = s3;
    ws[WS_EM + ri*32 + j] = s4;
    ws[WS_S1 + ri*32 + j] = s4 - 0.5f * ws[WS_MPP + ri*32 + j];
    ws[WS_C1 + ri*32 + j] = ws[WS_FPT + j*32 + ri];           // (Mtp@mtw)^T
    ws[WS_EMM + ri*32 + j] = s4 - 0.5f * ws[WS_MTP + ri*32 + j];
  }
  if (tid < 32) {
    float s1 = 0.f, s2 = 0.f, s3 = 0.f;
    for (int k = 0; k < 32; ++k) {
      s1 += ws[WS_QIW + k*32 + tid] * vtb[k];
      s2 += ws[WS_P0I + tid*32 + k] * vpm[k]
          + ws[WS_HTRI + tid*32 + k] * (obs[k] - veb[k]);
      s3 += ws[WS_QI + tid*32 + k] * vtb[k];
    }
    ws[WS_CTB + tid] = s1;
    ws[WS_ETA0 + tid] = s2;
    ws[WS_QIVTB + tid] = s3;
  }
  __syncthreads();
  if (tid == 0) {
    const double ldmt = (double)ws[WS_LDS3 + 0];
    const double ldme = (double)ws[WS_LDS3 + 1];
    const double ldmp = (double)ws[WS_LDS3 + 2];
    const double ct_me = -0.5 * (32.0 * LOG2PI + ldme);
    const double ct_mt = -0.5 * (32.0 * LOG2PI + ldmt);
    const double ct_mp = -0.5 * (32.0 * LOG2PI + ldmp);
    double c = ct_mp + ct_me;
    c += (double)(TT - 1) * (ct_me + ct_mt + 0.5 * 32.0 * LOG2PI + 16.0);
    c += 0.5 * 32.0 * LOG2PI + 16.0;
    ((double*)(ws + WS_DACC))[0] = c;
  }
}

// ---------------- Riccati operator squaring (block 0) ----------------
__device__ void dev_compose(float* __restrict__ ws, float* sm, int tid) {
  float *Kc = sm,      *Ac = sm+MS,   *Gc = sm+2*MS;
  float *Kn = sm+3*MS, *An = sm+4*MS, *Gn = sm+5*MS;
  float *Mi = sm+6*MS, *V1 = sm+7*MS, *Wm = sm+8*MS;
  stage_mat(ws + WS_QHC, Kc, tid);
  stage_mat(ws + WS_QIW, Ac, tid);
  for (int e = tid; e < MS; e += 256) Gc[e] = 0.f;
  __syncthreads();
  for (int d = 0; d < 8; ++d) {          // builds Phi^{2^{d+1}}
    for (int e = tid; e < MS; e += 256) Mi[e] = Kc[e] + Gc[e];
    __syncthreads();
    if (tid < 64) wave_inv36(Mi, tid);
    __syncthreads();
    mm_rr(Ac, Mi, V1, tid);   // A M^-1 (M^-1 sym)
    mm_tp(Ac, Mi, Wm, tid);   // A^T M^-1
    __syncthreads();
    mm_rr_sub(V1, Ac, Kc, Kn, tid);   // K' = K - A M^-1 A^T
    mm_p(V1, Ac, An, tid);            // A' = A M^-1 A
    mm_p_sub(Wm, Ac, Gc, Gn, tid);    // G' = G - A^T M^-1 A
    __syncthreads();
    float* tp;
    tp=Kc; Kc=Kn; Kn=tp;  tp=Ac; Ac=An; An=tp;  tp=Gc; Gc=Gn; Gn=tp;
    if (d >= 2) {                       // save Phi^8 .. Phi^256 (ops 0..5)
      float* op = ws + WS_OPS + (d-2)*3072;
      destage_mat(Kc, op, tid);
      destage_mat(Ac, op + 1024, tid);
      destage_mat(Gc, op + 2048, tid);
    }
  }
}

// ---------------- eta machinery ----------------
__device__ void dev_keta_a(float* __restrict__ ws, float* sm, int tid, int c) {
  float *Aa = sm, *Ab = sm+MS, *Xl = sm+2*MS, *bb = sm+3*MS;
  const int t1 = CH*c + 1;
  stage_mat(ws + WS_X + t1*1024, Aa, tid);
  if (tid < 32) bb[tid] = ws[WS_YT + t1*32 + tid];
  __syncthreads();
  float *Acur = Aa, *Anew = Ab; int pb = 0;
  for (int t = t1 + 1; t <= t1 + CH - 1; ++t) {
    stage_mat(ws + WS_X + t*1024, Xl, tid);
    __syncthreads();
    mm_p(Xl, Acur, Anew, tid);
    if (tid < 32) {
      float s = ws[WS_YT + t*32 + tid];
      for (int k = 0; k < 32; ++k) s += Xl[tid*ST+k] * bb[pb*32 + k];
      bb[(pb^1)*32 + tid] = s;
    }
    __syncthreads();
    float* tp = Acur; Acur = Anew; Anew = tp; pb ^= 1;
  }
  float* dst = ws + WS_ETA_A + (c+1)*1056;
  destage_mat(Acur, dst, tid);
  if (tid < 32) dst[1024 + tid] = bb[pb*32 + tid];
}

// radix-4 affine prefix level (elements stride 1056 in ws)
__device__ void dev_eta_lvl4(float* __restrict__ ws, float* sm,
                             int inoff, int outoff, int step, int tid, int c) {
  const float* in = ws + inoff;
  float* out = ws + outoff;
  float *AR0 = sm, *AR1 = sm+MS, *A0 = sm+2*MS;
  float *bv = sm+3*MS;   // bv[0..31], bv[32..63] ping-pong; b0 at +64
  float *b0 = bv + 64;
  stage_mat(in + c*1056, AR0, tid);
  if (tid < 32) bv[tid] = in[c*1056 + 1024 + tid];
  __syncthreads();
  float *AR = AR0, *At = AR1; int pb = 0;
  for (int kk = 1; kk <= 3; ++kk) {
    const int idx = c - kk*step;
    if (idx < 0) break;
    stage_mat(in + idx*1056, A0, tid);
    if (tid < 32) b0[tid] = in[idx*1056 + 1024 + tid];
    __syncthreads();
    mm_p(AR, A0, At, tid);                 // A' = A_R @ A_old
    if (tid < 32) {
      float s = bv[pb*32 + tid];
      for (int k = 0; k < 32; ++k) s += AR[tid*ST+k] * b0[k];
      bv[(pb^1)*32 + tid] = s;             // b' = A_R b_old + b_R
    }
    __syncthreads();
    float* tp = AR; AR = At; At = tp; pb ^= 1;
  }
  destage_mat(AR, out + c*1056, tid);
  if (tid < 32) out[c*1056 + 1024 + tid] = bv[pb*32 + tid];
}

__device__ void dev_keta_b(float* __restrict__ ws, float* sm, int tid, int c) {
  float *Ap = sm, *Bl = sm+MS, *Xl = sm+2*MS, *zeta = sm+3*MS, *zn = zeta+32;
  const int nst = (c == NCH-1) ? CH-1 : CH;
  stage_mat(ws + WS_ETA_B + c*1056, Ap, tid);
  __syncthreads();
  if (tid < 32) {
    float s = ws[WS_ETA_B + c*1056 + 1024 + tid];
    for (int k = 0; k < 32; ++k)
      s += Ap[tid*ST+k] * (ws[WS_ETA0 + k] - ws[WS_CTB + k]);
    zeta[tid] = s;
  }
  __syncthreads();
  for (int i = 0; i < nst; ++i) {
    const int t = CH*c + 1 + i;
    stage_mat(ws + WS_BCOV + t*1024, Bl, tid);
    stage_mat(ws + WS_X + t*1024, Xl, tid);
    __syncthreads();
    if (tid < 32) {
      float s = 0.f;
      for (int k = 0; k < 32; ++k) s += Bl[tid*ST+k] * zeta[k];
      ws[WS_BA + t*32 + tid] = s;
    } else if (tid < 64) {
      const int i2 = tid - 32;
      float s = ws[WS_YT + t*32 + i2];
      for (int k = 0; k < 32; ++k) s += Xl[i2*ST+k] * zeta[k];
      zn[i2] = s;
    }
    __syncthreads();
    if (tid < 32) zeta[tid] = zn[tid];
    __syncthreads();
  }
  if (c == NCH-1 && tid < 32)
    ws[WS_ETAF + tid] = zeta[tid] + ws[WS_CTB + tid];
}

// ---------------- S machinery ----------------
__device__ void dev_ksa(float* __restrict__ ws, float* sm, int tid, int c) {
  float *BTa=sm,      *BTb=sm+MS,   *Ka=sm+2*MS,  *Kb=sm+3*MS,
        *Tk=sm+4*MS,  *XC1=sm+5*MS, *Xl=sm+6*MS,  *KmTQ=sm+7*MS,
        *TQl=sm+8*MS, *EMMl=sm+9*MS,*C1l=sm+10*MS;
  const int t1 = CH*c + 1, t2 = CH*c + CH;
  const int j = tid & 31, r0 = tid >> 5;
  stage_mat(ws + WS_TQ, TQl, tid);
  stage_mat(ws + WS_EMM, EMMl, tid);
  stage_mat(ws + WS_C1, C1l, tid);
  for (int e = tid; e < MS; e += 256) {
    const int r = e / ST, cc = e - ST*r;
    BTa[e] = (cc < 32 && cc == r) ? 1.f : 0.f;   // BT = I
    Ka[e] = 0.f;                                  // K = 0
  }
  __syncthreads();
  float *BTc = BTa, *BTn = BTb, *Kc = Ka, *Kn = Kb;
  for (int t = t1; t <= t2; ++t) {
    stage_mat(ws + WS_X + t*1024, Xl, tid);
    for (int e = tid; e < MS; e += 256) KmTQ[e] = Kc[e] - 0.5f * TQl[e];
    __syncthreads();
    mm_rr(BTc, Xl, BTn, tid);          // BT' = BT @ X^T
    mm_rr(Xl, KmTQ, Tk, tid);          // X @ (K - .5TQ)  (sym)
    mm_p(Xl, C1l, XC1, tid);           // X @ C1
    __syncthreads();
    {
      float4 xb[8];
#pragma unroll
      for (int kk = 0; kk < 8; ++kk) xb[kk] = *(const float4*)(Xl + j*ST + 4*kk);
#pragma unroll
      for (int m = 0; m < 4; ++m) {
        const int ri = r0 + 8*m;
        float s = 0.f;
#pragma unroll
        for (int kk = 0; kk < 8; ++kk)
          s += dot4(*(const float4*)(Tk + ri*ST + 4*kk), xb[kk]);
        Kn[ri*ST+j] = s + 0.5f*(XC1[ri*ST+j] + XC1[j*ST+ri]) + EMMl[ri*ST+j];
      }
    }
    __syncthreads();
    float* tp = BTc; BTc = BTn; BTn = tp;
    tp = Kc; Kc = Kn; Kn = tp;
  }
  float* dst = ws + WS_CEA + (c+1)*2048;
  destage_mat(BTc, dst, tid);
  destage_mat(Kc, dst + 1024, tid);
}

// radix-4 S-scan level (elements stride 2048 in ws)
__device__ void dev_ks_lvl4(float* __restrict__ ws, float* sm,
                            int inoff, int outoff, int step, int tid, int c) {
  const float* in = ws + inoff;
  float* out = ws + outoff;
  float *BT0=sm,      *BT1=sm+MS,   *K0=sm+2*MS, *K1=sm+3*MS,
        *BTo=sm+4*MS, *Ko=sm+5*MS,  *tmp=sm+6*MS;
  stage_mat(in + c*2048, BT0, tid);
  stage_mat(in + c*2048 + 1024, K0, tid);
  __syncthreads();
  float *BTR = BT0, *BTt = BT1, *KR = K0, *Kt = K1;
  for (int kk = 1; kk <= 3; ++kk) {
    const int idx = c - kk*step;
    if (idx < 0) break;
    stage_mat(in + idx*2048, BTo, tid);
    stage_mat(in + idx*2048 + 1024, Ko, tid);
    __syncthreads();
    mm_p(Ko, BTR, tmp, tid);           // K_old @ B_R^T
    mm_p(BTo, BTR, BTt, tid);          // BT' = BT_old @ BT_R
    __syncthreads();
    mm_tp_addL(BTR, tmp, KR, Kt, tid); // K' = B_R tmp + K_R
    __syncthreads();
    float* tp = BTR; BTR = BTt; BTt = tp;
    tp = KR; KR = Kt; Kt = tp;
  }
  destage_mat(BTR, out + c*2048, tid);
  destage_mat(KR, out + c*2048 + 1024, tid);
}

__device__ void dev_ksc(float* __restrict__ ws, float* sm, float* red,
                        int tid, int c) {
  float *TQl=sm,    *EMMl=sm+MS,  *C1l=sm+2*MS, *BTP=sm+3*MS, *T1=sm+4*MS,
        *S=sm+5*MS, *SmTQ=sm+6*MS,*Xl=sm+7*MS,  *Bcl=sm+8*MS, *XC1=sm+9*MS;
  const int j = tid & 31, r0 = tid >> 5;
  stage_mat(ws + WS_TQ, TQl, tid);
  stage_mat(ws + WS_EMM, EMMl, tid);
  stage_mat(ws + WS_C1, C1l, tid);
  stage_mat(ws + WS_CEB + c*2048, BTP, tid);
  stage_mat(ws + WS_S1, SmTQ, tid);            // S0 temp
  __syncthreads();
  mm_p(SmTQ, BTP, T1, tid);                    // S0 @ B_P^T
  __syncthreads();
  mm_tp_addg(BTP, T1, ws + WS_CEB + c*2048 + 1024, S, tid);  // S = B_P T1 + K_P
  __syncthreads();
  double accd = 0.0;
  for (int i = 0; i < CH; ++i) {
    const int t = CH*c + 1 + i;
    if (t >= TT) break;
    stage_mat(ws + WS_X + t*1024, Xl, tid);
    stage_mat(ws + WS_BCOV + t*1024, Bcl, tid);
#pragma unroll
    for (int m = 0; m < 4; ++m) {
      const int ri = r0 + 8*m;
      SmTQ[ri*ST+j] = S[ri*ST+j] - 0.5f * TQl[ri*ST+j];
    }
    __syncthreads();                            // Xl/Bcl/SmTQ visible (fixes R6 race)
    float part = 0.f;
#pragma unroll
    for (int m = 0; m < 4; ++m) {
      const int ri = r0 + 8*m;
      part += SmTQ[ri*ST+j] * Bcl[ri*ST+j];     // trace((S-.5TQ) bcov)
    }
    const float r2 = block_reduce(part, red, tid);
    if (tid == 0) accd += (double)r2;
    mm_rr(Xl, SmTQ, T1, tid);                   // X @ (S-.5TQ)  (sym)
    mm_p(Xl, C1l, XC1, tid);
    __syncthreads();
    {
      float4 xb[8];
#pragma unroll
      for (int kk = 0; kk < 8; ++kk) xb[kk] = *(const float4*)(Xl + j*ST + 4*kk);
#pragma unroll
      for (int m = 0; m < 4; ++m) {
        const int ri = r0 + 8*m;
        float s = 0.f;
#pragma unroll
        for (int kk = 0; kk < 8; ++kk)
          s += dot4(*(const float4*)(T1 + ri*ST + 4*kk), xb[kk]);
        S[ri*ST+j] = s + 0.5f*(XC1[ri*ST+j] + XC1[j*ST+ri]) + EMMl[ri*ST+j];
      }
    }
    __syncthreads();
  }
  if (tid == 0) atomicAdd(((double*)(ws + WS_DACC)) + 2, accd);
}

// ---------------- G machinery ----------------
__device__ void dev_kga(float* __restrict__ ws, float* sm, int tid, int c) {
  float *ATa = sm, *ATb = sm+MS, *Xl = sm+2*MS, *bb = sm+3*MS;
  const int t1 = CH*c + 1;
  const int t2 = (CH*c + CH < TT) ? CH*c + CH : TT - 1;
  stage_mat(ws + WS_X + t2*1024, ATa, tid);     // AT = X_{t2}
  if (tid < 32) bb[tid] = ws[WS_BA + t2*32 + tid];
  __syncthreads();
  float *ATc = ATa, *ATn = ATb;
  int pb = 0;
  for (int t = t2 - 1; t >= t1; --t) {
    stage_mat(ws + WS_X + t*1024, Xl, tid);
    __syncthreads();
    mm_p(ATc, Xl, ATn, tid);                    // AT' = AT @ X_t
    if (tid < 32) {
      float s = ws[WS_BA + t*32 + tid];
      for (int k = 0; k < 32; ++k) s += Xl[k*ST+tid] * bb[pb*32 + k];
      bb[(pb^1)*32 + tid] = s;
    }
    __syncthreads();
    float* tp = ATc; ATc = ATn; ATn = tp; pb ^= 1;
  }
  float* dst = ws + WS_GEA + (c-1)*1056;
  destage_mat(ATc, dst, tid);
  if (tid < 32) dst[1024 + tid] = bb[pb*32 + tid];
}

// radix-4 suffix level (elements stride 1056)
__device__ void dev_kg_lvl4(float* __restrict__ ws, float* sm,
                            int inoff, int outoff, int step, int tid, int c) {
  const float* in = ws + inoff;
  float* out = ws + outoff;
  float *AR0 = sm, *AR1 = sm+MS, *ATl = sm+2*MS;
  float *bv = sm+3*MS, *bl = bv + 64;
  stage_mat(in + c*1056, AR0, tid);
  if (tid < 32) bv[tid] = in[c*1056 + 1024 + tid];
  __syncthreads();
  float *AR = AR0, *At = AR1; int pb = 0;
  for (int kk = 1; kk <= 3; ++kk) {
    const int idx = c + kk*step;
    if (idx > NCH - 1) break;
    stage_mat(in + idx*1056, ATl, tid);
    if (tid < 32) bl[tid] = in[idx*1056 + 1024 + tid];
    __syncthreads();
    mm_p(ATl, AR, At, tid);                    // AT' = AT_later @ AT_R
    if (tid < 32) {
      float s = bv[pb*32 + tid];
      for (int k = 0; k < 32; ++k) s += AR[k*ST+tid] * bl[k];  // b' = b_R + A_R b_lat
      bv[(pb^1)*32 + tid] = s;
    }
    __syncthreads();
    float* tp = AR; AR = At; At = tp; pb ^= 1;
  }
  destage_mat(AR, out + c*1056, tid);
  if (tid < 32) out[c*1056 + 1024 + tid] = bv[pb*32 + tid];
}

__device__ void dev_kgb(const float* __restrict__ obs, const float* __restrict__ mpm,
                        const float* __restrict__ mtw, const float* __restrict__ mtb,
                        const float* __restrict__ mew, const float* __restrict__ meb,
                        float* __restrict__ ws, float* sm, float* red, int tid, int c) {
  float *ATa=sm,      *ATb=sm+MS,    *Xl=sm+2*MS,  *Y1=sm+3*MS,  *Y2=sm+4*MS,
        *Jb=sm+5*MS,  *M2T=sm+6*MS,  *mewl=sm+7*MS,*EmLl=sm+8*MS,
        *fPl=sm+9*MS, *Mtpl=sm+10*MS,*Mepl=sm+11*MS,*mtwl=sm+12*MS;
  float *vec = sm + 13*MS;
  float *fml=vec, *mebl=vec+32, *mtbl=vec+64, *mpml=vec+96, *yl=vec+128,
        *bal=vec+160, *gv=vec+192, *cme=vec+224, *cmo=vec+256, *bv=vec+288;
  const int j = tid & 31, r0 = tid >> 5;
  stage_mat(mew, mewl, tid);
  stage_mat(ws + WS_EML, EmLl, tid);
  stage_mat(ws + WS_FPT, fPl, tid);
  stage_mat(ws + WS_MTP, Mtpl, tid);
  stage_mat(ws + WS_MEP, Mepl, tid);
  stage_mat(mtw, mtwl, tid);
  stage_mat(ws + WS_GEB + c*1056, ATa, tid);
  if (tid < 32) {
    fml[tid] = ws[WS_FMT + tid];
    mebl[tid] = meb[tid]; mtbl[tid] = mtb[tid]; mpml[tid] = mpm[tid];
    bv[tid] = ws[WS_GEB + c*1056 + 1024 + tid];
  }
  __syncthreads();
  float *ATc = ATa, *ATo = ATb;
  int bc = 0;
  double accd = 0.0;
  for (int s = CH*c + CH - 1; s >= CH*c; --s) {
    if (s < TT-1) stage_mat(ws + WS_X + (s+1)*1024, Xl, tid);
    if (s == 0)   stage_mat(ws + WS_MPP, Jb, tid);
    if (tid < 32) {
      yl[tid] = obs[s*32 + tid];
      if (s >= 1) bal[tid] = ws[WS_BA + s*32 + tid];
    }
    __syncthreads();
    if (s < TT-1) {
      mm_p(ATc, Xl, ATo, tid);                  // AT' = AT @ X_{s+1}
      if (tid < 32) {
        float v = ws[WS_BA + (s+1)*32 + tid];
        for (int k = 0; k < 32; ++k) v += Xl[k*ST+tid] * bv[bc*32 + k];
        bv[(bc^1)*32 + tid] = v;
      }
    }
    __syncthreads();
    const float* AT = (s < TT-1) ? ATo : ATc;
    const float* bl = (s < TT-1) ? (bv + (bc^1)*32) : (bv + bc*32);
    mm_rr(mewl, AT, Y1, tid);                   // mew@G
    mm_rr(EmLl, AT, Y2, tid);                   // EmL@G
    if (s >= 1) {                               // Jb = mtw@X_s^T - I (X_s global rows)
      const float* Xg = ws + WS_X + s*1024;
      float4 xg[8];
#pragma unroll
      for (int kk = 0; kk < 8; ++kk) xg[kk] = *(const float4*)(Xg + j*32 + 4*kk);
#pragma unroll
      for (int m = 0; m < 4; ++m) {
        const int ri = r0 + 8*m;
        float v = 0.f;
#pragma unroll
        for (int kk = 0; kk < 8; ++kk)
          v += dot4(*(const float4*)(mtwl + ri*ST + 4*kk), xg[kk]);
        Jb[ri*ST+j] = v - ((ri == j) ? 1.f : 0.f);
      }
    }
    if (tid < 32) {
      float g = bl[tid];
      for (int k = 0; k < 32; ++k) g += AT[k*ST+tid] * fml[k];
      gv[tid] = g;                              // g = G@fm + h
    }
    __syncthreads();
    if (s >= 1) mm_rr(AT, Jb, M2T, tid);        // M2^T = G^T Jb^T (row-row form)
    if (tid < 32) {
      float s1v = mebl[tid] - yl[tid];
      for (int k = 0; k < 32; ++k) s1v += mewl[tid*ST+k] * gv[k];
      cme[tid] = s1v;
      float s2v;
      if (s >= 1) {
        s2v = mtbl[tid];
        for (int k = 0; k < 32; ++k)
          s2v += Jb[tid*ST+k] * gv[k] + mtwl[tid*ST+k] * bal[k];
      } else {
        s2v = gv[tid] - mpml[tid];
      }
      cmo[tid] = s2v;
    }
    __syncthreads();
    const float* M2Tp = (s >= 1) ? M2T : AT;
    const float* Mqp  = (s >= 1) ? Mtpl : Jb;   // s=0: Jb holds Mpp
    float4 fb[8], m2b[8];
#pragma unroll
    for (int kk = 0; kk < 8; ++kk) {
      fb[kk]  = *(const float4*)(fPl + j*ST + 4*kk);
      m2b[kk] = *(const float4*)(M2Tp + j*ST + 4*kk);
    }
    float part = 0.f;
#pragma unroll
    for (int m = 0; m < 4; ++m) {
      const int ri = r0 + 8*m;
      float y3 = 0.f, e2 = 0.f, e1 = 0.f;
#pragma unroll
      for (int kk = 0; kk < 8; ++kk) {
        y3 += dot4(*(const float4*)(Y2 + ri*ST + 4*kk), fb[kk]);     // (Y2 fP)[ri][j]
        e2 += dot4(fb[kk], *(const float4*)(M2Tp + ri*ST + 4*kk));   // (fP M2)[j][ri]
        e1 += dot4(*(const float4*)(Mqp + ri*ST + 4*kk), m2b[kk]);   // (Mq M2)[ri][j]
      }
      part += y3 * Y1[j*ST+ri]
            - 0.5f * e1 * e2
            - 0.5f * cme[ri] * Mepl[ri*ST+j] * cme[j]
            - 0.5f * cmo[ri] * Mqp[ri*ST+j] * cmo[j];
    }
    const float r2 = block_reduce(part, red, tid);
    if (tid == 0) accd += (double)r2;
    if (s < TT-1) { float* tp = ATc; ATc = ATo; ATo = tp; bc ^= 1; }
    __syncthreads();
  }
  if (tid == 0) atomicAdd(((double*)(ws + WS_DACC)) + 3, accd);
}

// ---------------- k0: zero barriers + accumulators ----------------
__global__ __launch_bounds__(128) void k0_init(float* __restrict__ ws) {
  const int tid = threadIdx.x;
  if (tid < 64) ((unsigned*)(ws + WS_GBAR))[tid] = 0u;
  if (tid == 64) ((double*)(ws + WS_DACC))[1] = 0.0;
  if (tid == 65) ((double*)(ws + WS_DACC))[2] = 0.0;
  if (tid == 66) ((double*)(ws + WS_DACC))[3] = 0.0;
}

// ---------------- the fused kernel ----------------
__global__ __launch_bounds__(256) void mega(
    const float* __restrict__ obs, const float* __restrict__ mpm,
    const float* __restrict__ mpc, const float* __restrict__ mtw,
    const float* __restrict__ mtb, const float* __restrict__ mtc,
    const float* __restrict__ mew, const float* __restrict__ meb,
    const float* __restrict__ mec, const float* __restrict__ vpm,
    const float* __restrict__ vpc, const float* __restrict__ vtw,
    const float* __restrict__ vtb, const float* __restrict__ vtc,
    const float* __restrict__ vew, const float* __restrict__ veb,
    const float* __restrict__ vcc, float* __restrict__ ws,
    float* __restrict__ out) {
  __shared__ __align__(16) float sm[15360];
  __shared__ float red[4];
  const int tid = threadIdx.x, blk = blockIdx.x;
  unsigned* bars = (unsigned*)(ws + WS_GBAR);
  int bix = 0;

  // ---- P0: 6 constant SPD inverses ----
  if (blk < 6) {
    const float* src = blk==0?mtc : blk==1?mec : blk==2?mpc : blk==3?vtc : blk==4?vcc : vpc;
    float* dst = ws + (blk==0?WS_MTP : blk==1?WS_MEP : blk==2?WS_MPP :
                       blk==3?WS_QI  : blk==4?WS_RI  : WS_P0I);
    if (tid < 64) {
      float a[32]; const int cc = tid & 31;
#pragma unroll
      for (int r = 0; r < 32; ++r)
        a[r] = (tid < 32) ? src[r*32 + cc] : ((r == tid - 32) ? 1.f : 0.f);
      const double pp = gj_inv32(a);
      if (tid >= 32) {
        const int c2 = tid - 32;
#pragma unroll
        for (int r = 0; r < 32; ++r) dst[r*32 + c2] = a[r];
      }
      if (tid == 0 && blk < 3) ws[WS_LDS3 + blk] = (float)log(pp);
    }
  }
  gridbar(bars, bix++);   // 0

  // ---- P1: derived constants ----
  if (blk == 0) dev_k2(obs, vpm, vtw, vtb, vew, veb, mtw, mew, ws, tid);
  gridbar(bars, bix++);   // 1

  // ---- P2: b0 operator squarings; blocks 1..64 compute YT ----
  if (blk == 0) {
    dev_compose(ws, sm, tid);
  } else if (blk <= NCH) {
    const int tb = blk - 1;
    const int t = tb*CH + (tid >> 5), i = tid & 31;
    float s = ws[WS_QIVTB + i] - ws[WS_CTB + i];
    for (int k = 0; k < 32; ++k)
      s += ws[WS_HTRI + i*32 + k] * (obs[t*32 + k] - veb[k]);
    ws[WS_YT + t*32 + i] = s;
  }
  gridbar(bars, bix++);   // 2

  // ---- P3: per-block boundary (bit-decomposition) + chunk expansion ----
  if (blk < NCH) {
    float *Zl=sm, *Mi=sm+MS, *Aol=sm+2*MS, *V1=sm+3*MS;
    float *Bcv=sm+4*MS, *Xs=sm+5*MS, *QiWl=sm+6*MS, *QHCl=sm+7*MS;
    const int c = blk;
    stage_mat(ws + WS_LAM0CW, Zl, tid);
    stage_mat(ws + WS_QIW, QiWl, tid);
    stage_mat(ws + WS_QHC, QHCl, tid);
    __syncthreads();
    for (int k = 0; k < 6; ++k) {
      if (!((c >> k) & 1)) continue;           // block-uniform
      const float* OP = ws + WS_OPS + k*3072;  // (K,A,G) of Phi^{8*2^k}
      {
        const int r = tid >> 3, c4 = (tid & 7) * 4;
        const float4 g = *(const float4*)(OP + 2048 + r*32 + c4);
        float4 z = *(const float4*)(Zl + r*ST + c4);
        z.x += g.x; z.y += g.y; z.z += g.z; z.w += g.w;
        *(float4*)(Mi + r*ST + c4) = z;
      }
      stage_mat(OP + 1024, Aol, tid);
      __syncthreads();
      if (tid < 64) wave_inv36(Mi, tid);
      __syncthreads();
      mm_rr(Aol, Mi, V1, tid);                 // A M^-1 (sym)
      __syncthreads();
      mm_rr_subg(V1, Aol, OP, Zl, tid);        // Z' = K - A M^-1 A^T
      __syncthreads();
    }
    // chunk expansion
    const int nst = (c == NCH-1) ? CH-1 : CH;
    double acc = 0.0;
    for (int i = 0; i < nst; ++i) {
      const int t = CH*c + 1 + i;
      if (tid < 64) {
        float a[32]; const int cc = tid & 31;
#pragma unroll
        for (int r = 0; r < 32; ++r)
          a[r] = (tid < 32) ? Zl[r*ST+cc] : ((r == tid - 32) ? 1.f : 0.f);
        const double pp = gj_inv32(a);
        if (tid >= 32) {
          const int c2 = tid - 32;
#pragma unroll
          for (int r = 0; r < 32; ++r) {
            Bcv[r*ST + c2] = a[r];
            ws[WS_BCOV + t*1024 + r*32 + c2] = a[r];
          }
        }
        if (tid == 0) acc += -log(pp);
      }
      __syncthreads();
      mm_rr(QiWl, Bcv, Xs, tid);               // X = QiW bcov (sym)
      __syncthreads();
      destage_mat(Xs, ws + WS_X + t*1024, tid);
      mm_rr_sub(Xs, QiWl, QHCl, Zl, tid);      // Z' = QHC - X QiW^T
      __syncthreads();
    }
    if (c == NCH-1) destage_mat(Zl, ws + WS_Z512, tid);
    if (tid == 0) atomicAdd(((double*)(ws + WS_DACC)) + 1, acc);
  }
  gridbar(bars, bix++);   // 3

  // ---- P4: eta chunk compose (blk<64) || S chunk compose (blk>=64) ----
  if (blk < NCH) {
    if (blk < NCH-1) {
      dev_keta_a(ws, sm, tid, blk);
    } else {
      for (int e = tid; e < 1056; e += 256)
        ws[WS_ETA_A + e] = (e < 1024 && ((e >> 5) == (e & 31))) ? 1.f : 0.f;
    }
  } else {
    const int c = blk - NCH;
    if (c < NCH-1) {
      dev_ksa(ws, sm, tid, c);
    } else {
      for (int e = tid; e < 2048; e += 256)
        ws[WS_CEA + e] = (e < 1024 && ((e >> 5) == (e & 31))) ? 1.f : 0.f;
    }
  }
  gridbar(bars, bix++);   // 4

  // ---- P5-P7: radix-4 scans, eta (blk<64) || S (blk>=64) ----
  {
    const int steps[3] = {1, 4, 16};
#pragma unroll
    for (int L = 0; L < 3; ++L) {
      const int inA = (L & 1) == 0;
      if (blk < NCH) {
        dev_eta_lvl4(ws, sm, inA ? WS_ETA_A : WS_ETA_B,
                     inA ? WS_ETA_B : WS_ETA_A, steps[L], tid, blk);
      } else {
        dev_ks_lvl4(ws, sm, inA ? WS_CEA : WS_CEB,
                    inA ? WS_CEB : WS_CEA, steps[L], tid, blk - NCH);
      }
      gridbar(bars, bix++);   // 5,6,7
    }
  }
  // eta final in ETA_B; S final in CEB

  // ---- P8: keta_b + kga (blk<64) || ksc (blk>=64) ----
  if (blk < NCH) {
    dev_keta_b(ws, sm, tid, blk);
    __threadfence();         // make this block's BA writes visible to itself
    __syncthreads();
    if (blk == 0) {
      for (int e = tid; e < 1056; e += 256)
        ws[WS_GEA + (NCH-1)*1056 + e] =
            (e < 1024 && ((e >> 5) == (e & 31))) ? 1.f : 0.f;
    } else {
      dev_kga(ws, sm, tid, blk);   // chunk blk -> GEA slot blk-1
    }
  } else {
    dev_ksc(ws, sm, red, tid, blk - NCH);
  }
  gridbar(bars, bix++);   // 8

  // ---- P9-P11: radix-4 G suffix scan (blk<64); kfin on blk127 during P9 ----
  {
    const int steps[3] = {1, 4, 16};
#pragma unroll
    for (int L = 0; L < 3; ++L) {
      const int inA = (L & 1) == 0;
      if (blk < NCH) {
        dev_kg_lvl4(ws, sm, inA ? WS_GEA : WS_GEB,
                    inA ? WS_GEB : WS_GEA, steps[L], tid, blk);
      } else if (L == 0 && blk == NB-1) {
        // kfin: fP = inv(Z512 - CW), fm = fP eta_511, logdet finalize
        if (tid < 64) {
          float a[32]; const int cc = tid & 31;
#pragma unroll
          for (int r = 0; r < 32; ++r) {
            const float v = ws[WS_Z512 + r*32 + cc] - ws[WS_CW + r*32 + cc];
            a[r] = (tid < 32) ? v : ((r == tid - 32) ? 1.f : 0.f);
          }
          const double pp = gj_inv32(a);
          if (tid >= 32) {
            const int c2 = tid - 32;
            float fmv = 0.f;
#pragma unroll
            for (int r = 0; r < 32; ++r) {
              ws[WS_FPT + r*32 + c2] = a[r];
              fmv += a[r] * ws[WS_ETAF + r];
            }
            ws[WS_FMT + c2] = fmv;
          }
          if (tid == 0) {
            double* d = (double*)(ws + WS_DACC);
            d[1] = 0.5 * (d[1] + (-log(pp)));
          }
        }
      }
      gridbar(bars, bix++);   // 9,10,11
    }
  }
  // G final in CEB (= GEB)

  // ---- P12: G expand + final per-s terms (blk<64) ----
  if (blk < NCH) dev_kgb(obs, mpm, mtw, mtb, mew, meb, ws, sm, red, tid, blk);
  gridbar(bars, bix++);   // 12

  // ---- out ----
  if (blk == 0 && tid == 0) {
    const double* d = (const double*)(ws + WS_DACC);
    out[0] = (float)(d[0] + d[1] + d[2] + d[3]);
  }
}

extern "C" void kernel_launch(void* const* d_in, const int* in_sizes, int n_in,
                              void* d_out, int out_size, void* d_ws, size_t ws_size,
                              hipStream_t stream) {
  (void)in_sizes; (void)n_in; (void)out_size; (void)ws_size;
  const float* obs = (const float*)d_in[0];
  const float* mpm = (const float*)d_in[1];
  const float* mpc = (const float*)d_in[2];
  const float* mtw = (const float*)d_in[3];
  const float* mtb = (const float*)d_in[4];
  const float* mtc = (const float*)d_in[5];
  const float* mew = (const float*)d_in[6];
  const float* meb = (const float*)d_in[7];
  const float* mec = (const float*)d_in[8];
  const float* vpm = (const float*)d_in[9];
  const float* vpc = (const float*)d_in[10];
  const float* vtw = (const float*)d_in[11];
  const float* vtb = (const float*)d_in[12];
  const float* vtc = (const float*)d_in[13];
  const float* vew = (const float*)d_in[14];
  const float* veb = (const float*)d_in[15];
  const float* vcc = (const float*)d_in[16];
  float* ws  = (float*)d_ws;
  float* out = (float*)d_out;

  k0_init<<<1, 128, 0, stream>>>(ws);
  mega<<<NB, 256, 0, stream>>>(obs, mpm, mpc, mtw, mtb, mtc, mew, meb, mec,
                               vpm, vpc, vtw, vtb, vtc, vew, veb, vcc, ws, out);
}

// Round 8
// 606.334 us; speedup vs baseline: 56.1387x; 1.0201x over previous
//
#include <hip/hip_runtime.h>
#include <math.h>

#define TT 512
#define CH 8
#define NCH 64
#define NB 128
#define NGRP 8
#define GSZ (NB/NGRP)
#define ST 36
#define MS 1152
#define LOG2PI 1.8378770664093453

static_assert(TT == CH * NCH, "chunking");

// ---------------- workspace layout (float offsets, global stride 32) ----------------
enum : int {
  WS_X     = 0,                    // [TT][32][32] X_t (bA_t = X^T), t=1..511
  WS_BCOV  = WS_X    + TT*1024,
  WS_BA    = WS_BCOV + TT*1024,    // [TT][32] ba_t
  WS_YT    = WS_BA   + TT*32,      // [TT][32] Wt
  WS_MTP   = WS_YT   + TT*32,
  WS_MEP   = WS_MTP + 1024,
  WS_MPP   = WS_MEP + 1024,
  WS_QI    = WS_MPP + 1024,
  WS_RI    = WS_QI  + 1024,
  WS_P0I   = WS_RI  + 1024,
  WS_QIW   = WS_P0I + 1024,
  WS_CW    = WS_QIW + 1024,
  WS_HTRI  = WS_CW  + 1024,
  WS_HTRIH = WS_HTRI+ 1024,
  WS_TQ    = WS_HTRIH+1024,
  WS_EM    = WS_TQ  + 1024,
  WS_EML   = WS_EM  + 1024,
  WS_LAM0CW= WS_EML + 1024,        // Z_1
  WS_QHC   = WS_LAM0CW + 1024,
  WS_C1    = WS_QHC + 1024,        // mtw^T Mtp
  WS_EMM   = WS_C1  + 1024,        // Em - 0.5 Mtp
  WS_S1    = WS_EMM + 1024,
  WS_FPT   = WS_S1  + 1024,
  WS_ETA0  = WS_FPT + 1024,
  WS_CTB   = WS_ETA0 + 32,
  WS_QIVTB = WS_CTB + 32,
  WS_FMT   = WS_QIVTB + 32,
  WS_ETAF  = WS_FMT + 32,
  WS_LDS3  = WS_ETAF + 32,
  WS_DACC  = WS_LDS3 + 4,          // DACC[0] = analytic const (double)
  WS_Z512  = WS_DACC + 8,
  WS_OPS   = WS_Z512 + 1024,       // 6 ops x (K,A,G) x 1024
  WS_GBAR  = WS_OPS + 6*3072,      // hierarchical barrier: 4352 uints
  WS_PART  = WS_GBAR + 4352,       // 208 doubles (0..63 logdet, 64..127 S, 128..191 G, 192 kfin)
  WS_ETA_A = WS_PART + 416,        // NCH x 1056
  WS_ETA_B = WS_ETA_A + NCH*1056,
  WS_CEA   = WS_ETA_B + NCH*1056,  // NCH x 2048 (S); also G 1056-stride (time-disjoint)
  WS_CEB   = WS_CEA + NCH*2048,
  WS_END   = WS_CEB + NCH*2048
};
static_assert(WS_DACC % 2 == 0 && WS_PART % 2 == 0, "double alignment");

// ---------------- helpers ----------------
__device__ __forceinline__ float rlane(float v, int l) {
  return __uint_as_float(__builtin_amdgcn_readlane(__float_as_uint(v), l));
}
__device__ __forceinline__ float dot4(const float4 a, const float4 b) {
  return a.x*b.x + a.y*b.y + a.z*b.z + a.w*b.w;
}

__device__ __forceinline__ double gj_inv32(float a[32]) {
  double pp = 1.0;
#pragma unroll
  for (int p = 0; p < 32; ++p) {
    const float piv = rlane(a[p], p);
    pp *= (double)piv;
    const float sc = a[p] * (1.0f / piv);
#pragma unroll
    for (int r = 0; r < 32; ++r) {
      if (r != p) a[r] -= rlane(a[r], p) * sc;
    }
    a[p] = sc;
  }
  return pp;
}

// invert 32x32 (stride-ST LDS) in place; call with tid<64 only
__device__ __forceinline__ double wave_inv36(float* M, int tid) {
  float a[32]; const int cc = tid & 31;
#pragma unroll
  for (int r = 0; r < 32; ++r)
    a[r] = (tid < 32) ? M[r*ST + cc] : ((r == tid - 32) ? 1.f : 0.f);
  const double pp = gj_inv32(a);
  if (tid >= 32) {
    const int c2 = tid - 32;
#pragma unroll
    for (int r = 0; r < 32; ++r) M[r*ST + c2] = a[r];
  }
  return pp;
}

__device__ __forceinline__ float block_reduce(float v, float* red, int tid) {
#pragma unroll
  for (int m = 32; m >= 1; m >>= 1) v += __shfl_xor(v, m, 64);
  if ((tid & 63) == 0) red[tid >> 6] = v;
  __syncthreads();
  return red[0] + red[1] + red[2] + red[3];
}

__device__ __forceinline__ void stage_mat(const float* __restrict__ g, float* L, int tid) {
  const int r = tid >> 3, c = (tid & 7) * 4;
  *(float4*)(L + r*ST + c) = *(const float4*)(g + r*32 + c);
}
__device__ __forceinline__ void destage_mat(const float* L, float* __restrict__ g, int tid) {
  const int r = tid >> 3, c = (tid & 7) * 4;
  *(float4*)(g + r*32 + c) = *(const float4*)(L + r*ST + c);
}

// ---- vectorized matmul family (LDS stride ST, rows 16B-aligned) ----
__device__ __forceinline__ void mm_rr(const float* A, const float* B, float* C, int tid) {
  const int j = tid & 31, r0 = tid >> 5;
  float4 b[8];
#pragma unroll
  for (int kk = 0; kk < 8; ++kk) b[kk] = *(const float4*)(B + j*ST + 4*kk);
#pragma unroll
  for (int m = 0; m < 4; ++m) {
    const int ri = r0 + 8*m;
    float s = 0.f;
#pragma unroll
    for (int kk = 0; kk < 8; ++kk)
      s += dot4(*(const float4*)(A + ri*ST + 4*kk), b[kk]);
    C[ri*ST+j] = s;
  }
}
__device__ __forceinline__ void mm_rr_sub(const float* A, const float* B,
                                          const float* Base, float* C, int tid) {
  const int j = tid & 31, r0 = tid >> 5;
  float4 b[8];
#pragma unroll
  for (int kk = 0; kk < 8; ++kk) b[kk] = *(const float4*)(B + j*ST + 4*kk);
#pragma unroll
  for (int m = 0; m < 4; ++m) {
    const int ri = r0 + 8*m;
    float s = 0.f;
#pragma unroll
    for (int kk = 0; kk < 8; ++kk)
      s += dot4(*(const float4*)(A + ri*ST + 4*kk), b[kk]);
    C[ri*ST+j] = Base[ri*ST+j] - s;
  }
}
__device__ __forceinline__ void mm_rr_subg(const float* A, const float* B,
                                           const float* __restrict__ gBase,
                                           float* C, int tid) {
  const int j = tid & 31, r0 = tid >> 5;
  float4 b[8];
#pragma unroll
  for (int kk = 0; kk < 8; ++kk) b[kk] = *(const float4*)(B + j*ST + 4*kk);
#pragma unroll
  for (int m = 0; m < 4; ++m) {
    const int ri = r0 + 8*m;
    float s = 0.f;
#pragma unroll
    for (int kk = 0; kk < 8; ++kk)
      s += dot4(*(const float4*)(A + ri*ST + 4*kk), b[kk]);
    C[ri*ST+j] = gBase[ri*32+j] - s;
  }
}
__device__ __forceinline__ void mm_p(const float* A, const float* B, float* C, int tid) {
  const int ri = tid >> 3, j4 = (tid & 7) * 4;
  float4 acc = {0.f,0.f,0.f,0.f};
#pragma unroll 8
  for (int k = 0; k < 32; ++k) {
    const float a = A[ri*ST + k];
    const float4 b = *(const float4*)(B + k*ST + j4);
    acc.x += a*b.x; acc.y += a*b.y; acc.z += a*b.z; acc.w += a*b.w;
  }
  *(float4*)(C + ri*ST + j4) = acc;
}
__device__ __forceinline__ void mm_p_sub(const float* A, const float* B,
                                         const float* Base, float* C, int tid) {
  const int ri = tid >> 3, j4 = (tid & 7) * 4;
  float4 acc = *(const float4*)(Base + ri*ST + j4);
#pragma unroll 8
  for (int k = 0; k < 32; ++k) {
    const float a = A[ri*ST + k];
    const float4 b = *(const float4*)(B + k*ST + j4);
    acc.x -= a*b.x; acc.y -= a*b.y; acc.z -= a*b.z; acc.w -= a*b.w;
  }
  *(float4*)(C + ri*ST + j4) = acc;
}
__device__ __forceinline__ void mm_tp(const float* A, const float* B, float* C, int tid) {
  const int ri = tid >> 3, j4 = (tid & 7) * 4;
  float4 acc = {0.f,0.f,0.f,0.f};
#pragma unroll 8
  for (int k = 0; k < 32; ++k) {
    const float a = A[k*ST + ri];
    const float4 b = *(const float4*)(B + k*ST + j4);
    acc.x += a*b.x; acc.y += a*b.y; acc.z += a*b.z; acc.w += a*b.w;
  }
  *(float4*)(C + ri*ST + j4) = acc;
}
__device__ __forceinline__ void mm_tp_addL(const float* A, const float* B,
                                           const float* AddL, float* C, int tid) {
  const int ri = tid >> 3, j4 = (tid & 7) * 4;
  float4 acc = *(const float4*)(AddL + ri*ST + j4);
#pragma unroll 8
  for (int k = 0; k < 32; ++k) {
    const float a = A[k*ST + ri];
    const float4 b = *(const float4*)(B + k*ST + j4);
    acc.x += a*b.x; acc.y += a*b.y; acc.z += a*b.z; acc.w += a*b.w;
  }
  *(float4*)(C + ri*ST + j4) = acc;
}

// ---------------- hierarchical grid barrier ----------------
// layout in GBAR (uints): lcl[idx][g] @ idx*128+g*16 ; go[idx][g] @ 2048+idx*128+g*16 ;
// glob[idx] @ 4096+idx*16.  Cross-XCD serialized RMWs per barrier: 8 (was 128).
__device__ __forceinline__ void gridbar(unsigned* base, int idx, int blk) {
  __syncthreads();
  if (threadIdx.x == 0) {
    const int g = blk & (NGRP-1);
    unsigned* lcl  = base + idx*128 + g*16;
    unsigned* go   = base + 2048 + idx*128 + g*16;
    unsigned* glob = base + 4096 + idx*16;
    __threadfence();
    __hip_atomic_fetch_add(lcl, 1u, __ATOMIC_RELEASE, __HIP_MEMORY_SCOPE_AGENT);
    if (blk < NGRP) {   // group leader (blk == g)
      while (__hip_atomic_load(lcl, __ATOMIC_ACQUIRE, __HIP_MEMORY_SCOPE_AGENT)
             < (unsigned)GSZ)
        __builtin_amdgcn_s_sleep(1);
      __hip_atomic_fetch_add(glob, 1u, __ATOMIC_RELEASE, __HIP_MEMORY_SCOPE_AGENT);
      while (__hip_atomic_load(glob, __ATOMIC_ACQUIRE, __HIP_MEMORY_SCOPE_AGENT)
             < (unsigned)NGRP)
        __builtin_amdgcn_s_sleep(1);
      __hip_atomic_store(go, 1u, __ATOMIC_RELEASE, __HIP_MEMORY_SCOPE_AGENT);
    } else {
      while (__hip_atomic_load(go, __ATOMIC_ACQUIRE, __HIP_MEMORY_SCOPE_AGENT) == 0u)
        __builtin_amdgcn_s_sleep(1);
    }
  }
  __syncthreads();
}

// ---------------- k2 body (block 0) ----------------
__device__ void dev_k2(const float* __restrict__ obs, const float* __restrict__ vpm,
                       const float* __restrict__ vtw, const float* __restrict__ vtb,
                       const float* __restrict__ vew, const float* __restrict__ veb,
                       const float* __restrict__ mtw, const float* __restrict__ mew,
                       float* __restrict__ ws, int tid) {
  const int j = tid & 31, r0 = tid >> 5;
#pragma unroll
  for (int m = 0; m < 4; ++m) {
    const int ri = r0 + 8*m;
    float s1 = 0.f, s2 = 0.f, s3 = 0.f, s4 = 0.f;
    for (int k = 0; k < 32; ++k) {
      s1 += ws[WS_QI  + ri*32 + k] * vtw[k*32 + j];
      s2 += vew[k*32 + ri] * ws[WS_RI + k*32 + j];
      s3 += ws[WS_MTP + ri*32 + k] * mtw[k*32 + j];
      s4 += ws[WS_MEP + ri*32 + k] * mew[k*32 + j];
    }
    ws[WS_QIW + ri*32 + j] = s1;
    ws[WS_HTRI + ri*32 + j] = s2;
    ws[WS_FPT + ri*32 + j] = s3;      // temp Mtp@mtw
    ws[WS_EML + ri*32 + j] = -0.5f * s4;
  }
  __syncthreads();
#pragma unroll
  for (int m = 0; m < 4; ++m) {
    const int ri = r0 + 8*m;
    float s1 = 0.f, s2 = 0.f, s3 = 0.f, s4 = 0.f;
    for (int k = 0; k < 32; ++k) {
      s1 += vtw[k*32 + ri] * ws[WS_QIW + k*32 + j];
      s2 += ws[WS_HTRI + ri*32 + k] * vew[k*32 + j];
      s3 += mtw[k*32 + ri] * ws[WS_FPT + k*32 + j];
      s4 += mew[k*32 + ri] * ws[WS_EML + k*32 + j];
    }
    ws[WS_CW + ri*32 + j] = s1;
    ws[WS_HTRIH + ri*32 + j] = s2;
    ws[WS_LAM0CW + ri*32 + j] = ws[WS_P0I + ri*32 + j] + s1 + s2;
    ws[WS_QHC    + ri*32 + j] = ws[WS_QI  + ri*32 + j] + s1 + s2;
    ws[WS_TQ + ri*32 + j] = s3;
    ws[WS_EM + ri*32 + j] = s4;
    ws[WS_S1 + ri*32 + j] = s4 - 0.5f * ws[WS_MPP + ri*32 + j];
    ws[WS_C1 + ri*32 + j] = ws[WS_FPT + j*32 + ri];           // (Mtp@mtw)^T
    ws[WS_EMM + ri*32 + j] = s4 - 0.5f * ws[WS_MTP + ri*32 + j];
  }
  if (tid < 32) {
    float s1 = 0.f, s2 = 0.f, s3 = 0.f;
    for (int k = 0; k < 32; ++k) {
      s1 += ws[WS_QIW + k*32 + tid] * vtb[k];
      s2 += ws[WS_P0I + tid*32 + k] * vpm[k]
          + ws[WS_HTRI + tid*32 + k] * (obs[k] - veb[k]);
      s3 += ws[WS_QI + tid*32 + k] * vtb[k];
    }
    ws[WS_CTB + tid] = s1;
    ws[WS_ETA0 + tid] = s2;
    ws[WS_QIVTB + tid] = s3;
  }
  __syncthreads();
  if (tid == 0) {
    const double ldmt = (double)ws[WS_LDS3 + 0];
    const double ldme = (double)ws[WS_LDS3 + 1];
    const double ldmp = (double)ws[WS_LDS3 + 2];
    const double ct_me = -0.5 * (32.0 * LOG2PI + ldme);
    const double ct_mt = -0.5 * (32.0 * LOG2PI + ldmt);
    const double ct_mp = -0.5 * (32.0 * LOG2PI + ldmp);
    double c = ct_mp + ct_me;
    c += (double)(TT - 1) * (ct_me + ct_mt + 0.5 * 32.0 * LOG2PI + 16.0);
    c += 0.5 * 32.0 * LOG2PI + 16.0;
    ((double*)(ws + WS_DACC))[0] = c;
  }
  __syncthreads();
}

// ---------------- Riccati operator squaring (block 0) ----------------
__device__ void dev_compose(float* __restrict__ ws, float* sm, int tid) {
  float *Kc = sm,      *Ac = sm+MS,   *Gc = sm+2*MS;
  float *Kn = sm+3*MS, *An = sm+4*MS, *Gn = sm+5*MS;
  float *Mi = sm+6*MS, *V1 = sm+7*MS, *Wm = sm+8*MS;
  stage_mat(ws + WS_QHC, Kc, tid);
  stage_mat(ws + WS_QIW, Ac, tid);
  for (int e = tid; e < MS; e += 256) Gc[e] = 0.f;
  __syncthreads();
  for (int d = 0; d < 8; ++d) {          // builds Phi^{2^{d+1}}
    for (int e = tid; e < MS; e += 256) Mi[e] = Kc[e] + Gc[e];
    __syncthreads();
    if (tid < 64) wave_inv36(Mi, tid);
    __syncthreads();
    mm_rr(Ac, Mi, V1, tid);   // A M^-1 (M^-1 sym)
    mm_tp(Ac, Mi, Wm, tid);   // A^T M^-1
    __syncthreads();
    mm_rr_sub(V1, Ac, Kc, Kn, tid);   // K' = K - A M^-1 A^T
    mm_p(V1, Ac, An, tid);            // A' = A M^-1 A
    mm_p_sub(Wm, Ac, Gc, Gn, tid);    // G' = G - A^T M^-1 A
    __syncthreads();
    float* tp;
    tp=Kc; Kc=Kn; Kn=tp;  tp=Ac; Ac=An; An=tp;  tp=Gc; Gc=Gn; Gn=tp;
    if (d >= 2) {                       // save Phi^8 .. Phi^256 (ops 0..5)
      float* op = ws + WS_OPS + (d-2)*3072;
      destage_mat(Kc, op, tid);
      destage_mat(Ac, op + 1024, tid);
      destage_mat(Gc, op + 2048, tid);
    }
  }
}

// ---------------- eta machinery ----------------
__device__ void dev_keta_a(float* __restrict__ ws, float* sm, int tid, int c) {
  float *Aa = sm, *Ab = sm+MS, *Xl = sm+2*MS, *bb = sm+3*MS;
  const int t1 = CH*c + 1;
  stage_mat(ws + WS_X + t1*1024, Aa, tid);
  if (tid < 32) bb[tid] = ws[WS_YT + t1*32 + tid];
  __syncthreads();
  float *Acur = Aa, *Anew = Ab; int pb = 0;
  for (int t = t1 + 1; t <= t1 + CH - 1; ++t) {
    stage_mat(ws + WS_X + t*1024, Xl, tid);
    __syncthreads();
    mm_p(Xl, Acur, Anew, tid);
    if (tid < 32) {
      float s = ws[WS_YT + t*32 + tid];
      for (int k = 0; k < 32; ++k) s += Xl[tid*ST+k] * bb[pb*32 + k];
      bb[(pb^1)*32 + tid] = s;
    }
    __syncthreads();
    float* tp = Acur; Acur = Anew; Anew = tp; pb ^= 1;
  }
  float* dst = ws + WS_ETA_A + (c+1)*1056;
  destage_mat(Acur, dst, tid);
  if (tid < 32) dst[1024 + tid] = bb[pb*32 + tid];
}

// radix-8 prefix level, step 1 (ETA_A -> ETA_B)
__device__ void dev_eta_lvl8(float* __restrict__ ws, float* sm, int tid, int c) {
  const float* in = ws + WS_ETA_A;
  float* out = ws + WS_ETA_B;
  float *AR0 = sm, *AR1 = sm+MS, *A0 = sm+2*MS;
  float *bv = sm+3*MS, *b0 = bv + 64;
  stage_mat(in + c*1056, AR0, tid);
  if (tid < 32) bv[tid] = in[c*1056 + 1024 + tid];
  __syncthreads();
  float *AR = AR0, *At = AR1; int pb = 0;
  for (int kk = 1; kk <= 7; ++kk) {
    const int idx = c - kk;
    if (idx < 0) break;
    stage_mat(in + idx*1056, A0, tid);
    if (tid < 32) b0[tid] = in[idx*1056 + 1024 + tid];
    __syncthreads();
    mm_p(AR, A0, At, tid);                 // A' = A_R @ A_earlier
    if (tid < 32) {
      float s = bv[pb*32 + tid];
      for (int k = 0; k < 32; ++k) s += AR[tid*ST+k] * b0[k];
      bv[(pb^1)*32 + tid] = s;             // b' = A_R b_earlier + b_R
    }
    __syncthreads();
    float* tp = AR; AR = At; At = tp; pb ^= 1;
  }
  destage_mat(AR, out + c*1056, tid);
  if (tid < 32) out[c*1056 + 1024 + tid] = bv[pb*32 + tid];
}

// keta_b with folded L2 (reads ETA_B, folds stride-8 predecessors)
__device__ void dev_keta_b(float* __restrict__ ws, float* sm, int tid, int c) {
  float *A_0 = sm, *A_1 = sm+MS, *A_2 = sm+2*MS;
  float *bb = sm+3*MS;   // [0..63] ping-pong, [64..95] stage, [96..127] zeta, [128..159] zn
  stage_mat(ws + WS_ETA_B + c*1056, A_0, tid);
  if (tid < 32) bb[tid] = ws[WS_ETA_B + c*1056 + 1024 + tid];
  __syncthreads();
  float *AR = A_0, *Ax = A_1; int pb = 0;
  for (int kk = 1; kk <= 7; ++kk) {
    const int idx = c - 8*kk;
    if (idx < 0) break;
    stage_mat(ws + WS_ETA_B + idx*1056, A_2, tid);
    if (tid < 32) bb[64 + tid] = ws[WS_ETA_B + idx*1056 + 1024 + tid];
    __syncthreads();
    mm_p(AR, A_2, Ax, tid);
    if (tid < 32) {
      float s = bb[pb*32 + tid];
      for (int k = 0; k < 32; ++k) s += AR[tid*ST+k] * bb[64+k];
      bb[(pb^1)*32 + tid] = s;
    }
    __syncthreads();
    float* tp = AR; AR = Ax; Ax = tp; pb ^= 1;
  }
  float *zeta = bb + 96, *zn = bb + 128;
  if (tid < 32) {
    float s = bb[pb*32 + tid];
    for (int k = 0; k < 32; ++k)
      s += AR[tid*ST+k] * (ws[WS_ETA0 + k] - ws[WS_CTB + k]);
    zeta[tid] = s;                         // zeta_{8c}
  }
  __syncthreads();
  float *Bl = A_0, *Xl = A_1;              // AR dead after zeta
  const int nst = (c == NCH-1) ? CH-1 : CH;
  for (int i = 0; i < nst; ++i) {
    const int t = CH*c + 1 + i;
    stage_mat(ws + WS_BCOV + t*1024, Bl, tid);
    stage_mat(ws + WS_X + t*1024, Xl, tid);
    __syncthreads();
    if (tid < 32) {
      float s = 0.f;
      for (int k = 0; k < 32; ++k) s += Bl[tid*ST+k] * zeta[k];
      ws[WS_BA + t*32 + tid] = s;
    } else if (tid < 64) {
      const int i2 = tid - 32;
      float s = ws[WS_YT + t*32 + i2];
      for (int k = 0; k < 32; ++k) s += Xl[i2*ST+k] * zeta[k];
      zn[i2] = s;
    }
    __syncthreads();
    if (tid < 32) zeta[tid] = zn[tid];
    __syncthreads();
  }
  if (c == NCH-1 && tid < 32)
    ws[WS_ETAF + tid] = zeta[tid] + ws[WS_CTB + tid];
}

// ---------------- S machinery ----------------
__device__ void dev_ksa(float* __restrict__ ws, float* sm, int tid, int c) {
  float *BTa=sm,      *BTb=sm+MS,   *Ka=sm+2*MS,  *Kb=sm+3*MS,
        *Tk=sm+4*MS,  *XC1=sm+5*MS, *Xl=sm+6*MS,  *KmTQ=sm+7*MS,
        *TQl=sm+8*MS, *EMMl=sm+9*MS,*C1l=sm+10*MS;
  const int t1 = CH*c + 1, t2 = CH*c + CH;
  const int j = tid & 31, r0 = tid >> 5;
  stage_mat(ws + WS_TQ, TQl, tid);
  stage_mat(ws + WS_EMM, EMMl, tid);
  stage_mat(ws + WS_C1, C1l, tid);
  for (int e = tid; e < MS; e += 256) {
    const int r = e / ST, cc = e - ST*r;
    BTa[e] = (cc < 32 && cc == r) ? 1.f : 0.f;   // BT = I
    Ka[e] = 0.f;                                  // K = 0
  }
  __syncthreads();
  float *BTc = BTa, *BTn = BTb, *Kc = Ka, *Kn = Kb;
  for (int t = t1; t <= t2; ++t) {
    stage_mat(ws + WS_X + t*1024, Xl, tid);
    for (int e = tid; e < MS; e += 256) KmTQ[e] = Kc[e] - 0.5f * TQl[e];
    __syncthreads();
    mm_rr(BTc, Xl, BTn, tid);          // BT' = BT @ X^T
    mm_rr(Xl, KmTQ, Tk, tid);          // X @ (K - .5TQ)  (sym)
    mm_p(Xl, C1l, XC1, tid);           // X @ C1
    __syncthreads();
    {
      float4 xb[8];
#pragma unroll
      for (int kk = 0; kk < 8; ++kk) xb[kk] = *(const float4*)(Xl + j*ST + 4*kk);
#pragma unroll
      for (int m = 0; m < 4; ++m) {
        const int ri = r0 + 8*m;
        float s = 0.f;
#pragma unroll
        for (int kk = 0; kk < 8; ++kk)
          s += dot4(*(const float4*)(Tk + ri*ST + 4*kk), xb[kk]);
        Kn[ri*ST+j] = s + 0.5f*(XC1[ri*ST+j] + XC1[j*ST+ri]) + EMMl[ri*ST+j];
      }
    }
    __syncthreads();
    float* tp = BTc; BTc = BTn; BTn = tp;
    tp = Kc; Kc = Kn; Kn = tp;
  }
  float* dst = ws + WS_CEA + (c+1)*2048;
  destage_mat(BTc, dst, tid);
  destage_mat(Kc, dst + 1024, tid);
}

// radix-8 S prefix level, step 1 (CEA -> CEB)
__device__ void dev_ks_lvl8(float* __restrict__ ws, float* sm, int tid, int c) {
  const float* in = ws + WS_CEA;
  float* out = ws + WS_CEB;
  float *BT0=sm, *BT1=sm+MS, *K0=sm+2*MS, *K1=sm+3*MS,
        *BTo=sm+4*MS, *Ko=sm+5*MS, *tmp=sm+6*MS;
  stage_mat(in + c*2048, BT0, tid);
  stage_mat(in + c*2048 + 1024, K0, tid);
  __syncthreads();
  float *BTR=BT0, *BTt=BT1, *KR=K0, *Kt=K1;
  for (int kk = 1; kk <= 7; ++kk) {
    const int idx = c - kk;
    if (idx < 0) break;
    stage_mat(in + idx*2048, BTo, tid);
    stage_mat(in + idx*2048 + 1024, Ko, tid);
    __syncthreads();
    mm_p(Ko, BTR, tmp, tid);           // K_old @ B_R^T
    mm_p(BTo, BTR, BTt, tid);          // BT' = BT_old @ BT_R
    __syncthreads();
    mm_tp_addL(BTR, tmp, KR, Kt, tid); // K' = B_R tmp + K_R
    __syncthreads();
    float* tp = BTR; BTR = BTt; BTt = tp;
    tp = KR; KR = Kt; Kt = tp;
  }
  destage_mat(BTR, out + c*2048, tid);
  destage_mat(KR, out + c*2048 + 1024, tid);
}

// ksc with folded L2 (reads CEB, folds stride-8 predecessors)
__device__ void dev_ksc(float* __restrict__ ws, float* sm, float* red,
                        int tid, int c) {
  float *BT0=sm, *BT1=sm+MS, *K0=sm+2*MS, *K1=sm+3*MS,
        *BTo=sm+4*MS, *Ko=sm+5*MS, *tmp=sm+6*MS;
  stage_mat(ws + WS_CEB + c*2048, BT0, tid);
  stage_mat(ws + WS_CEB + c*2048 + 1024, K0, tid);
  __syncthreads();
  float *BTR=BT0, *BTt=BT1, *KR=K0, *Kt=K1;
  for (int kk = 1; kk <= 7; ++kk) {
    const int idx = c - 8*kk;
    if (idx < 0) break;
    stage_mat(ws + WS_CEB + idx*2048, BTo, tid);
    stage_mat(ws + WS_CEB + idx*2048 + 1024, Ko, tid);
    __syncthreads();
    mm_p(Ko, BTR, tmp, tid);
    mm_p(BTo, BTR, BTt, tid);
    __syncthreads();
    mm_tp_addL(BTR, tmp, KR, Kt, tid);
    __syncthreads();
    float* tp = BTR; BTR = BTt; BTt = tp;
    tp = KR; KR = Kt; Kt = tp;
  }
  // prefix composed: BTP = BTR, K_P = KR
  float *TQl=sm+7*MS, *EMMl=sm+8*MS, *C1l=sm+9*MS,
        *S=sm+10*MS, *SmTQ=sm+11*MS, *XC1=sm+12*MS;
  float *T1=tmp, *Xl=BTo, *Bcl=Ko;    // free after fold
  const int j = tid & 31, r0 = tid >> 5;
  stage_mat(ws + WS_TQ, TQl, tid);
  stage_mat(ws + WS_EMM, EMMl, tid);
  stage_mat(ws + WS_C1, C1l, tid);
  stage_mat(ws + WS_S1, SmTQ, tid);   // S0 temp
  __syncthreads();
  mm_p(SmTQ, BTR, T1, tid);           // S0 @ B_P^T
  __syncthreads();
  mm_tp_addL(BTR, T1, KR, S, tid);    // S = B_P T1 + K_P
  __syncthreads();
  double accd = 0.0;
  for (int i = 0; i < CH; ++i) {
    const int t = CH*c + 1 + i;
    if (t >= TT) break;
    stage_mat(ws + WS_X + t*1024, Xl, tid);
    stage_mat(ws + WS_BCOV + t*1024, Bcl, tid);
#pragma unroll
    for (int m = 0; m < 4; ++m) {
      const int ri = r0 + 8*m;
      SmTQ[ri*ST+j] = S[ri*ST+j] - 0.5f * TQl[ri*ST+j];
    }
    __syncthreads();
    float part = 0.f;
#pragma unroll
    for (int m = 0; m < 4; ++m) {
      const int ri = r0 + 8*m;
      part += SmTQ[ri*ST+j] * Bcl[ri*ST+j];     // trace((S-.5TQ) bcov)
    }
    const float r2 = block_reduce(part, red, tid);
    if (tid == 0) accd += (double)r2;
    mm_rr(Xl, SmTQ, T1, tid);                   // X @ (S-.5TQ)  (sym)
    mm_p(Xl, C1l, XC1, tid);
    __syncthreads();
    {
      float4 xb[8];
#pragma unroll
      for (int kk = 0; kk < 8; ++kk) xb[kk] = *(const float4*)(Xl + j*ST + 4*kk);
#pragma unroll
      for (int m = 0; m < 4; ++m) {
        const int ri = r0 + 8*m;
        float s = 0.f;
#pragma unroll
        for (int kk = 0; kk < 8; ++kk)
          s += dot4(*(const float4*)(T1 + ri*ST + 4*kk), xb[kk]);
        S[ri*ST+j] = s + 0.5f*(XC1[ri*ST+j] + XC1[j*ST+ri]) + EMMl[ri*ST+j];
      }
    }
    __syncthreads();
  }
  if (tid == 0) ((double*)(ws + WS_PART))[64 + c] = accd;
}

// ---------------- G machinery ----------------
__device__ void dev_kga(float* __restrict__ ws, float* sm, int tid, int c) {
  float *ATa = sm, *ATb = sm+MS, *Xl = sm+2*MS, *bb = sm+3*MS;
  const int t1 = CH*c + 1;
  const int t2 = (CH*c + CH < TT) ? CH*c + CH : TT - 1;
  stage_mat(ws + WS_X + t2*1024, ATa, tid);     // AT = X_{t2}
  if (tid < 32) bb[tid] = ws[WS_BA + t2*32 + tid];
  __syncthreads();
  float *ATc = ATa, *ATn = ATb;
  int pb = 0;
  for (int t = t2 - 1; t >= t1; --t) {
    stage_mat(ws + WS_X + t*1024, Xl, tid);
    __syncthreads();
    mm_p(ATc, Xl, ATn, tid);                    // AT' = AT @ X_t
    if (tid < 32) {
      float s = ws[WS_BA + t*32 + tid];
      for (int k = 0; k < 32; ++k) s += Xl[k*ST+tid] * bb[pb*32 + k];
      bb[(pb^1)*32 + tid] = s;
    }
    __syncthreads();
    float* tp = ATc; ATc = ATn; ATn = tp; pb ^= 1;
  }
  float* dst = ws + WS_CEA + (c-1)*1056;        // GEA = CEA (1056-stride)
  destage_mat(ATc, dst, tid);
  if (tid < 32) dst[1024 + tid] = bb[pb*32 + tid];
}

// radix-8 G suffix level, step 1 (CEA -> CEB, 1056-stride)
__device__ void dev_kg_lvl8(float* __restrict__ ws, float* sm, int tid, int c) {
  const float* in = ws + WS_CEA;
  float* out = ws + WS_CEB;
  float *AR0 = sm, *AR1 = sm+MS, *ATl = sm+2*MS;
  float *bv = sm+3*MS, *bl = bv + 64;
  stage_mat(in + c*1056, AR0, tid);
  if (tid < 32) bv[tid] = in[c*1056 + 1024 + tid];
  __syncthreads();
  float *AR = AR0, *At = AR1; int pb = 0;
  for (int kk = 1; kk <= 7; ++kk) {
    const int idx = c + kk;
    if (idx > NCH - 1) break;
    stage_mat(in + idx*1056, ATl, tid);
    if (tid < 32) bl[tid] = in[idx*1056 + 1024 + tid];
    __syncthreads();
    mm_p(ATl, AR, At, tid);                    // AT' = AT_later @ AT_R
    if (tid < 32) {
      float s = bv[pb*32 + tid];
      for (int k = 0; k < 32; ++k) s += AR[k*ST+tid] * bl[k];  // b' = b_R + A_R b_later
      bv[(pb^1)*32 + tid] = s;
    }
    __syncthreads();
    float* tp = AR; AR = At; At = tp; pb ^= 1;
  }
  destage_mat(AR, out + c*1056, tid);
  if (tid < 32) out[c*1056 + 1024 + tid] = bv[pb*32 + tid];
}

// kgb with folded G-L2 (reads CEB, folds stride-8 successors)
__device__ void dev_kgb(const float* __restrict__ obs, const float* __restrict__ mpm,
                        const float* __restrict__ mtw, const float* __restrict__ mtb,
                        const float* __restrict__ mew, const float* __restrict__ meb,
                        float* __restrict__ ws, float* sm, float* red, int tid, int c) {
  float *ATa=sm,      *ATb=sm+MS,    *Xl=sm+2*MS,  *Y1=sm+3*MS,  *Y2=sm+4*MS,
        *Jb=sm+5*MS,  *M2T=sm+6*MS,  *mewl=sm+7*MS,*EmLl=sm+8*MS,
        *fPl=sm+9*MS, *Mtpl=sm+10*MS,*Mepl=sm+11*MS,*mtwl=sm+12*MS;
  float *vec = sm + 13*MS;
  float *fml=vec, *mebl=vec+32, *mtbl=vec+64, *mpml=vec+96, *yl=vec+128,
        *bal=vec+160, *gv=vec+192, *cme=vec+224, *cmo=vec+256, *bv=vec+288;
  const int j = tid & 31, r0 = tid >> 5;
  stage_mat(mew, mewl, tid);
  stage_mat(ws + WS_EML, EmLl, tid);
  stage_mat(ws + WS_FPT, fPl, tid);
  stage_mat(ws + WS_MTP, Mtpl, tid);
  stage_mat(ws + WS_MEP, Mepl, tid);
  stage_mat(mtw, mtwl, tid);
  stage_mat(ws + WS_CEB + c*1056, ATa, tid);
  if (tid < 32) {
    fml[tid] = ws[WS_FMT + tid];
    mebl[tid] = meb[tid]; mtbl[tid] = mtb[tid]; mpml[tid] = mpm[tid];
    bv[tid] = ws[WS_CEB + c*1056 + 1024 + tid];
  }
  __syncthreads();
  float *ATc = ATa, *ATo = ATb;
  int bc = 0;
  // fold G-L2: compose with CEB slots c+8k (suffix)
  for (int kk = 1; kk <= 7; ++kk) {
    const int idx = c + 8*kk;
    if (idx > NCH - 1) break;
    stage_mat(ws + WS_CEB + idx*1056, Xl, tid);
    if (tid < 32) bal[tid] = ws[WS_CEB + idx*1056 + 1024 + tid];
    __syncthreads();
    mm_p(Xl, ATc, ATo, tid);
    if (tid < 32) {
      float s = bv[bc*32 + tid];
      for (int k = 0; k < 32; ++k) s += ATc[k*ST+tid] * bal[k];
      bv[(bc^1)*32 + tid] = s;
    }
    __syncthreads();
    float* tp = ATc; ATc = ATo; ATo = tp; bc ^= 1;
  }
  double accd = 0.0;
  for (int s = CH*c + CH - 1; s >= CH*c; --s) {
    if (s < TT-1) stage_mat(ws + WS_X + (s+1)*1024, Xl, tid);
    if (s == 0)   stage_mat(ws + WS_MPP, Jb, tid);
    if (tid < 32) {
      yl[tid] = obs[s*32 + tid];
      if (s >= 1) bal[tid] = ws[WS_BA + s*32 + tid];
    }
    __syncthreads();
    if (s < TT-1) {
      mm_p(ATc, Xl, ATo, tid);                  // AT' = AT @ X_{s+1}
      if (tid < 32) {
        float v = ws[WS_BA + (s+1)*32 + tid];
        for (int k = 0; k < 32; ++k) v += Xl[k*ST+tid] * bv[bc*32 + k];
        bv[(bc^1)*32 + tid] = v;
      }
    }
    __syncthreads();
    const float* AT = (s < TT-1) ? ATo : ATc;
    const float* bl = (s < TT-1) ? (bv + (bc^1)*32) : (bv + bc*32);
    mm_rr(mewl, AT, Y1, tid);                   // mew@G
    mm_rr(EmLl, AT, Y2, tid);                   // EmL@G
    if (s >= 1) {                               // Jb = mtw@X_s^T - I (X_s global rows)
      const float* Xg = ws + WS_X + s*1024;
      float4 xg[8];
#pragma unroll
      for (int kk = 0; kk < 8; ++kk) xg[kk] = *(const float4*)(Xg + j*32 + 4*kk);
#pragma unroll
      for (int m = 0; m < 4; ++m) {
        const int ri = r0 + 8*m;
        float v = 0.f;
#pragma unroll
        for (int kk = 0; kk < 8; ++kk)
          v += dot4(*(const float4*)(mtwl + ri*ST + 4*kk), xg[kk]);
        Jb[ri*ST+j] = v - ((ri == j) ? 1.f : 0.f);
      }
    }
    if (tid < 32) {
      float g = bl[tid];
      for (int k = 0; k < 32; ++k) g += AT[k*ST+tid] * fml[k];
      gv[tid] = g;                              // g = G@fm + h
    }
    __syncthreads();
    if (s >= 1) mm_rr(AT, Jb, M2T, tid);        // M2^T = G^T Jb^T
    if (tid < 32) {
      float s1v = mebl[tid] - yl[tid];
      for (int k = 0; k < 32; ++k) s1v += mewl[tid*ST+k] * gv[k];
      cme[tid] = s1v;
      float s2v;
      if (s >= 1) {
        s2v = mtbl[tid];
        for (int k = 0; k < 32; ++k)
          s2v += Jb[tid*ST+k] * gv[k] + mtwl[tid*ST+k] * bal[k];
      } else {
        s2v = gv[tid] - mpml[tid];
      }
      cmo[tid] = s2v;
    }
    __syncthreads();
    const float* M2Tp = (s >= 1) ? M2T : AT;
    const float* Mqp  = (s >= 1) ? Mtpl : Jb;   // s=0: Jb holds Mpp
    float4 fb[8], m2b[8];
#pragma unroll
    for (int kk = 0; kk < 8; ++kk) {
      fb[kk]  = *(const float4*)(fPl + j*ST + 4*kk);
      m2b[kk] = *(const float4*)(M2Tp + j*ST + 4*kk);
    }
    float part = 0.f;
#pragma unroll
    for (int m = 0; m < 4; ++m) {
      const int ri = r0 + 8*m;
      float y3 = 0.f, e2 = 0.f, e1 = 0.f;
#pragma unroll
      for (int kk = 0; kk < 8; ++kk) {
        y3 += dot4(*(const float4*)(Y2 + ri*ST + 4*kk), fb[kk]);
        e2 += dot4(fb[kk], *(const float4*)(M2Tp + ri*ST + 4*kk));
        e1 += dot4(*(const float4*)(Mqp + ri*ST + 4*kk), m2b[kk]);
      }
      part += y3 * Y1[j*ST+ri]
            - 0.5f * e1 * e2
            - 0.5f * cme[ri] * Mepl[ri*ST+j] * cme[j]
            - 0.5f * cmo[ri] * Mqp[ri*ST+j] * cmo[j];
    }
    const float r2 = block_reduce(part, red, tid);
    if (tid == 0) accd += (double)r2;
    if (s < TT-1) { float* tp = ATc; ATc = ATo; ATo = tp; bc ^= 1; }
    __syncthreads();
  }
  if (tid == 0) ((double*)(ws + WS_PART))[128 + c] = accd;
}

// ---------------- k0: zero barrier counters ----------------
__global__ __launch_bounds__(256) void k0_init(float* __restrict__ ws) {
  unsigned* b = (unsigned*)(ws + WS_GBAR);
  for (int e = threadIdx.x; e < 4352; e += 256) b[e] = 0u;
}

// ---------------- the fused kernel ----------------
__global__ __launch_bounds__(256) void mega(
    const float* __restrict__ obs, const float* __restrict__ mpm,
    const float* __restrict__ mpc, const float* __restrict__ mtw,
    const float* __restrict__ mtb, const float* __restrict__ mtc,
    const float* __restrict__ mew, const float* __restrict__ meb,
    const float* __restrict__ mec, const float* __restrict__ vpm,
    const float* __restrict__ vpc, const float* __restrict__ vtw,
    const float* __restrict__ vtb, const float* __restrict__ vtc,
    const float* __restrict__ vew, const float* __restrict__ veb,
    const float* __restrict__ vcc, float* __restrict__ ws,
    float* __restrict__ out) {
  __shared__ __align__(16) float sm[15360];
  __shared__ float red[4];
  const int tid = threadIdx.x, blk = blockIdx.x;
  unsigned* bars = (unsigned*)(ws + WS_GBAR);
  double* P = (double*)(ws + WS_PART);
  int bix = 0;

  // ---- B0: 6 constant SPD inverses ----
  if (blk < 6) {
    const float* src = blk==0?mtc : blk==1?mec : blk==2?mpc : blk==3?vtc : blk==4?vcc : vpc;
    float* dst = ws + (blk==0?WS_MTP : blk==1?WS_MEP : blk==2?WS_MPP :
                       blk==3?WS_QI  : blk==4?WS_RI  : WS_P0I);
    if (tid < 64) {
      float a[32]; const int cc = tid & 31;
#pragma unroll
      for (int r = 0; r < 32; ++r)
        a[r] = (tid < 32) ? src[r*32 + cc] : ((r == tid - 32) ? 1.f : 0.f);
      const double pp = gj_inv32(a);
      if (tid >= 32) {
        const int c2 = tid - 32;
#pragma unroll
        for (int r = 0; r < 32; ++r) dst[r*32 + c2] = a[r];
      }
      if (tid == 0 && blk < 3) ws[WS_LDS3 + blk] = (float)log(pp);
    }
  }
  gridbar(bars, bix++, blk);   // 0

  // ---- B1: derived constants + operator squarings (blk0) ----
  if (blk == 0) {
    dev_k2(obs, vpm, vtw, vtb, vew, veb, mtw, mew, ws, tid);
    dev_compose(ws, sm, tid);
  }
  gridbar(bars, bix++, blk);   // 1

  // ---- B2: boundary (bit-decomp) + chunk expansion (blk<64) || YT (blk>=64) ----
  if (blk < NCH) {
    float *Zl=sm, *Mi=sm+MS, *Aol=sm+2*MS, *V1=sm+3*MS;
    float *Bcv=sm+4*MS, *Xs=sm+5*MS, *QiWl=sm+6*MS, *QHCl=sm+7*MS;
    const int c = blk;
    stage_mat(ws + WS_LAM0CW, Zl, tid);
    stage_mat(ws + WS_QIW, QiWl, tid);
    stage_mat(ws + WS_QHC, QHCl, tid);
    __syncthreads();
    for (int k = 0; k < 6; ++k) {
      if (!((c >> k) & 1)) continue;           // block-uniform
      const float* OP = ws + WS_OPS + k*3072;  // (K,A,G) of Phi^{8*2^k}
      {
        const int r = tid >> 3, c4 = (tid & 7) * 4;
        const float4 g = *(const float4*)(OP + 2048 + r*32 + c4);
        float4 z = *(const float4*)(Zl + r*ST + c4);
        z.x += g.x; z.y += g.y; z.z += g.z; z.w += g.w;
        *(float4*)(Mi + r*ST + c4) = z;
      }
      stage_mat(OP + 1024, Aol, tid);
      __syncthreads();
      if (tid < 64) wave_inv36(Mi, tid);
      __syncthreads();
      mm_rr(Aol, Mi, V1, tid);                 // A M^-1 (sym)
      __syncthreads();
      mm_rr_subg(V1, Aol, OP, Zl, tid);        // Z' = K - A M^-1 A^T
      __syncthreads();
    }
    const int nst = (c == NCH-1) ? CH-1 : CH;
    double acc = 0.0;
    for (int i = 0; i < nst; ++i) {
      const int t = CH*c + 1 + i;
      if (tid < 64) {
        float a[32]; const int cc = tid & 31;
#pragma unroll
        for (int r = 0; r < 32; ++r)
          a[r] = (tid < 32) ? Zl[r*ST+cc] : ((r == tid - 32) ? 1.f : 0.f);
        const double pp = gj_inv32(a);
        if (tid >= 32) {
          const int c2 = tid - 32;
#pragma unroll
          for (int r = 0; r < 32; ++r) {
            Bcv[r*ST + c2] = a[r];
            ws[WS_BCOV + t*1024 + r*32 + c2] = a[r];
          }
        }
        if (tid == 0) acc += -log(pp);
      }
      __syncthreads();
      mm_rr(QiWl, Bcv, Xs, tid);               // X = QiW bcov (sym)
      __syncthreads();
      destage_mat(Xs, ws + WS_X + t*1024, tid);
      mm_rr_sub(Xs, QiWl, QHCl, Zl, tid);      // Z' = QHC - X QiW^T
      __syncthreads();
    }
    if (c == NCH-1) destage_mat(Zl, ws + WS_Z512, tid);
    if (tid == 0) P[blk] = acc;
  } else {
    const int tb = blk - NCH;                  // 0..63
    const int t = tb*CH + (tid >> 5), i = tid & 31;
    float s = ws[WS_QIVTB + i] - ws[WS_CTB + i];
    for (int k = 0; k < 32; ++k)
      s += ws[WS_HTRI + i*32 + k] * (obs[t*32 + k] - veb[k]);
    ws[WS_YT + t*32 + i] = s;
  }
  gridbar(bars, bix++, blk);   // 2

  // ---- B3: eta chunk compose (blk<64) || S chunk compose (blk>=64) ----
  if (blk < NCH) {
    if (blk < NCH-1) {
      dev_keta_a(ws, sm, tid, blk);
    } else {
      for (int e = tid; e < 1056; e += 256)
        ws[WS_ETA_A + e] = (e < 1024 && ((e >> 5) == (e & 31))) ? 1.f : 0.f;
    }
  } else {
    const int c = blk - NCH;
    if (c < NCH-1) {
      dev_ksa(ws, sm, tid, c);
    } else {
      for (int e = tid; e < 2048; e += 256)
        ws[WS_CEA + e] = (e < 1024 && ((e >> 5) == (e & 31))) ? 1.f : 0.f;
    }
  }
  gridbar(bars, bix++, blk);   // 3

  // ---- B4: radix-8 L1: eta (blk<64) || S (blk>=64) ----
  if (blk < NCH) dev_eta_lvl8(ws, sm, tid, blk);
  else           dev_ks_lvl8(ws, sm, tid, blk - NCH);
  gridbar(bars, bix++, blk);   // 4

  // ---- B5: keta_b(+fold) then kga (blk<64) || ksc(+fold) (blk>=64) ----
  if (blk < NCH) {
    dev_keta_b(ws, sm, tid, blk);
    __threadfence();
    __syncthreads();
    if (blk == 0) {
      for (int e = tid; e < 1056; e += 256)
        ws[WS_CEA + (NCH-1)*1056 + e] =
            (e < 1024 && ((e >> 5) == (e & 31))) ? 1.f : 0.f;
    } else {
      dev_kga(ws, sm, tid, blk);   // chunk blk -> CEA slot blk-1 (1056-stride)
    }
  } else {
    dev_ksc(ws, sm, red, tid, blk - NCH);
  }
  gridbar(bars, bix++, blk);   // 5

  // ---- B6: radix-8 G-L1 (blk<64) || kfin (blk==64) ----
  if (blk < NCH) {
    dev_kg_lvl8(ws, sm, tid, blk);
  } else if (blk == NCH) {
    if (tid < 64) {
      float a[32]; const int cc = tid & 31;
#pragma unroll
      for (int r = 0; r < 32; ++r) {
        const float v = ws[WS_Z512 + r*32 + cc] - ws[WS_CW + r*32 + cc];
        a[r] = (tid < 32) ? v : ((r == tid - 32) ? 1.f : 0.f);
      }
      const double pp = gj_inv32(a);
      if (tid >= 32) {
        const int c2 = tid - 32;
        float fmv = 0.f;
#pragma unroll
        for (int r = 0; r < 32; ++r) {
          ws[WS_FPT + r*32 + c2] = a[r];
          fmv += a[r] * ws[WS_ETAF + r];
        }
        ws[WS_FMT + c2] = fmv;
      }
      if (tid == 0) P[192] = -log(pp);
    }
  }
  gridbar(bars, bix++, blk);   // 6

  // ---- B7: kgb(+fold) (blk<64) ----
  if (blk < NCH) dev_kgb(obs, mpm, mtw, mtb, mew, meb, ws, sm, red, tid, blk);
  gridbar(bars, bix++, blk);   // 7

  // ---- out: wave-parallel partial reduction (blk0) ----
  if (blk == 0 && tid < 64) {
    double v = 0.5 * P[tid] + P[64 + tid] + P[128 + tid];
#pragma unroll
    for (int m = 32; m >= 1; m >>= 1) v += __shfl_xor(v, m, 64);
    if (tid == 0) {
      const double* d = (const double*)(ws + WS_DACC);
      out[0] = (float)(v + d[0] + 0.5 * P[192]);
    }
  }
}

extern "C" void kernel_launch(void* const* d_in, const int* in_sizes, int n_in,
                              void* d_out, int out_size, void* d_ws, size_t ws_size,
                              hipStream_t stream) {
  (void)in_sizes; (void)n_in; (void)out_size; (void)ws_size;
  const float* obs = (const float*)d_in[0];
  const float* mpm = (const float*)d_in[1];
  const float* mpc = (const float*)d_in[2];
  const float* mtw = (const float*)d_in[3];
  const float* mtb = (const float*)d_in[4];
  const float* mtc = (const float*)d_in[5];
  const float* mew = (const float*)d_in[6];
  const float* meb = (const float*)d_in[7];
  const float* mec = (const float*)d_in[8];
  const float* vpm = (const float*)d_in[9];
  const float* vpc = (const float*)d_in[10];
  const float* vtw = (const float*)d_in[11];
  const float* vtb = (const float*)d_in[12];
  const float* vtc = (const float*)d_in[13];
  const float* vew = (const float*)d_in[14];
  const float* veb = (const float*)d_in[15];
  const float* vcc = (const float*)d_in[16];
  float* ws  = (float*)d_ws;
  float* out = (float*)d_out;

  k0_init<<<1, 256, 0, stream>>>(ws);
  mega<<<NB, 256, 0, stream>>>(obs, mpm, mpc, mtw, mtb, mtc, mew, meb, mec,
                               vpm, vpc, vtw, vtb, vtc, vew, veb, vcc, ws, out);
}